// Round 1
// baseline (1279.857 us; speedup 1.0000x reference)
//
#include <hip/hip_runtime.h>
#include <hip/hip_bf16.h>

#define HID 128
#define NHEAD 4
#define HOFF 32

// ---------------- CSR build ----------------
__global__ void count_deg(const int* __restrict__ dst, int* __restrict__ deg, int E) {
    int i = blockIdx.x * blockDim.x + threadIdx.x;
    if (i < E) atomicAdd(&deg[dst[i]], 1);
}

__global__ void block_sums(const int* __restrict__ deg, int* __restrict__ bsum, int n) {
    __shared__ int sbuf[512];
    int tid = threadIdx.x;
    int i = blockIdx.x * 512 + tid;
    sbuf[tid] = (i < n) ? deg[i] : 0;
    __syncthreads();
    for (int d = 256; d > 0; d >>= 1) {
        if (tid < d) sbuf[tid] += sbuf[tid + d];
        __syncthreads();
    }
    if (tid == 0) bsum[blockIdx.x] = sbuf[0];
}

__global__ void scan_partials(const int* __restrict__ bsum, int* __restrict__ bpre, int P) {
    __shared__ int buf[128];
    int tid = threadIdx.x; // 128 threads, P <= 128
    int v = (tid < P) ? bsum[tid] : 0;
    buf[tid] = v;
    __syncthreads();
    for (int d = 1; d < 128; d <<= 1) {
        int t = (tid >= d) ? buf[tid - d] : 0;
        __syncthreads();
        buf[tid] += t;
        __syncthreads();
    }
    if (tid < P) bpre[tid] = buf[tid] - v; // exclusive
}

__global__ void scan_blocks(const int* __restrict__ deg, const int* __restrict__ bpre,
                            int* __restrict__ offs, int* __restrict__ woff, int n) {
    __shared__ int sbuf[512];
    int tid = threadIdx.x;
    int i = blockIdx.x * 512 + tid;
    int v = (i < n) ? deg[i] : 0;
    sbuf[tid] = v;
    __syncthreads();
    for (int d = 1; d < 512; d <<= 1) {
        int t = (tid >= d) ? sbuf[tid - d] : 0;
        __syncthreads();
        sbuf[tid] += t;
        __syncthreads();
    }
    if (i < n) {
        int incl = bpre[blockIdx.x] + sbuf[tid];
        offs[i + 1] = incl;
        woff[i] = incl - v;
    }
    if (i == 0) offs[0] = 0;
}

__global__ void fill_csr(const int* __restrict__ src, const int* __restrict__ dst,
                         int* __restrict__ woff, int* __restrict__ csr_src, int E) {
    int i = blockIdx.x * blockDim.x + threadIdx.x;
    if (i < E) {
        int pos = atomicAdd(&woff[dst[i]], 1);
        csr_src[pos] = src[i];
    }
}

// ---------------- GEMM: C[n,128] = act(A[n,K] @ W[K,128] + b) ----------------
#define GEMM_ROWS 32
template <int K, bool RELU>
__global__ __launch_bounds__(256) void gemm_k(const float* __restrict__ A,
                                              const float* __restrict__ W,
                                              const float* __restrict__ bias,
                                              float* __restrict__ C, int n) {
    __shared__ __align__(16) float a_sh[GEMM_ROWS * K];
    const int tid = threadIdx.x;
    const int c = tid & 127;
    const int g = tid >> 7; // 0..1, each group computes 16 rows
    const int r0 = blockIdx.x * GEMM_ROWS;

    for (int i = tid * 4; i < GEMM_ROWS * K; i += 256 * 4) {
        int r = i / K, k = i % K;
        int gr = r0 + r;
        float4 v = make_float4(0.f, 0.f, 0.f, 0.f);
        if (gr < n) v = *(const float4*)&A[(size_t)gr * K + k];
        *(float4*)&a_sh[i] = v;
    }
    __syncthreads();

    float acc[16];
#pragma unroll
    for (int r = 0; r < 16; ++r) acc[r] = 0.f;
    const float* a_base = &a_sh[g * 16 * K];

    for (int k = 0; k < K; k += 4) {
        float w0 = W[(size_t)(k + 0) * 128 + c];
        float w1 = W[(size_t)(k + 1) * 128 + c];
        float w2 = W[(size_t)(k + 2) * 128 + c];
        float w3 = W[(size_t)(k + 3) * 128 + c];
#pragma unroll
        for (int r = 0; r < 16; ++r) {
            float4 av = *(const float4*)&a_base[r * K + k];
            acc[r] = fmaf(av.x, w0, acc[r]);
            acc[r] = fmaf(av.y, w1, acc[r]);
            acc[r] = fmaf(av.z, w2, acc[r]);
            acc[r] = fmaf(av.w, w3, acc[r]);
        }
    }
    float b = bias[c];
#pragma unroll
    for (int r = 0; r < 16; ++r) {
        int gr = r0 + g * 16 + r;
        if (gr < n) {
            float v = acc[r] + b;
            if (RELU) v = fmaxf(v, 0.f);
            C[(size_t)gr * 128 + c] = v;
        }
    }
}

// ---------------- fused GATv2 aggregate + residuals + LayerNorm + ReLU ----------------
// one wave (64 lanes) per node; lane holds features f0=2*lane, f0+1
// head of f0 = f0>>5 = lane>>4 -> 16-lane head groups
__global__ __launch_bounds__(256) void gat_aggregate(
    const float* __restrict__ h,      // [n,128] layer input
    const float* __restrict__ hs,     // [n,128] feat_src
    const float* __restrict__ hd,     // [n,128] feat_dst
    const int* __restrict__ offs,     // [n+1]
    const int* __restrict__ csr_src,  // [E]
    const float* __restrict__ attn,   // [128] this layer (H*O)
    const float* __restrict__ ln_g, const float* __restrict__ ln_b,
    float* __restrict__ h_out, int n) {
    int v = (blockIdx.x * blockDim.x + threadIdx.x) >> 6;
    int lane = threadIdx.x & 63;
    if (v >= n) return;
    int f0 = lane * 2;

    float a0 = attn[f0], a1 = attn[f0 + 1];
    float2 hdv = *(const float2*)&hd[(size_t)v * 128 + f0];
    float2 hsv = *(const float2*)&hs[(size_t)v * 128 + f0];

    // self-loop initializes the online softmax state
    float t0 = hsv.x + hdv.x; t0 = t0 > 0.f ? t0 : 0.2f * t0;
    float t1 = hsv.y + hdv.y; t1 = t1 > 0.f ? t1 : 0.2f * t1;
    float p = t0 * a0 + t1 * a1;
    p += __shfl_xor(p, 1); p += __shfl_xor(p, 2);
    p += __shfl_xor(p, 4); p += __shfl_xor(p, 8);
    float m = p;      // running per-head max (uniform within 16-lane group)
    float s = 1.0f;   // exp(p - m) = 1
    float accx = hsv.x, accy = hsv.y;

    int beg = offs[v], end = offs[v + 1];
    for (int i = beg; i < end; ++i) {
        int u = csr_src[i];
        float2 hsu = *(const float2*)&hs[(size_t)u * 128 + f0];
        float q0 = hsu.x + hdv.x; q0 = q0 > 0.f ? q0 : 0.2f * q0;
        float q1 = hsu.y + hdv.y; q1 = q1 > 0.f ? q1 : 0.2f * q1;
        float sc = q0 * a0 + q1 * a1;
        sc += __shfl_xor(sc, 1); sc += __shfl_xor(sc, 2);
        sc += __shfl_xor(sc, 4); sc += __shfl_xor(sc, 8);
        // branchless online-softmax update
        float mn = fmaxf(m, sc);
        float rr = __expf(m - mn);
        float w  = __expf(sc - mn);
        s    = fmaf(s, rr, w);
        accx = fmaf(accx, rr, w * hsu.x);
        accy = fmaf(accy, rr, w * hsu.y);
        m = mn;
    }
    float inv = 1.0f / (s + 1e-9f);

    float2 hv = *(const float2*)&h[(size_t)v * 128 + f0];
    // rst = agg + h ; x = h + rst = 2h + agg
    float x0 = fmaf(accx, inv, 2.f * hv.x);
    float x1 = fmaf(accy, inv, 2.f * hv.y);

    // LayerNorm over 128 features
    float sum = x0 + x1, sq = x0 * x0 + x1 * x1;
#pragma unroll
    for (int d = 1; d < 64; d <<= 1) { sum += __shfl_xor(sum, d); sq += __shfl_xor(sq, d); }
    float mu = sum * (1.f / 128.f);
    float var = sq * (1.f / 128.f) - mu * mu;
    float rstd = rsqrtf(var + 1e-5f);
    float y0 = (x0 - mu) * rstd * ln_g[f0]     + ln_b[f0];
    float y1 = (x1 - mu) * rstd * ln_g[f0 + 1] + ln_b[f0 + 1];
    y0 = fmaxf(y0, 0.f); y1 = fmaxf(y1, 0.f);
    *(float2*)&h_out[(size_t)v * 128 + f0] = make_float2(y0, y1);
}

// ---------------- epilogue ----------------
__global__ void copy_f4(const float4* __restrict__ src, float4* __restrict__ dst, size_t n4) {
    size_t i = blockIdx.x * (size_t)blockDim.x + threadIdx.x;
    size_t stride = (size_t)gridDim.x * blockDim.x;
    for (; i < n4; i += stride) dst[i] = src[i];
}

__global__ void graph_mean_partial(const float* __restrict__ h, float* __restrict__ gacc, int n) {
    int tid = threadIdx.x; // 256
    size_t gid = blockIdx.x * 256 + tid;
    size_t stride = (size_t)gridDim.x * 256; // multiple of 128
    float p = 0.f;
    size_t tot = (size_t)n * 128;
    for (size_t i = gid; i < tot; i += stride) p += h[i];
    __shared__ float sbuf[256];
    sbuf[tid] = p;
    __syncthreads();
    if (tid < 128) {
        // column of sbuf[tid] and sbuf[tid+128] are both tid (stride % 128 == 0)
        atomicAdd(&gacc[tid], sbuf[tid] + sbuf[tid + 128]);
    }
}

__global__ void graph_mean_final(const float* __restrict__ gacc, float* __restrict__ out, int n) {
    int c = threadIdx.x; // 128
    out[c] = gacc[c] / (float)n;
}

__global__ __launch_bounds__(256) void heads_kernel(
    const float* __restrict__ z,
    const float* __restrict__ Wa, const float* __restrict__ ba,
    const float* __restrict__ Wg, const float* __restrict__ bg,
    const float* __restrict__ Wal, const float* __restrict__ bal,
    const float* __restrict__ Wn, const float* __restrict__ bn,
    const float* __restrict__ Wt, const float* __restrict__ bt,
    float* __restrict__ logits, float* __restrict__ spawn, int n) {
    int v = (blockIdx.x * blockDim.x + threadIdx.x) >> 6;
    int lane = threadIdx.x & 63;
    if (v >= n) return;
    int f0 = lane * 2;
    float2 zv = *(const float2*)&z[(size_t)v * 128 + f0];
    float p0 = zv.x * Wa[f0 * 2]     + zv.y * Wa[(f0 + 1) * 2];
    float p1 = zv.x * Wa[f0 * 2 + 1] + zv.y * Wa[(f0 + 1) * 2 + 1];
    float p2 = zv.x * Wg[f0]  + zv.y * Wg[f0 + 1];
    float p3 = zv.x * Wal[f0] + zv.y * Wal[f0 + 1];
    float p4 = zv.x * Wn[f0]  + zv.y * Wn[f0 + 1];
    float p5 = zv.x * Wt[f0]  + zv.y * Wt[f0 + 1];
#pragma unroll
    for (int d = 1; d < 64; d <<= 1) {
        p0 += __shfl_xor(p0, d); p1 += __shfl_xor(p1, d); p2 += __shfl_xor(p2, d);
        p3 += __shfl_xor(p3, d); p4 += __shfl_xor(p4, d); p5 += __shfl_xor(p5, d);
    }
    if (lane == 0) {
        logits[(size_t)v * 2 + 0] = p0 + ba[0];
        logits[(size_t)v * 2 + 1] = p1 + ba[1];
        float gamma = 5.f / (1.f + __expf(-(p2 + bg[0])));
        float alpha = 2.f / (1.f + __expf(-(p3 + bal[0])));
        float noise = 1.f / (1.f + __expf(-(p4 + bn[0])));
        float theta = tanhf(p5 + bt[0]) * 3.14159265358979323846f;
        spawn[(size_t)v * 4 + 0] = gamma;
        spawn[(size_t)v * 4 + 1] = alpha;
        spawn[(size_t)v * 4 + 2] = noise;
        spawn[(size_t)v * 4 + 3] = theta;
    }
}

extern "C" void kernel_launch(void* const* d_in, const int* in_sizes, int n_in,
                              void* d_out, int out_size, void* d_ws, size_t ws_size,
                              hipStream_t stream) {
    const float* node_feats = (const float*)d_in[0];
    const int*   src  = (const int*)d_in[1];
    const int*   dst  = (const int*)d_in[2];
    const float* W_in = (const float*)d_in[3];
    const float* b_in = (const float*)d_in[4];
    const float* W_src = (const float*)d_in[5];
    const float* b_src = (const float*)d_in[6];
    const float* W_dst = (const float*)d_in[7];
    const float* b_dst = (const float*)d_in[8];
    const float* attn  = (const float*)d_in[9];
    const float* ln_g  = (const float*)d_in[10];
    const float* ln_b  = (const float*)d_in[11];
    const float* W1 = (const float*)d_in[12]; const float* b1 = (const float*)d_in[13];
    const float* W2 = (const float*)d_in[14]; const float* b2 = (const float*)d_in[15];
    const float* Wa = (const float*)d_in[16]; const float* ba = (const float*)d_in[17];
    const float* Wg = (const float*)d_in[18]; const float* bg = (const float*)d_in[19];
    const float* Wal = (const float*)d_in[20]; const float* bal = (const float*)d_in[21];
    const float* Wn = (const float*)d_in[22]; const float* bn = (const float*)d_in[23];
    const float* Wt = (const float*)d_in[24]; const float* bt = (const float*)d_in[25];

    const int n = in_sizes[0] / 32;  // 50000
    const int E = in_sizes[1];       // 1600000
    const int P = (n + 511) / 512;   // scan partial blocks

    // workspace partition
    char* ws = (char*)d_ws;
    size_t off = 0;
    auto alloc = [&](size_t bytes) -> void* {
        void* p = ws + off;
        off = (off + bytes + 255) & ~(size_t)255;
        return p;
    };
    float* B0 = (float*)alloc((size_t)n * 128 * 4);
    float* B1 = (float*)alloc((size_t)n * 128 * 4);
    float* B2 = (float*)alloc((size_t)n * 128 * 4);
    float* B3 = (float*)alloc((size_t)n * 128 * 4);
    int* deg  = (int*)alloc((size_t)n * 4);
    int* offs = (int*)alloc((size_t)(n + 1) * 4);
    int* woff = (int*)alloc((size_t)n * 4);
    int* csr  = (int*)alloc((size_t)E * 4);
    int* bsum = (int*)alloc((size_t)P * 4);
    int* bpre = (int*)alloc((size_t)P * 4);
    float* gacc = (float*)alloc(128 * 4);

    float* out = (float*)d_out;
    float* out_gemb   = out;                     // 128
    float* out_nemb   = out + 128;               // n*128
    float* out_logits = out + 128 + (size_t)n * 128;
    float* out_spawn  = out_logits + (size_t)n * 2;

    hipMemsetAsync(deg, 0, (size_t)n * 4, stream);
    hipMemsetAsync(gacc, 0, 128 * 4, stream);

    // CSR by dst (self-loops handled analytically in aggregate kernel)
    count_deg<<<(E + 255) / 256, 256, 0, stream>>>(dst, deg, E);
    block_sums<<<P, 512, 0, stream>>>(deg, bsum, n);
    scan_partials<<<1, 128, 0, stream>>>(bsum, bpre, P);
    scan_blocks<<<P, 512, 0, stream>>>(deg, bpre, offs, woff, n);
    fill_csr<<<(E + 255) / 256, 256, 0, stream>>>(src, dst, woff, csr, E);

    int gemm_grid = (n + GEMM_ROWS - 1) / GEMM_ROWS;

    // input projection
    gemm_k<32, false><<<gemm_grid, 256, 0, stream>>>(node_feats, W_in, b_in, B0, n);

    // layers: buffer rotation (cur, hs, hd, out)
    const float* cur = B0;
    float* HS[3] = {B1, B0, B0};
    float* HD[3] = {B2, B1, B1};
    float* HO[3] = {B3, B2, B3};
    for (int l = 0; l < 3; ++l) {
        gemm_k<128, false><<<gemm_grid, 256, 0, stream>>>(cur, W_src + (size_t)l * 128 * 128,
                                                          b_src + l * 128, HS[l], n);
        gemm_k<128, false><<<gemm_grid, 256, 0, stream>>>(cur, W_dst + (size_t)l * 128 * 128,
                                                          b_dst + l * 128, HD[l], n);
        gat_aggregate<<<(n + 3) / 4, 256, 0, stream>>>(cur, HS[l], HD[l], offs, csr,
                                                       attn + l * 128, ln_g + l * 128,
                                                       ln_b + l * 128, HO[l], n);
        cur = HO[l];
    }
    // cur == B3 == final node embedding

    // node MLP
    gemm_k<128, true><<<gemm_grid, 256, 0, stream>>>(cur, W1, b1, B0, n);   // z1
    gemm_k<128, true><<<gemm_grid, 256, 0, stream>>>(B0, W2, b2, B1, n);    // z

    // outputs
    copy_f4<<<1024, 256, 0, stream>>>((const float4*)cur, (float4*)out_nemb, (size_t)n * 32);
    graph_mean_partial<<<128, 256, 0, stream>>>(cur, gacc, n);
    graph_mean_final<<<1, 128, 0, stream>>>(gacc, out_gemb, n);
    heads_kernel<<<(n + 3) / 4, 256, 0, stream>>>(B1, Wa, ba, Wg, bg, Wal, bal,
                                                  Wn, bn, Wt, bt, out_logits, out_spawn, n);
}

// Round 2
// 965.869 us; speedup vs baseline: 1.3251x; 1.3251x over previous
//
#include <hip/hip_runtime.h>
#include <hip/hip_bf16.h>

#define HID 128
#define NHEAD 4

// ---------------- CSR build ----------------
__global__ void count_deg(const int* __restrict__ dst, int* __restrict__ deg, int E) {
    int i = blockIdx.x * blockDim.x + threadIdx.x;
    if (i < E) atomicAdd(&deg[dst[i]], 1);
}

__global__ void block_sums(const int* __restrict__ deg, int* __restrict__ bsum, int n) {
    __shared__ int sbuf[512];
    int tid = threadIdx.x;
    int i = blockIdx.x * 512 + tid;
    sbuf[tid] = (i < n) ? deg[i] : 0;
    __syncthreads();
    for (int d = 256; d > 0; d >>= 1) {
        if (tid < d) sbuf[tid] += sbuf[tid + d];
        __syncthreads();
    }
    if (tid == 0) bsum[blockIdx.x] = sbuf[0];
}

__global__ void scan_partials(const int* __restrict__ bsum, int* __restrict__ bpre, int P) {
    __shared__ int buf[128];
    int tid = threadIdx.x; // 128 threads, P <= 128
    int v = (tid < P) ? bsum[tid] : 0;
    buf[tid] = v;
    __syncthreads();
    for (int d = 1; d < 128; d <<= 1) {
        int t = (tid >= d) ? buf[tid - d] : 0;
        __syncthreads();
        buf[tid] += t;
        __syncthreads();
    }
    if (tid < P) bpre[tid] = buf[tid] - v; // exclusive
}

__global__ void scan_blocks(const int* __restrict__ deg, const int* __restrict__ bpre,
                            int* __restrict__ offs, int* __restrict__ woff, int n) {
    __shared__ int sbuf[512];
    int tid = threadIdx.x;
    int i = blockIdx.x * 512 + tid;
    int v = (i < n) ? deg[i] : 0;
    sbuf[tid] = v;
    __syncthreads();
    for (int d = 1; d < 512; d <<= 1) {
        int t = (tid >= d) ? sbuf[tid - d] : 0;
        __syncthreads();
        sbuf[tid] += t;
        __syncthreads();
    }
    if (i < n) {
        int incl = bpre[blockIdx.x] + sbuf[tid];
        offs[i + 1] = incl;
        woff[i] = incl - v;
    }
    if (i == 0) offs[0] = 0;
}

__global__ void fill_csr(const int* __restrict__ src, const int* __restrict__ dst,
                         int* __restrict__ woff, int* __restrict__ csr_src, int E) {
    int i = blockIdx.x * blockDim.x + threadIdx.x;
    if (i < E) {
        int pos = atomicAdd(&woff[dst[i]], 1);
        csr_src[pos] = src[i];
    }
}

// ---------------- GEMM: C[n,128] = act(A[n,K] @ W[K,128] + b) ----------------
// 64 rows x 128 cols per block, 256 threads, each thread 8 rows x 4 cols.
// LDS reads are b128 broadcasts (2 distinct addrs per wave) -> ~1B/FMA.
#define GR 64
template <int K, bool RELU>
__global__ __launch_bounds__(256) void gemm_k(const float* __restrict__ A,
                                              const float* __restrict__ W,
                                              const float* __restrict__ bias,
                                              float* __restrict__ C, int n) {
    __shared__ __align__(16) float a_sh[GR * K];
    const int tid = threadIdx.x;
    const int tx = tid & 31;  // column group: cols tx*4 .. tx*4+3
    const int ty = tid >> 5;  // 0..7: rows ty*8 .. ty*8+7
    const int r0 = blockIdx.x * GR;

    for (int i = tid * 4; i < GR * K; i += 1024) {
        int r = i / K, k = i % K;
        int gr = r0 + r;
        float4 v = make_float4(0.f, 0.f, 0.f, 0.f);
        if (gr < n) v = *(const float4*)&A[(size_t)gr * K + k];
        *(float4*)&a_sh[i] = v;
    }
    __syncthreads();

    float4 acc[8];
#pragma unroll
    for (int r = 0; r < 8; ++r) acc[r] = make_float4(0.f, 0.f, 0.f, 0.f);

    const float* ab = &a_sh[ty * 8 * K];
    const float* wb = &W[tx * 4];

    for (int k = 0; k < K; k += 4) {
        float4 w0 = *(const float4*)&wb[(size_t)(k + 0) * 128];
        float4 w1 = *(const float4*)&wb[(size_t)(k + 1) * 128];
        float4 w2 = *(const float4*)&wb[(size_t)(k + 2) * 128];
        float4 w3 = *(const float4*)&wb[(size_t)(k + 3) * 128];
#pragma unroll
        for (int r = 0; r < 8; ++r) {
            float4 a4 = *(const float4*)&ab[r * K + k];
            acc[r].x = fmaf(a4.x, w0.x, acc[r].x);
            acc[r].y = fmaf(a4.x, w0.y, acc[r].y);
            acc[r].z = fmaf(a4.x, w0.z, acc[r].z);
            acc[r].w = fmaf(a4.x, w0.w, acc[r].w);
            acc[r].x = fmaf(a4.y, w1.x, acc[r].x);
            acc[r].y = fmaf(a4.y, w1.y, acc[r].y);
            acc[r].z = fmaf(a4.y, w1.z, acc[r].z);
            acc[r].w = fmaf(a4.y, w1.w, acc[r].w);
            acc[r].x = fmaf(a4.z, w2.x, acc[r].x);
            acc[r].y = fmaf(a4.z, w2.y, acc[r].y);
            acc[r].z = fmaf(a4.z, w2.z, acc[r].z);
            acc[r].w = fmaf(a4.z, w2.w, acc[r].w);
            acc[r].x = fmaf(a4.w, w3.x, acc[r].x);
            acc[r].y = fmaf(a4.w, w3.y, acc[r].y);
            acc[r].z = fmaf(a4.w, w3.z, acc[r].z);
            acc[r].w = fmaf(a4.w, w3.w, acc[r].w);
        }
    }

    float4 b4 = *(const float4*)&bias[tx * 4];
#pragma unroll
    for (int r = 0; r < 8; ++r) {
        int gr = r0 + ty * 8 + r;
        if (gr < n) {
            float4 o;
            o.x = acc[r].x + b4.x;
            o.y = acc[r].y + b4.y;
            o.z = acc[r].z + b4.z;
            o.w = acc[r].w + b4.w;
            if (RELU) {
                o.x = fmaxf(o.x, 0.f); o.y = fmaxf(o.y, 0.f);
                o.z = fmaxf(o.z, 0.f); o.w = fmaxf(o.w, 0.f);
            }
            *(float4*)&C[(size_t)gr * 128 + tx * 4] = o;
        }
    }
}

// ---------------- fused GATv2 aggregate + residuals + LayerNorm + ReLU ----------------
// one wave (64 lanes) per node; lane holds features f0=2*lane, f0+1
// 16-lane head groups; dual online-softmax states (edge unroll x2) + defer-max
__global__ __launch_bounds__(256) void gat_aggregate(
    const float* __restrict__ h,      // [n,128] layer input
    const float* __restrict__ hs,     // [n,128] feat_src
    const float* __restrict__ hd,     // [n,128] feat_dst
    const int* __restrict__ offs,     // [n+1]
    const int* __restrict__ csr_src,  // [E]
    const float* __restrict__ attn,   // [128] this layer (H*O)
    const float* __restrict__ ln_g, const float* __restrict__ ln_b,
    float* __restrict__ h_out, int n) {
    int v = (blockIdx.x * blockDim.x + threadIdx.x) >> 6;
    int lane = threadIdx.x & 63;
    if (v >= n) return;
    int f0 = lane * 2;

    float a0 = attn[f0], a1 = attn[f0 + 1];
    float2 hdv = *(const float2*)&hd[(size_t)v * 128 + f0];
    float2 hsv = *(const float2*)&hs[(size_t)v * 128 + f0];

    // self-loop score initializes reference max
    float t0 = hsv.x + hdv.x; t0 = t0 > 0.f ? t0 : 0.2f * t0;
    float t1 = hsv.y + hdv.y; t1 = t1 > 0.f ? t1 : 0.2f * t1;
    float p = t0 * a0 + t1 * a1;
    p += __shfl_xor(p, 1); p += __shfl_xor(p, 2);
    p += __shfl_xor(p, 4); p += __shfl_xor(p, 8);

    // dual states: (m, s, accx, accy)
    float m0 = p, s0 = 1.0f, ax0 = hsv.x, ay0 = hsv.y;
    float m1 = p, s1 = 0.0f, ax1 = 0.f, ay1 = 0.f;

    const char* hsb = (const char*)hs;
    const unsigned fb = (unsigned)f0 << 2;
    int beg = offs[v], end = offs[v + 1];
    int i = beg;
    for (; i + 2 <= end; i += 2) {
        int u0 = csr_src[i], u1 = csr_src[i + 1];
        float2 h0 = *(const float2*)(hsb + (((size_t)(unsigned)u0) << 9) + fb);
        float2 h1 = *(const float2*)(hsb + (((size_t)(unsigned)u1) << 9) + fb);
        float q0 = h0.x + hdv.x; q0 = q0 > 0.f ? q0 : 0.2f * q0;
        float q1 = h0.y + hdv.y; q1 = q1 > 0.f ? q1 : 0.2f * q1;
        float r0 = h1.x + hdv.x; r0 = r0 > 0.f ? r0 : 0.2f * r0;
        float r1 = h1.y + hdv.y; r1 = r1 > 0.f ? r1 : 0.2f * r1;
        float scA = q0 * a0 + q1 * a1;
        float scB = r0 * a0 + r1 * a1;
        scA += __shfl_xor(scA, 1); scB += __shfl_xor(scB, 1);
        scA += __shfl_xor(scA, 2); scB += __shfl_xor(scB, 2);
        scA += __shfl_xor(scA, 4); scB += __shfl_xor(scB, 4);
        scA += __shfl_xor(scA, 8); scB += __shfl_xor(scB, 8);
        if (__builtin_expect(__any((scA > m0 + 8.f) || (scB > m1 + 8.f)), 0)) {
            float mnA = fmaxf(m0, scA);
            float rrA = __expf(m0 - mnA), wA = __expf(scA - mnA);
            s0 = fmaf(s0, rrA, wA);
            ax0 = fmaf(ax0, rrA, wA * h0.x);
            ay0 = fmaf(ay0, rrA, wA * h0.y);
            m0 = mnA;
            float mnB = fmaxf(m1, scB);
            float rrB = __expf(m1 - mnB), wB = __expf(scB - mnB);
            s1 = fmaf(s1, rrB, wB);
            ax1 = fmaf(ax1, rrB, wB * h1.x);
            ay1 = fmaf(ay1, rrB, wB * h1.y);
            m1 = mnB;
        } else {
            float wA = __expf(scA - m0);
            float wB = __expf(scB - m1);
            s0 += wA; ax0 = fmaf(wA, h0.x, ax0); ay0 = fmaf(wA, h0.y, ay0);
            s1 += wB; ax1 = fmaf(wB, h1.x, ax1); ay1 = fmaf(wB, h1.y, ay1);
        }
    }
    if (i < end) { // odd tail -> state0
        int u0 = csr_src[i];
        float2 h0 = *(const float2*)(hsb + (((size_t)(unsigned)u0) << 9) + fb);
        float q0 = h0.x + hdv.x; q0 = q0 > 0.f ? q0 : 0.2f * q0;
        float q1 = h0.y + hdv.y; q1 = q1 > 0.f ? q1 : 0.2f * q1;
        float scA = q0 * a0 + q1 * a1;
        scA += __shfl_xor(scA, 1); scA += __shfl_xor(scA, 2);
        scA += __shfl_xor(scA, 4); scA += __shfl_xor(scA, 8);
        if (__builtin_expect(__any(scA > m0 + 8.f), 0)) {
            float mnA = fmaxf(m0, scA);
            float rrA = __expf(m0 - mnA), wA = __expf(scA - mnA);
            s0 = fmaf(s0, rrA, wA);
            ax0 = fmaf(ax0, rrA, wA * h0.x);
            ay0 = fmaf(ay0, rrA, wA * h0.y);
            m0 = mnA;
        } else {
            float wA = __expf(scA - m0);
            s0 += wA; ax0 = fmaf(wA, h0.x, ax0); ay0 = fmaf(wA, h0.y, ay0);
        }
    }
    // merge state1 into state0
    float mn = fmaxf(m0, m1);
    float e0 = __expf(m0 - mn), e1 = __expf(m1 - mn);
    float s = s0 * e0 + s1 * e1;
    float accx = ax0 * e0 + ax1 * e1;
    float accy = ay0 * e0 + ay1 * e1;
    float inv = 1.0f / (s + 1e-9f);

    float2 hv = *(const float2*)&h[(size_t)v * 128 + f0];
    // rst = agg + h ; x = h + rst = 2h + agg
    float x0 = fmaf(accx, inv, 2.f * hv.x);
    float x1 = fmaf(accy, inv, 2.f * hv.y);

    // LayerNorm over 128 features
    float sum = x0 + x1, sq = x0 * x0 + x1 * x1;
#pragma unroll
    for (int d = 1; d < 64; d <<= 1) { sum += __shfl_xor(sum, d); sq += __shfl_xor(sq, d); }
    float mu = sum * (1.f / 128.f);
    float var = sq * (1.f / 128.f) - mu * mu;
    float rstd = rsqrtf(var + 1e-5f);
    float y0 = (x0 - mu) * rstd * ln_g[f0]     + ln_b[f0];
    float y1 = (x1 - mu) * rstd * ln_g[f0 + 1] + ln_b[f0 + 1];
    y0 = fmaxf(y0, 0.f); y1 = fmaxf(y1, 0.f);
    *(float2*)&h_out[(size_t)v * 128 + f0] = make_float2(y0, y1);
}

// ---------------- epilogue ----------------
__global__ void copy_f4(const float4* __restrict__ src, float4* __restrict__ dst, size_t n4) {
    size_t i = blockIdx.x * (size_t)blockDim.x + threadIdx.x;
    size_t stride = (size_t)gridDim.x * blockDim.x;
    for (; i < n4; i += stride) dst[i] = src[i];
}

__global__ void graph_mean_partial(const float* __restrict__ h, float* __restrict__ gacc, int n) {
    int tid = threadIdx.x; // 256
    size_t gid = blockIdx.x * 256 + tid;
    size_t stride = (size_t)gridDim.x * 256; // multiple of 128
    float p = 0.f;
    size_t tot = (size_t)n * 128;
    for (size_t i = gid; i < tot; i += stride) p += h[i];
    __shared__ float sbuf[256];
    sbuf[tid] = p;
    __syncthreads();
    if (tid < 128) {
        atomicAdd(&gacc[tid], sbuf[tid] + sbuf[tid + 128]);
    }
}

__global__ void graph_mean_final(const float* __restrict__ gacc, float* __restrict__ out, int n) {
    int c = threadIdx.x; // 128
    out[c] = gacc[c] / (float)n;
}

__global__ __launch_bounds__(256) void heads_kernel(
    const float* __restrict__ z,
    const float* __restrict__ Wa, const float* __restrict__ ba,
    const float* __restrict__ Wg, const float* __restrict__ bg,
    const float* __restrict__ Wal, const float* __restrict__ bal,
    const float* __restrict__ Wn, const float* __restrict__ bn,
    const float* __restrict__ Wt, const float* __restrict__ bt,
    float* __restrict__ logits, float* __restrict__ spawn, int n) {
    int v = (blockIdx.x * blockDim.x + threadIdx.x) >> 6;
    int lane = threadIdx.x & 63;
    if (v >= n) return;
    int f0 = lane * 2;
    float2 zv = *(const float2*)&z[(size_t)v * 128 + f0];
    float p0 = zv.x * Wa[f0 * 2]     + zv.y * Wa[(f0 + 1) * 2];
    float p1 = zv.x * Wa[f0 * 2 + 1] + zv.y * Wa[(f0 + 1) * 2 + 1];
    float p2 = zv.x * Wg[f0]  + zv.y * Wg[f0 + 1];
    float p3 = zv.x * Wal[f0] + zv.y * Wal[f0 + 1];
    float p4 = zv.x * Wn[f0]  + zv.y * Wn[f0 + 1];
    float p5 = zv.x * Wt[f0]  + zv.y * Wt[f0 + 1];
#pragma unroll
    for (int d = 1; d < 64; d <<= 1) {
        p0 += __shfl_xor(p0, d); p1 += __shfl_xor(p1, d); p2 += __shfl_xor(p2, d);
        p3 += __shfl_xor(p3, d); p4 += __shfl_xor(p4, d); p5 += __shfl_xor(p5, d);
    }
    if (lane == 0) {
        logits[(size_t)v * 2 + 0] = p0 + ba[0];
        logits[(size_t)v * 2 + 1] = p1 + ba[1];
        float gamma = 5.f / (1.f + __expf(-(p2 + bg[0])));
        float alpha = 2.f / (1.f + __expf(-(p3 + bal[0])));
        float noise = 1.f / (1.f + __expf(-(p4 + bn[0])));
        float theta = tanhf(p5 + bt[0]) * 3.14159265358979323846f;
        spawn[(size_t)v * 4 + 0] = gamma;
        spawn[(size_t)v * 4 + 1] = alpha;
        spawn[(size_t)v * 4 + 2] = noise;
        spawn[(size_t)v * 4 + 3] = theta;
    }
}

extern "C" void kernel_launch(void* const* d_in, const int* in_sizes, int n_in,
                              void* d_out, int out_size, void* d_ws, size_t ws_size,
                              hipStream_t stream) {
    const float* node_feats = (const float*)d_in[0];
    const int*   src  = (const int*)d_in[1];
    const int*   dst  = (const int*)d_in[2];
    const float* W_in = (const float*)d_in[3];
    const float* b_in = (const float*)d_in[4];
    const float* W_src = (const float*)d_in[5];
    const float* b_src = (const float*)d_in[6];
    const float* W_dst = (const float*)d_in[7];
    const float* b_dst = (const float*)d_in[8];
    const float* attn  = (const float*)d_in[9];
    const float* ln_g  = (const float*)d_in[10];
    const float* ln_b  = (const float*)d_in[11];
    const float* W1 = (const float*)d_in[12]; const float* b1 = (const float*)d_in[13];
    const float* W2 = (const float*)d_in[14]; const float* b2 = (const float*)d_in[15];
    const float* Wa = (const float*)d_in[16]; const float* ba = (const float*)d_in[17];
    const float* Wg = (const float*)d_in[18]; const float* bg = (const float*)d_in[19];
    const float* Wal = (const float*)d_in[20]; const float* bal = (const float*)d_in[21];
    const float* Wn = (const float*)d_in[22]; const float* bn = (const float*)d_in[23];
    const float* Wt = (const float*)d_in[24]; const float* bt = (const float*)d_in[25];

    const int n = in_sizes[0] / 32;  // 50000
    const int E = in_sizes[1];       // 1600000
    const int P = (n + 511) / 512;   // scan partial blocks

    char* ws = (char*)d_ws;
    size_t off = 0;
    auto alloc = [&](size_t bytes) -> void* {
        void* p = ws + off;
        off = (off + bytes + 255) & ~(size_t)255;
        return p;
    };
    float* B0 = (float*)alloc((size_t)n * 128 * 4);
    float* B1 = (float*)alloc((size_t)n * 128 * 4);
    float* B2 = (float*)alloc((size_t)n * 128 * 4);
    float* B3 = (float*)alloc((size_t)n * 128 * 4);
    int* deg  = (int*)alloc((size_t)n * 4);
    int* offs = (int*)alloc((size_t)(n + 1) * 4);
    int* woff = (int*)alloc((size_t)n * 4);
    int* csr  = (int*)alloc((size_t)E * 4);
    int* bsum = (int*)alloc((size_t)P * 4);
    int* bpre = (int*)alloc((size_t)P * 4);
    float* gacc = (float*)alloc(128 * 4);

    float* out = (float*)d_out;
    float* out_gemb   = out;                     // 128
    float* out_nemb   = out + 128;               // n*128
    float* out_logits = out + 128 + (size_t)n * 128;
    float* out_spawn  = out_logits + (size_t)n * 2;

    hipMemsetAsync(deg, 0, (size_t)n * 4, stream);
    hipMemsetAsync(gacc, 0, 128 * 4, stream);

    count_deg<<<(E + 255) / 256, 256, 0, stream>>>(dst, deg, E);
    block_sums<<<P, 512, 0, stream>>>(deg, bsum, n);
    scan_partials<<<1, 128, 0, stream>>>(bsum, bpre, P);
    scan_blocks<<<P, 512, 0, stream>>>(deg, bpre, offs, woff, n);
    fill_csr<<<(E + 255) / 256, 256, 0, stream>>>(src, dst, woff, csr, E);

    int gemm_grid = (n + GR - 1) / GR;

    gemm_k<32, false><<<gemm_grid, 256, 0, stream>>>(node_feats, W_in, b_in, B0, n);

    const float* cur = B0;
    float* HS[3] = {B1, B0, B0};
    float* HD[3] = {B2, B1, B1};
    float* HO[3] = {B3, B2, B3};
    for (int l = 0; l < 3; ++l) {
        gemm_k<128, false><<<gemm_grid, 256, 0, stream>>>(cur, W_src + (size_t)l * 128 * 128,
                                                          b_src + l * 128, HS[l], n);
        gemm_k<128, false><<<gemm_grid, 256, 0, stream>>>(cur, W_dst + (size_t)l * 128 * 128,
                                                          b_dst + l * 128, HD[l], n);
        gat_aggregate<<<(n + 3) / 4, 256, 0, stream>>>(cur, HS[l], HD[l], offs, csr,
                                                       attn + l * 128, ln_g + l * 128,
                                                       ln_b + l * 128, HO[l], n);
        cur = HO[l];
    }

    gemm_k<128, true><<<gemm_grid, 256, 0, stream>>>(cur, W1, b1, B0, n);   // z1
    gemm_k<128, true><<<gemm_grid, 256, 0, stream>>>(B0, W2, b2, B1, n);    // z

    copy_f4<<<1024, 256, 0, stream>>>((const float4*)cur, (float4*)out_nemb, (size_t)n * 32);
    graph_mean_partial<<<128, 256, 0, stream>>>(cur, gacc, n);
    graph_mean_final<<<1, 128, 0, stream>>>(gacc, out_gemb, n);
    heads_kernel<<<(n + 3) / 4, 256, 0, stream>>>(B1, Wa, ba, Wg, bg, Wal, bal,
                                                  Wn, bn, Wt, bt, out_logits, out_spawn, n);
}

// Round 3
// 836.233 us; speedup vs baseline: 1.5305x; 1.1550x over previous
//
#include <hip/hip_runtime.h>
#include <hip/hip_bf16.h>

#define HID 128
#define NHEAD 4

// ---------------- CSR build ----------------
__global__ void count_deg(const int* __restrict__ dst, int* __restrict__ deg, int E) {
    int i = blockIdx.x * blockDim.x + threadIdx.x;
    if (i < E) atomicAdd(&deg[dst[i]], 1);
}

__global__ void block_sums(const int* __restrict__ deg, int* __restrict__ bsum, int n) {
    __shared__ int sbuf[512];
    int tid = threadIdx.x;
    int i = blockIdx.x * 512 + tid;
    sbuf[tid] = (i < n) ? deg[i] : 0;
    __syncthreads();
    for (int d = 256; d > 0; d >>= 1) {
        if (tid < d) sbuf[tid] += sbuf[tid + d];
        __syncthreads();
    }
    if (tid == 0) bsum[blockIdx.x] = sbuf[0];
}

__global__ void scan_partials(const int* __restrict__ bsum, int* __restrict__ bpre, int P) {
    __shared__ int buf[128];
    int tid = threadIdx.x; // 128 threads, P <= 128
    int v = (tid < P) ? bsum[tid] : 0;
    buf[tid] = v;
    __syncthreads();
    for (int d = 1; d < 128; d <<= 1) {
        int t = (tid >= d) ? buf[tid - d] : 0;
        __syncthreads();
        buf[tid] += t;
        __syncthreads();
    }
    if (tid < P) bpre[tid] = buf[tid] - v; // exclusive
}

__global__ void scan_blocks(const int* __restrict__ deg, const int* __restrict__ bpre,
                            int* __restrict__ offs, int* __restrict__ woff, int n) {
    __shared__ int sbuf[512];
    int tid = threadIdx.x;
    int i = blockIdx.x * 512 + tid;
    int v = (i < n) ? deg[i] : 0;
    sbuf[tid] = v;
    __syncthreads();
    for (int d = 1; d < 512; d <<= 1) {
        int t = (tid >= d) ? sbuf[tid - d] : 0;
        __syncthreads();
        sbuf[tid] += t;
        __syncthreads();
    }
    if (i < n) {
        int incl = bpre[blockIdx.x] + sbuf[tid];
        offs[i + 1] = incl;
        woff[i] = incl - v;
    }
    if (i == 0) offs[0] = 0;
}

__global__ void fill_csr(const int* __restrict__ src, const int* __restrict__ dst,
                         int* __restrict__ woff, int* __restrict__ csr_src, int E) {
    int i = blockIdx.x * blockDim.x + threadIdx.x;
    if (i < E) {
        int pos = atomicAdd(&woff[dst[i]], 1);
        csr_src[pos] = src[i];
    }
}

// ---------------- helpers ----------------
__device__ __forceinline__ unsigned pack2_bf16_rne(float lo, float hi) {
    unsigned a = __float_as_uint(lo);
    a = (a + 0x7fffu + ((a >> 16) & 1u)) >> 16;
    unsigned b = __float_as_uint(hi);
    b = (b + 0x7fffu + ((b >> 16) & 1u)) & 0xffff0000u;
    return a | b;
}

// ---------------- GEMM: C[n,128] = act(A[n,K] @ W[K,128] + b) ----------------
// 64 rows x 128 cols per block, 256 threads, each thread 8 rows x 4 cols.
#define GR 64
template <int K, bool RELU, bool BF16OUT>
__global__ __launch_bounds__(256) void gemm_k(const float* __restrict__ A,
                                              const float* __restrict__ W,
                                              const float* __restrict__ bias,
                                              void* __restrict__ Cout, int n) {
    __shared__ __align__(16) float a_sh[GR * K];
    const int tid = threadIdx.x;
    const int tx = tid & 31;  // cols tx*4 .. tx*4+3
    const int ty = tid >> 5;  // rows ty*8 .. ty*8+7
    const int r0 = blockIdx.x * GR;

    for (int i = tid * 4; i < GR * K; i += 1024) {
        int r = i / K, k = i % K;
        int gr = r0 + r;
        float4 v = make_float4(0.f, 0.f, 0.f, 0.f);
        if (gr < n) v = *(const float4*)&A[(size_t)gr * K + k];
        *(float4*)&a_sh[i] = v;
    }
    __syncthreads();

    float4 acc[8];
#pragma unroll
    for (int r = 0; r < 8; ++r) acc[r] = make_float4(0.f, 0.f, 0.f, 0.f);

    const float* ab = &a_sh[ty * 8 * K];
    const float* wb = &W[tx * 4];

    for (int k = 0; k < K; k += 4) {
        float4 w0 = *(const float4*)&wb[(size_t)(k + 0) * 128];
        float4 w1 = *(const float4*)&wb[(size_t)(k + 1) * 128];
        float4 w2 = *(const float4*)&wb[(size_t)(k + 2) * 128];
        float4 w3 = *(const float4*)&wb[(size_t)(k + 3) * 128];
#pragma unroll
        for (int r = 0; r < 8; ++r) {
            float4 a4 = *(const float4*)&ab[r * K + k];
            acc[r].x = fmaf(a4.x, w0.x, acc[r].x);
            acc[r].y = fmaf(a4.x, w0.y, acc[r].y);
            acc[r].z = fmaf(a4.x, w0.z, acc[r].z);
            acc[r].w = fmaf(a4.x, w0.w, acc[r].w);
            acc[r].x = fmaf(a4.y, w1.x, acc[r].x);
            acc[r].y = fmaf(a4.y, w1.y, acc[r].y);
            acc[r].z = fmaf(a4.y, w1.z, acc[r].z);
            acc[r].w = fmaf(a4.y, w1.w, acc[r].w);
            acc[r].x = fmaf(a4.z, w2.x, acc[r].x);
            acc[r].y = fmaf(a4.z, w2.y, acc[r].y);
            acc[r].z = fmaf(a4.z, w2.z, acc[r].z);
            acc[r].w = fmaf(a4.z, w2.w, acc[r].w);
            acc[r].x = fmaf(a4.w, w3.x, acc[r].x);
            acc[r].y = fmaf(a4.w, w3.y, acc[r].y);
            acc[r].z = fmaf(a4.w, w3.z, acc[r].z);
            acc[r].w = fmaf(a4.w, w3.w, acc[r].w);
        }
    }

    float4 b4 = *(const float4*)&bias[tx * 4];
#pragma unroll
    for (int r = 0; r < 8; ++r) {
        int gr = r0 + ty * 8 + r;
        if (gr < n) {
            float4 o;
            o.x = acc[r].x + b4.x;
            o.y = acc[r].y + b4.y;
            o.z = acc[r].z + b4.z;
            o.w = acc[r].w + b4.w;
            if (RELU) {
                o.x = fmaxf(o.x, 0.f); o.y = fmaxf(o.y, 0.f);
                o.z = fmaxf(o.z, 0.f); o.w = fmaxf(o.w, 0.f);
            }
            if (BF16OUT) {
                unsigned short* C16 = (unsigned short*)Cout;
                uint2 st;
                st.x = pack2_bf16_rne(o.x, o.y);
                st.y = pack2_bf16_rne(o.z, o.w);
                *(uint2*)&C16[(size_t)gr * 128 + tx * 4] = st;
            } else {
                float* C = (float*)Cout;
                *(float4*)&C[(size_t)gr * 128 + tx * 4] = o;
            }
        }
    }
}

// ---------------- fused GATv2 aggregate + residuals + LayerNorm + ReLU ----------------
// one wave per node; lane holds features f0=2*lane, f0+1; 16-lane head groups.
// hs is bf16-packed [n,128] (gather = 256B/edge); 4-way unrolled, 4 softmax states.
__global__ __launch_bounds__(256) void gat_aggregate(
    const float* __restrict__ h,        // [n,128] layer input (f32)
    const unsigned short* __restrict__ hs16, // [n,128] feat_src (bf16)
    const float* __restrict__ hd,       // [n,128] feat_dst (f32)
    const int* __restrict__ offs,       // [n+1]
    const int* __restrict__ csr_src,    // [E]
    const float* __restrict__ attn,     // [128] this layer
    const float* __restrict__ ln_g, const float* __restrict__ ln_b,
    float* __restrict__ h_out, int n) {
    int v = (blockIdx.x * blockDim.x + threadIdx.x) >> 6;
    int lane = threadIdx.x & 63;
    if (v >= n) return;
    const unsigned fb = (unsigned)lane << 2;  // byte offset within bf16 row (256B rows)
    int f0 = lane * 2;

    float a0 = attn[f0], a1 = attn[f0 + 1];
    float2 hdv = *(const float2*)&hd[(size_t)v * 128 + f0];

    const char* hsb = (const char*)hs16;
    unsigned uv = *(const unsigned*)(hsb + ((size_t)(unsigned)v << 8) + fb);
    float svx = __uint_as_float(uv << 16);
    float svy = __uint_as_float(uv & 0xffff0000u);

    // self-loop score -> reference max
    float t0 = svx + hdv.x; t0 = fmaxf(t0, 0.2f * t0);
    float t1 = svy + hdv.y; t1 = fmaxf(t1, 0.2f * t1);
    float p = t0 * a0 + t1 * a1;
    p += __shfl_xor(p, 1); p += __shfl_xor(p, 2);
    p += __shfl_xor(p, 4); p += __shfl_xor(p, 8);

    float m0 = p, s0 = 1.0f, ax0 = svx, ay0 = svy;
    float m1 = p, s1 = 0.0f, ax1 = 0.f, ay1 = 0.f;
    float m2 = p, s2 = 0.0f, ax2 = 0.f, ay2 = 0.f;
    float m3 = p, s3 = 0.0f, ax3 = 0.f, ay3 = 0.f;

    int beg = offs[v], end = offs[v + 1];
    int i = beg;
    int end4 = beg + ((end - beg) & ~3);
    for (; i < end4; i += 4) {
        int u0 = csr_src[i], u1 = csr_src[i + 1], u2 = csr_src[i + 2], u3 = csr_src[i + 3];
        unsigned w0 = *(const unsigned*)(hsb + ((size_t)(unsigned)u0 << 8) + fb);
        unsigned w1 = *(const unsigned*)(hsb + ((size_t)(unsigned)u1 << 8) + fb);
        unsigned w2 = *(const unsigned*)(hsb + ((size_t)(unsigned)u2 << 8) + fb);
        unsigned w3 = *(const unsigned*)(hsb + ((size_t)(unsigned)u3 << 8) + fb);
        float h0x = __uint_as_float(w0 << 16), h0y = __uint_as_float(w0 & 0xffff0000u);
        float h1x = __uint_as_float(w1 << 16), h1y = __uint_as_float(w1 & 0xffff0000u);
        float h2x = __uint_as_float(w2 << 16), h2y = __uint_as_float(w2 & 0xffff0000u);
        float h3x = __uint_as_float(w3 << 16), h3y = __uint_as_float(w3 & 0xffff0000u);
        float q0x = h0x + hdv.x; q0x = fmaxf(q0x, 0.2f * q0x);
        float q0y = h0y + hdv.y; q0y = fmaxf(q0y, 0.2f * q0y);
        float q1x = h1x + hdv.x; q1x = fmaxf(q1x, 0.2f * q1x);
        float q1y = h1y + hdv.y; q1y = fmaxf(q1y, 0.2f * q1y);
        float q2x = h2x + hdv.x; q2x = fmaxf(q2x, 0.2f * q2x);
        float q2y = h2y + hdv.y; q2y = fmaxf(q2y, 0.2f * q2y);
        float q3x = h3x + hdv.x; q3x = fmaxf(q3x, 0.2f * q3x);
        float q3y = h3y + hdv.y; q3y = fmaxf(q3y, 0.2f * q3y);
        float sc0 = fmaf(q0y, a1, q0x * a0);
        float sc1 = fmaf(q1y, a1, q1x * a0);
        float sc2 = fmaf(q2y, a1, q2x * a0);
        float sc3 = fmaf(q3y, a1, q3x * a0);
        sc0 += __shfl_xor(sc0, 1); sc1 += __shfl_xor(sc1, 1);
        sc2 += __shfl_xor(sc2, 1); sc3 += __shfl_xor(sc3, 1);
        sc0 += __shfl_xor(sc0, 2); sc1 += __shfl_xor(sc1, 2);
        sc2 += __shfl_xor(sc2, 2); sc3 += __shfl_xor(sc3, 2);
        sc0 += __shfl_xor(sc0, 4); sc1 += __shfl_xor(sc1, 4);
        sc2 += __shfl_xor(sc2, 4); sc3 += __shfl_xor(sc3, 4);
        sc0 += __shfl_xor(sc0, 8); sc1 += __shfl_xor(sc1, 8);
        sc2 += __shfl_xor(sc2, 8); sc3 += __shfl_xor(sc3, 8);
        float d0 = sc0 - m0, d1 = sc1 - m1, d2 = sc2 - m2, d3 = sc3 - m3;
        float dm = fmaxf(fmaxf(d0, d1), fmaxf(d2, d3));
        if (__builtin_expect(__any(dm > 8.f), 0)) {
            // rescale states whose max grew
            float mn0 = fmaxf(m0, sc0), r0 = __expf(m0 - mn0), e0 = __expf(sc0 - mn0);
            s0 = fmaf(s0, r0, e0); ax0 = fmaf(ax0, r0, e0 * h0x); ay0 = fmaf(ay0, r0, e0 * h0y); m0 = mn0;
            float mn1 = fmaxf(m1, sc1), r1 = __expf(m1 - mn1), e1 = __expf(sc1 - mn1);
            s1 = fmaf(s1, r1, e1); ax1 = fmaf(ax1, r1, e1 * h1x); ay1 = fmaf(ay1, r1, e1 * h1y); m1 = mn1;
            float mn2 = fmaxf(m2, sc2), r2 = __expf(m2 - mn2), e2 = __expf(sc2 - mn2);
            s2 = fmaf(s2, r2, e2); ax2 = fmaf(ax2, r2, e2 * h2x); ay2 = fmaf(ay2, r2, e2 * h2y); m2 = mn2;
            float mn3 = fmaxf(m3, sc3), r3 = __expf(m3 - mn3), e3 = __expf(sc3 - mn3);
            s3 = fmaf(s3, r3, e3); ax3 = fmaf(ax3, r3, e3 * h3x); ay3 = fmaf(ay3, r3, e3 * h3y); m3 = mn3;
        } else {
            float e0 = __expf(d0), e1 = __expf(d1), e2 = __expf(d2), e3 = __expf(d3);
            s0 += e0; ax0 = fmaf(e0, h0x, ax0); ay0 = fmaf(e0, h0y, ay0);
            s1 += e1; ax1 = fmaf(e1, h1x, ax1); ay1 = fmaf(e1, h1y, ay1);
            s2 += e2; ax2 = fmaf(e2, h2x, ax2); ay2 = fmaf(e2, h2y, ay2);
            s3 += e3; ax3 = fmaf(e3, h3x, ax3); ay3 = fmaf(e3, h3y, ay3);
        }
    }
    for (; i < end; ++i) { // tail -> state0
        int u0 = csr_src[i];
        unsigned w0 = *(const unsigned*)(hsb + ((size_t)(unsigned)u0 << 8) + fb);
        float h0x = __uint_as_float(w0 << 16), h0y = __uint_as_float(w0 & 0xffff0000u);
        float q0x = h0x + hdv.x; q0x = fmaxf(q0x, 0.2f * q0x);
        float q0y = h0y + hdv.y; q0y = fmaxf(q0y, 0.2f * q0y);
        float sc0 = fmaf(q0y, a1, q0x * a0);
        sc0 += __shfl_xor(sc0, 1); sc0 += __shfl_xor(sc0, 2);
        sc0 += __shfl_xor(sc0, 4); sc0 += __shfl_xor(sc0, 8);
        float d0 = sc0 - m0;
        if (__builtin_expect(__any(d0 > 8.f), 0)) {
            float mn0 = fmaxf(m0, sc0), r0 = __expf(m0 - mn0), e0 = __expf(sc0 - mn0);
            s0 = fmaf(s0, r0, e0); ax0 = fmaf(ax0, r0, e0 * h0x); ay0 = fmaf(ay0, r0, e0 * h0y); m0 = mn0;
        } else {
            float e0 = __expf(d0);
            s0 += e0; ax0 = fmaf(e0, h0x, ax0); ay0 = fmaf(e0, h0y, ay0);
        }
    }
    // merge 4 states (tree)
    {
        float mn = fmaxf(m0, m1), e0 = __expf(m0 - mn), e1 = __expf(m1 - mn);
        s0 = s0 * e0 + s1 * e1; ax0 = ax0 * e0 + ax1 * e1; ay0 = ay0 * e0 + ay1 * e1; m0 = mn;
        float mn2 = fmaxf(m2, m3), e2 = __expf(m2 - mn2), e3 = __expf(m3 - mn2);
        s2 = s2 * e2 + s3 * e3; ax2 = ax2 * e2 + ax3 * e3; ay2 = ay2 * e2 + ay3 * e3; m2 = mn2;
        float mnf = fmaxf(m0, m2), f0e = __expf(m0 - mnf), f2e = __expf(m2 - mnf);
        s0 = s0 * f0e + s2 * f2e; ax0 = ax0 * f0e + ax2 * f2e; ay0 = ay0 * f0e + ay2 * f2e;
    }
    float inv = 1.0f / (s0 + 1e-9f);

    float2 hv = *(const float2*)&h[(size_t)v * 128 + f0];
    float x0 = fmaf(ax0, inv, 2.f * hv.x);
    float x1 = fmaf(ay0, inv, 2.f * hv.y);

    // LayerNorm over 128 features
    float sum = x0 + x1, sq = x0 * x0 + x1 * x1;
#pragma unroll
    for (int d = 1; d < 64; d <<= 1) { sum += __shfl_xor(sum, d); sq += __shfl_xor(sq, d); }
    float mu = sum * (1.f / 128.f);
    float var = sq * (1.f / 128.f) - mu * mu;
    float rstd = rsqrtf(var + 1e-5f);
    float y0 = (x0 - mu) * rstd * ln_g[f0]     + ln_b[f0];
    float y1 = (x1 - mu) * rstd * ln_g[f0 + 1] + ln_b[f0 + 1];
    y0 = fmaxf(y0, 0.f); y1 = fmaxf(y1, 0.f);
    *(float2*)&h_out[(size_t)v * 128 + f0] = make_float2(y0, y1);
}

// ---------------- epilogue ----------------
__global__ void copy_f4(const float4* __restrict__ src, float4* __restrict__ dst, size_t n4) {
    size_t i = blockIdx.x * (size_t)blockDim.x + threadIdx.x;
    size_t stride = (size_t)gridDim.x * blockDim.x;
    for (; i < n4; i += stride) dst[i] = src[i];
}

__global__ void graph_mean_partial(const float* __restrict__ h, float* __restrict__ gacc, int n) {
    int tid = threadIdx.x; // 256
    size_t gid = blockIdx.x * 256 + tid;
    size_t stride = (size_t)gridDim.x * 256; // multiple of 128
    float p = 0.f;
    size_t tot = (size_t)n * 128;
    for (size_t i = gid; i < tot; i += stride) p += h[i];
    __shared__ float sbuf[256];
    sbuf[tid] = p;
    __syncthreads();
    if (tid < 128) {
        atomicAdd(&gacc[tid], sbuf[tid] + sbuf[tid + 128]);
    }
}

__global__ void graph_mean_final(const float* __restrict__ gacc, float* __restrict__ out, int n) {
    int c = threadIdx.x; // 128
    out[c] = gacc[c] / (float)n;
}

__global__ __launch_bounds__(256) void heads_kernel(
    const float* __restrict__ z,
    const float* __restrict__ Wa, const float* __restrict__ ba,
    const float* __restrict__ Wg, const float* __restrict__ bg,
    const float* __restrict__ Wal, const float* __restrict__ bal,
    const float* __restrict__ Wn, const float* __restrict__ bn,
    const float* __restrict__ Wt, const float* __restrict__ bt,
    float* __restrict__ logits, float* __restrict__ spawn, int n) {
    int v = (blockIdx.x * blockDim.x + threadIdx.x) >> 6;
    int lane = threadIdx.x & 63;
    if (v >= n) return;
    int f0 = lane * 2;
    float2 zv = *(const float2*)&z[(size_t)v * 128 + f0];
    float p0 = zv.x * Wa[f0 * 2]     + zv.y * Wa[(f0 + 1) * 2];
    float p1 = zv.x * Wa[f0 * 2 + 1] + zv.y * Wa[(f0 + 1) * 2 + 1];
    float p2 = zv.x * Wg[f0]  + zv.y * Wg[f0 + 1];
    float p3 = zv.x * Wal[f0] + zv.y * Wal[f0 + 1];
    float p4 = zv.x * Wn[f0]  + zv.y * Wn[f0 + 1];
    float p5 = zv.x * Wt[f0]  + zv.y * Wt[f0 + 1];
#pragma unroll
    for (int d = 1; d < 64; d <<= 1) {
        p0 += __shfl_xor(p0, d); p1 += __shfl_xor(p1, d); p2 += __shfl_xor(p2, d);
        p3 += __shfl_xor(p3, d); p4 += __shfl_xor(p4, d); p5 += __shfl_xor(p5, d);
    }
    if (lane == 0) {
        logits[(size_t)v * 2 + 0] = p0 + ba[0];
        logits[(size_t)v * 2 + 1] = p1 + ba[1];
        float gamma = 5.f / (1.f + __expf(-(p2 + bg[0])));
        float alpha = 2.f / (1.f + __expf(-(p3 + bal[0])));
        float noise = 1.f / (1.f + __expf(-(p4 + bn[0])));
        float theta = tanhf(p5 + bt[0]) * 3.14159265358979323846f;
        spawn[(size_t)v * 4 + 0] = gamma;
        spawn[(size_t)v * 4 + 1] = alpha;
        spawn[(size_t)v * 4 + 2] = noise;
        spawn[(size_t)v * 4 + 3] = theta;
    }
}

extern "C" void kernel_launch(void* const* d_in, const int* in_sizes, int n_in,
                              void* d_out, int out_size, void* d_ws, size_t ws_size,
                              hipStream_t stream) {
    const float* node_feats = (const float*)d_in[0];
    const int*   src  = (const int*)d_in[1];
    const int*   dst  = (const int*)d_in[2];
    const float* W_in = (const float*)d_in[3];
    const float* b_in = (const float*)d_in[4];
    const float* W_src = (const float*)d_in[5];
    const float* b_src = (const float*)d_in[6];
    const float* W_dst = (const float*)d_in[7];
    const float* b_dst = (const float*)d_in[8];
    const float* attn  = (const float*)d_in[9];
    const float* ln_g  = (const float*)d_in[10];
    const float* ln_b  = (const float*)d_in[11];
    const float* W1 = (const float*)d_in[12]; const float* b1 = (const float*)d_in[13];
    const float* W2 = (const float*)d_in[14]; const float* b2 = (const float*)d_in[15];
    const float* Wa = (const float*)d_in[16]; const float* ba = (const float*)d_in[17];
    const float* Wg = (const float*)d_in[18]; const float* bg = (const float*)d_in[19];
    const float* Wal = (const float*)d_in[20]; const float* bal = (const float*)d_in[21];
    const float* Wn = (const float*)d_in[22]; const float* bn = (const float*)d_in[23];
    const float* Wt = (const float*)d_in[24]; const float* bt = (const float*)d_in[25];

    const int n = in_sizes[0] / 32;  // 50000
    const int E = in_sizes[1];       // 1600000
    const int P = (n + 511) / 512;

    char* ws = (char*)d_ws;
    size_t off = 0;
    auto alloc = [&](size_t bytes) -> void* {
        void* p = ws + off;
        off = (off + bytes + 255) & ~(size_t)255;
        return p;
    };
    float* Bh0 = (float*)alloc((size_t)n * 128 * 4);
    float* Bh1 = (float*)alloc((size_t)n * 128 * 4);
    float* Bhd = (float*)alloc((size_t)n * 128 * 4);
    float* Bz  = (float*)alloc((size_t)n * 128 * 4);
    unsigned short* hs16 = (unsigned short*)alloc((size_t)n * 128 * 2);
    int* deg  = (int*)alloc((size_t)n * 4);
    int* offs = (int*)alloc((size_t)(n + 1) * 4);
    int* woff = (int*)alloc((size_t)n * 4);
    int* csr  = (int*)alloc((size_t)E * 4);
    int* bsum = (int*)alloc((size_t)P * 4);
    int* bpre = (int*)alloc((size_t)P * 4);
    float* gacc = (float*)alloc(128 * 4);

    float* out = (float*)d_out;
    float* out_gemb   = out;
    float* out_nemb   = out + 128;
    float* out_logits = out + 128 + (size_t)n * 128;
    float* out_spawn  = out_logits + (size_t)n * 2;

    hipMemsetAsync(deg, 0, (size_t)n * 4, stream);
    hipMemsetAsync(gacc, 0, 128 * 4, stream);

    count_deg<<<(E + 255) / 256, 256, 0, stream>>>(dst, deg, E);
    block_sums<<<P, 512, 0, stream>>>(deg, bsum, n);
    scan_partials<<<1, 128, 0, stream>>>(bsum, bpre, P);
    scan_blocks<<<P, 512, 0, stream>>>(deg, bpre, offs, woff, n);
    fill_csr<<<(E + 255) / 256, 256, 0, stream>>>(src, dst, woff, csr, E);

    int gemm_grid = (n + GR - 1) / GR;

    gemm_k<32, false, false><<<gemm_grid, 256, 0, stream>>>(node_feats, W_in, b_in, Bh0, n);

    float* cur = Bh0;
    float* nxt = Bh1;
    for (int l = 0; l < 3; ++l) {
        gemm_k<128, false, true><<<gemm_grid, 256, 0, stream>>>(cur, W_src + (size_t)l * 128 * 128,
                                                                b_src + l * 128, hs16, n);
        gemm_k<128, false, false><<<gemm_grid, 256, 0, stream>>>(cur, W_dst + (size_t)l * 128 * 128,
                                                                 b_dst + l * 128, Bhd, n);
        gat_aggregate<<<(n + 3) / 4, 256, 0, stream>>>(cur, hs16, Bhd, offs, csr,
                                                       attn + l * 128, ln_g + l * 128,
                                                       ln_b + l * 128, nxt, n);
        float* t = cur; cur = nxt; nxt = t;
    }
    // cur = final node embedding

    gemm_k<128, true, false><<<gemm_grid, 256, 0, stream>>>(cur, W1, b1, Bhd, n); // z1
    gemm_k<128, true, false><<<gemm_grid, 256, 0, stream>>>(Bhd, W2, b2, Bz, n);  // z

    copy_f4<<<1024, 256, 0, stream>>>((const float4*)cur, (float4*)out_nemb, (size_t)n * 32);
    graph_mean_partial<<<512, 256, 0, stream>>>(cur, gacc, n);
    graph_mean_final<<<1, 128, 0, stream>>>(gacc, out_gemb, n);
    heads_kernel<<<(n + 3) / 4, 256, 0, stream>>>(Bz, Wa, ba, Wg, bg, Wal, bal,
                                                  Wn, bn, Wt, bt, out_logits, out_spawn, n);
}

// Round 4
// 762.335 us; speedup vs baseline: 1.6789x; 1.0969x over previous
//
#include <hip/hip_runtime.h>
#include <hip/hip_bf16.h>

#define HID 128
#define NHEAD 4

typedef __attribute__((ext_vector_type(8))) short bf16x8;
typedef __attribute__((ext_vector_type(4))) float f32x4;

// ---------------- CSR build ----------------
__global__ void count_deg(const int* __restrict__ dst, int* __restrict__ deg, int E) {
    int i = blockIdx.x * blockDim.x + threadIdx.x;
    if (i < E) atomicAdd(&deg[dst[i]], 1);
}

__global__ void block_sums(const int* __restrict__ deg, int* __restrict__ bsum, int n) {
    __shared__ int sbuf[512];
    int tid = threadIdx.x;
    int i = blockIdx.x * 512 + tid;
    sbuf[tid] = (i < n) ? deg[i] : 0;
    __syncthreads();
    for (int d = 256; d > 0; d >>= 1) {
        if (tid < d) sbuf[tid] += sbuf[tid + d];
        __syncthreads();
    }
    if (tid == 0) bsum[blockIdx.x] = sbuf[0];
}

__global__ void scan_partials(const int* __restrict__ bsum, int* __restrict__ bpre, int P) {
    __shared__ int buf[128];
    int tid = threadIdx.x; // 128 threads, P <= 128
    int v = (tid < P) ? bsum[tid] : 0;
    buf[tid] = v;
    __syncthreads();
    for (int d = 1; d < 128; d <<= 1) {
        int t = (tid >= d) ? buf[tid - d] : 0;
        __syncthreads();
        buf[tid] += t;
        __syncthreads();
    }
    if (tid < P) bpre[tid] = buf[tid] - v; // exclusive
}

__global__ void scan_blocks(const int* __restrict__ deg, const int* __restrict__ bpre,
                            int* __restrict__ offs, int* __restrict__ woff, int n) {
    __shared__ int sbuf[512];
    int tid = threadIdx.x;
    int i = blockIdx.x * 512 + tid;
    int v = (i < n) ? deg[i] : 0;
    sbuf[tid] = v;
    __syncthreads();
    for (int d = 1; d < 512; d <<= 1) {
        int t = (tid >= d) ? sbuf[tid - d] : 0;
        __syncthreads();
        sbuf[tid] += t;
        __syncthreads();
    }
    if (i < n) {
        int incl = bpre[blockIdx.x] + sbuf[tid];
        offs[i + 1] = incl;
        woff[i] = incl - v;
    }
    if (i == 0) offs[0] = 0;
}

// XCD-partitioned scatter: group g (blockIdx&7) handles dst in [lo,hi) only, so
// all writes to a given CSR cacheline come from one XCD -> full-line writeback.
__global__ __launch_bounds__(256) void fill_csr_xcd(
    const int* __restrict__ src, const int* __restrict__ dst,
    int* __restrict__ woff, int* __restrict__ csr_src, int E, int n) {
    int grp = blockIdx.x & 7;
    int blk = blockIdx.x >> 3;
    int nblk = gridDim.x >> 3;
    int lo = (int)(((long long)n * grp) >> 3);
    int hi = (int)(((long long)n * (grp + 1)) >> 3);
    for (int i = blk * 256 + threadIdx.x; i < E; i += nblk * 256) {
        int d = dst[i];
        if (d >= lo && d < hi) {
            int pos = atomicAdd(&woff[d], 1);
            csr_src[pos] = src[i];
        }
    }
}

// ---------------- helpers ----------------
__device__ __forceinline__ unsigned pack2_bf16_rne(float lo, float hi) {
    unsigned a = __float_as_uint(lo);
    a = (a + 0x7fffu + ((a >> 16) & 1u)) >> 16;
    unsigned b = __float_as_uint(hi);
    b = (b + 0x7fffu + ((b >> 16) & 1u)) & 0xffff0000u;
    return a | b;
}

__device__ __forceinline__ unsigned short bf16_rne(float x) {
    unsigned u = __float_as_uint(x);
    u = (u + 0x7fffu + ((u >> 16) & 1u)) >> 16;
    return (unsigned short)u;
}

// Transpose+convert 8 [128,128] f32 weight mats to bf16 [N][K]
__global__ void prep_weights(const float* __restrict__ W_src, const float* __restrict__ W_dst,
                             const float* __restrict__ W1, const float* __restrict__ W2,
                             unsigned short* __restrict__ Wt) {
    int mat = blockIdx.x; // 0..7
    const float* Wf = (mat < 3) ? (W_src + (size_t)mat * 16384)
                    : (mat < 6) ? (W_dst + (size_t)(mat - 3) * 16384)
                    : (mat == 6) ? W1 : W2;
    unsigned short* out = Wt + (size_t)mat * 16384;
    for (int idx = threadIdx.x; idx < 16384; idx += blockDim.x) {
        int k = idx >> 7, nn = idx & 127;
        out[nn * 128 + k] = bf16_rne(Wf[idx]);
    }
}

// ---------------- vector GEMM (K=32 input projection) ----------------
#define GR 64
template <int K, bool RELU, bool F32OUT, bool BF16OUT>
__global__ __launch_bounds__(256) void gemm_k(const float* __restrict__ A,
                                              const float* __restrict__ W,
                                              const float* __restrict__ bias,
                                              float* __restrict__ Cf,
                                              unsigned short* __restrict__ C16, int n) {
    __shared__ __align__(16) float a_sh[GR * K];
    const int tid = threadIdx.x;
    const int tx = tid & 31;  // cols tx*4 .. tx*4+3
    const int ty = tid >> 5;  // rows ty*8 .. ty*8+7
    const int r0 = blockIdx.x * GR;

    for (int i = tid * 4; i < GR * K; i += 1024) {
        int r = i / K, k = i % K;
        int gr = r0 + r;
        float4 v = make_float4(0.f, 0.f, 0.f, 0.f);
        if (gr < n) v = *(const float4*)&A[(size_t)gr * K + k];
        *(float4*)&a_sh[i] = v;
    }
    __syncthreads();

    float4 acc[8];
#pragma unroll
    for (int r = 0; r < 8; ++r) acc[r] = make_float4(0.f, 0.f, 0.f, 0.f);

    const float* ab = &a_sh[ty * 8 * K];
    const float* wb = &W[tx * 4];

    for (int k = 0; k < K; k += 4) {
        float4 w0 = *(const float4*)&wb[(size_t)(k + 0) * 128];
        float4 w1 = *(const float4*)&wb[(size_t)(k + 1) * 128];
        float4 w2 = *(const float4*)&wb[(size_t)(k + 2) * 128];
        float4 w3 = *(const float4*)&wb[(size_t)(k + 3) * 128];
#pragma unroll
        for (int r = 0; r < 8; ++r) {
            float4 a4 = *(const float4*)&ab[r * K + k];
            acc[r].x = fmaf(a4.x, w0.x, acc[r].x);
            acc[r].y = fmaf(a4.x, w0.y, acc[r].y);
            acc[r].z = fmaf(a4.x, w0.z, acc[r].z);
            acc[r].w = fmaf(a4.x, w0.w, acc[r].w);
            acc[r].x = fmaf(a4.y, w1.x, acc[r].x);
            acc[r].y = fmaf(a4.y, w1.y, acc[r].y);
            acc[r].z = fmaf(a4.y, w1.z, acc[r].z);
            acc[r].w = fmaf(a4.y, w1.w, acc[r].w);
            acc[r].x = fmaf(a4.z, w2.x, acc[r].x);
            acc[r].y = fmaf(a4.z, w2.y, acc[r].y);
            acc[r].z = fmaf(a4.z, w2.z, acc[r].z);
            acc[r].w = fmaf(a4.z, w2.w, acc[r].w);
            acc[r].x = fmaf(a4.w, w3.x, acc[r].x);
            acc[r].y = fmaf(a4.w, w3.y, acc[r].y);
            acc[r].z = fmaf(a4.w, w3.z, acc[r].z);
            acc[r].w = fmaf(a4.w, w3.w, acc[r].w);
        }
    }

    float4 b4 = *(const float4*)&bias[tx * 4];
#pragma unroll
    for (int r = 0; r < 8; ++r) {
        int gr = r0 + ty * 8 + r;
        if (gr < n) {
            float4 o;
            o.x = acc[r].x + b4.x;
            o.y = acc[r].y + b4.y;
            o.z = acc[r].z + b4.z;
            o.w = acc[r].w + b4.w;
            if (RELU) {
                o.x = fmaxf(o.x, 0.f); o.y = fmaxf(o.y, 0.f);
                o.z = fmaxf(o.z, 0.f); o.w = fmaxf(o.w, 0.f);
            }
            if (F32OUT) *(float4*)&Cf[(size_t)gr * 128 + tx * 4] = o;
            if (BF16OUT) {
                uint2 st;
                st.x = pack2_bf16_rne(o.x, o.y);
                st.y = pack2_bf16_rne(o.z, o.w);
                *(uint2*)&C16[(size_t)gr * 128 + tx * 4] = st;
            }
        }
    }
}

// ---------------- MFMA GEMM: C[n,128] = act(A16[n,128] @ Bt16^T + b) ----------------
// Bt16 is [N=128][K=128] bf16 (pre-transposed). Block = 4 waves = 64 rows.
// Wave computes 16 rows x 128 cols via 8 col-tiles x 4 K-steps of 16x16x32 MFMA.
// A-frag: lane holds A[m0 + (l&15)][kb*32 + (l>>4)*8 + e]  (16B contiguous)
// B-frag: lane holds B[kb*32 + (l>>4)*8 + e][ct*16 + (l&15)] = Bt16 row (ct*16+(l&15))
// C/D:    reg j -> C[m0 + (l>>4)*4 + j][ct*16 + (l&15)]   (m89-verified layout)
template <bool RELU, bool F32OUT, bool BF16OUT>
__global__ __launch_bounds__(256) void gemm_mfma(
    const unsigned short* __restrict__ A16,
    const unsigned short* __restrict__ Bt16,
    const float* __restrict__ bias,
    float* __restrict__ Cf, unsigned short* __restrict__ C16, int n) {
    const int wave = threadIdx.x >> 6;
    const int lane = threadIdx.x & 63;
    const int r = lane & 15, g = lane >> 4;
    const int m0 = blockIdx.x * 64 + wave * 16;
    int ra = m0 + r; if (ra > n - 1) ra = n - 1; // clamp; rows are independent
    const bf16x8* Arow = (const bf16x8*)(A16 + (size_t)ra * 128);
    bf16x8 a0 = Arow[g];
    bf16x8 a1 = Arow[4 + g];
    bf16x8 a2 = Arow[8 + g];
    bf16x8 a3 = Arow[12 + g];
#pragma unroll
    for (int ct = 0; ct < 8; ++ct) {
        const bf16x8* Brow = (const bf16x8*)(Bt16 + (size_t)(ct * 16 + r) * 128);
        f32x4 acc = {0.f, 0.f, 0.f, 0.f};
        acc = __builtin_amdgcn_mfma_f32_16x16x32_bf16(a0, Brow[g], acc, 0, 0, 0);
        acc = __builtin_amdgcn_mfma_f32_16x16x32_bf16(a1, Brow[4 + g], acc, 0, 0, 0);
        acc = __builtin_amdgcn_mfma_f32_16x16x32_bf16(a2, Brow[8 + g], acc, 0, 0, 0);
        acc = __builtin_amdgcn_mfma_f32_16x16x32_bf16(a3, Brow[12 + g], acc, 0, 0, 0);
        const int col = ct * 16 + r;
        const float bcol = bias[col];
#pragma unroll
        for (int j = 0; j < 4; ++j) {
            int row = m0 + g * 4 + j;
            if (row < n) {
                float v = acc[j] + bcol;
                if (RELU) v = fmaxf(v, 0.f);
                if (F32OUT) Cf[(size_t)row * 128 + col] = v;
                if (BF16OUT) C16[(size_t)row * 128 + col] = bf16_rne(v);
            }
        }
    }
}

// ---------------- fused GATv2 aggregate + residuals + LayerNorm + ReLU ----------------
__global__ __launch_bounds__(256) void gat_aggregate(
    const float* __restrict__ h,             // [n,128] layer input (f32)
    const unsigned short* __restrict__ hs16, // [n,128] feat_src (bf16)
    const float* __restrict__ hd,            // [n,128] feat_dst (f32)
    const int* __restrict__ offs,
    const int* __restrict__ csr_src,
    const float* __restrict__ attn,
    const float* __restrict__ ln_g, const float* __restrict__ ln_b,
    float* __restrict__ h_out, unsigned* __restrict__ h16_out, int n) {
    int v = (blockIdx.x * blockDim.x + threadIdx.x) >> 6;
    int lane = threadIdx.x & 63;
    if (v >= n) return;
    const unsigned fb = (unsigned)lane << 2;
    int f0 = lane * 2;

    float a0 = attn[f0], a1 = attn[f0 + 1];
    float2 hdv = *(const float2*)&hd[(size_t)v * 128 + f0];

    const char* hsb = (const char*)hs16;
    unsigned uv = *(const unsigned*)(hsb + ((size_t)(unsigned)v << 8) + fb);
    float svx = __uint_as_float(uv << 16);
    float svy = __uint_as_float(uv & 0xffff0000u);

    float t0 = svx + hdv.x; t0 = fmaxf(t0, 0.2f * t0);
    float t1 = svy + hdv.y; t1 = fmaxf(t1, 0.2f * t1);
    float p = t0 * a0 + t1 * a1;
    p += __shfl_xor(p, 1); p += __shfl_xor(p, 2);
    p += __shfl_xor(p, 4); p += __shfl_xor(p, 8);

    float m0 = p, s0 = 1.0f, ax0 = svx, ay0 = svy;
    float m1 = p, s1 = 0.0f, ax1 = 0.f, ay1 = 0.f;
    float m2 = p, s2 = 0.0f, ax2 = 0.f, ay2 = 0.f;
    float m3 = p, s3 = 0.0f, ax3 = 0.f, ay3 = 0.f;

    int beg = offs[v], end = offs[v + 1];
    int i = beg;
    int end4 = beg + ((end - beg) & ~3);
    for (; i < end4; i += 4) {
        int u0 = csr_src[i], u1 = csr_src[i + 1], u2 = csr_src[i + 2], u3 = csr_src[i + 3];
        unsigned w0 = *(const unsigned*)(hsb + ((size_t)(unsigned)u0 << 8) + fb);
        unsigned w1 = *(const unsigned*)(hsb + ((size_t)(unsigned)u1 << 8) + fb);
        unsigned w2 = *(const unsigned*)(hsb + ((size_t)(unsigned)u2 << 8) + fb);
        unsigned w3 = *(const unsigned*)(hsb + ((size_t)(unsigned)u3 << 8) + fb);
        float h0x = __uint_as_float(w0 << 16), h0y = __uint_as_float(w0 & 0xffff0000u);
        float h1x = __uint_as_float(w1 << 16), h1y = __uint_as_float(w1 & 0xffff0000u);
        float h2x = __uint_as_float(w2 << 16), h2y = __uint_as_float(w2 & 0xffff0000u);
        float h3x = __uint_as_float(w3 << 16), h3y = __uint_as_float(w3 & 0xffff0000u);
        float q0x = h0x + hdv.x; q0x = fmaxf(q0x, 0.2f * q0x);
        float q0y = h0y + hdv.y; q0y = fmaxf(q0y, 0.2f * q0y);
        float q1x = h1x + hdv.x; q1x = fmaxf(q1x, 0.2f * q1x);
        float q1y = h1y + hdv.y; q1y = fmaxf(q1y, 0.2f * q1y);
        float q2x = h2x + hdv.x; q2x = fmaxf(q2x, 0.2f * q2x);
        float q2y = h2y + hdv.y; q2y = fmaxf(q2y, 0.2f * q2y);
        float q3x = h3x + hdv.x; q3x = fmaxf(q3x, 0.2f * q3x);
        float q3y = h3y + hdv.y; q3y = fmaxf(q3y, 0.2f * q3y);
        float sc0 = fmaf(q0y, a1, q0x * a0);
        float sc1 = fmaf(q1y, a1, q1x * a0);
        float sc2 = fmaf(q2y, a1, q2x * a0);
        float sc3 = fmaf(q3y, a1, q3x * a0);
        sc0 += __shfl_xor(sc0, 1); sc1 += __shfl_xor(sc1, 1);
        sc2 += __shfl_xor(sc2, 1); sc3 += __shfl_xor(sc3, 1);
        sc0 += __shfl_xor(sc0, 2); sc1 += __shfl_xor(sc1, 2);
        sc2 += __shfl_xor(sc2, 2); sc3 += __shfl_xor(sc3, 2);
        sc0 += __shfl_xor(sc0, 4); sc1 += __shfl_xor(sc1, 4);
        sc2 += __shfl_xor(sc2, 4); sc3 += __shfl_xor(sc3, 4);
        sc0 += __shfl_xor(sc0, 8); sc1 += __shfl_xor(sc1, 8);
        sc2 += __shfl_xor(sc2, 8); sc3 += __shfl_xor(sc3, 8);
        float d0 = sc0 - m0, d1 = sc1 - m1, d2 = sc2 - m2, d3 = sc3 - m3;
        float dm = fmaxf(fmaxf(d0, d1), fmaxf(d2, d3));
        if (__builtin_expect(__any(dm > 8.f), 0)) {
            float mn0 = fmaxf(m0, sc0), r0 = __expf(m0 - mn0), e0 = __expf(sc0 - mn0);
            s0 = fmaf(s0, r0, e0); ax0 = fmaf(ax0, r0, e0 * h0x); ay0 = fmaf(ay0, r0, e0 * h0y); m0 = mn0;
            float mn1 = fmaxf(m1, sc1), r1 = __expf(m1 - mn1), e1 = __expf(sc1 - mn1);
            s1 = fmaf(s1, r1, e1); ax1 = fmaf(ax1, r1, e1 * h1x); ay1 = fmaf(ay1, r1, e1 * h1y); m1 = mn1;
            float mn2 = fmaxf(m2, sc2), r2 = __expf(m2 - mn2), e2 = __expf(sc2 - mn2);
            s2 = fmaf(s2, r2, e2); ax2 = fmaf(ax2, r2, e2 * h2x); ay2 = fmaf(ay2, r2, e2 * h2y); m2 = mn2;
            float mn3 = fmaxf(m3, sc3), r3 = __expf(m3 - mn3), e3 = __expf(sc3 - mn3);
            s3 = fmaf(s3, r3, e3); ax3 = fmaf(ax3, r3, e3 * h3x); ay3 = fmaf(ay3, r3, e3 * h3y); m3 = mn3;
        } else {
            float e0 = __expf(d0), e1 = __expf(d1), e2 = __expf(d2), e3 = __expf(d3);
            s0 += e0; ax0 = fmaf(e0, h0x, ax0); ay0 = fmaf(e0, h0y, ay0);
            s1 += e1; ax1 = fmaf(e1, h1x, ax1); ay1 = fmaf(e1, h1y, ay1);
            s2 += e2; ax2 = fmaf(e2, h2x, ax2); ay2 = fmaf(e2, h2y, ay2);
            s3 += e3; ax3 = fmaf(e3, h3x, ax3); ay3 = fmaf(e3, h3y, ay3);
        }
    }
    for (; i < end; ++i) {
        int u0 = csr_src[i];
        unsigned w0 = *(const unsigned*)(hsb + ((size_t)(unsigned)u0 << 8) + fb);
        float h0x = __uint_as_float(w0 << 16), h0y = __uint_as_float(w0 & 0xffff0000u);
        float q0x = h0x + hdv.x; q0x = fmaxf(q0x, 0.2f * q0x);
        float q0y = h0y + hdv.y; q0y = fmaxf(q0y, 0.2f * q0y);
        float sc0 = fmaf(q0y, a1, q0x * a0);
        sc0 += __shfl_xor(sc0, 1); sc0 += __shfl_xor(sc0, 2);
        sc0 += __shfl_xor(sc0, 4); sc0 += __shfl_xor(sc0, 8);
        float d0 = sc0 - m0;
        if (__builtin_expect(__any(d0 > 8.f), 0)) {
            float mn0 = fmaxf(m0, sc0), r0 = __expf(m0 - mn0), e0 = __expf(sc0 - mn0);
            s0 = fmaf(s0, r0, e0); ax0 = fmaf(ax0, r0, e0 * h0x); ay0 = fmaf(ay0, r0, e0 * h0y); m0 = mn0;
        } else {
            float e0 = __expf(d0);
            s0 += e0; ax0 = fmaf(e0, h0x, ax0); ay0 = fmaf(e0, h0y, ay0);
        }
    }
    {
        float mn = fmaxf(m0, m1), e0 = __expf(m0 - mn), e1 = __expf(m1 - mn);
        s0 = s0 * e0 + s1 * e1; ax0 = ax0 * e0 + ax1 * e1; ay0 = ay0 * e0 + ay1 * e1; m0 = mn;
        float mn2 = fmaxf(m2, m3), e2 = __expf(m2 - mn2), e3 = __expf(m3 - mn2);
        s2 = s2 * e2 + s3 * e3; ax2 = ax2 * e2 + ax3 * e3; ay2 = ay2 * e2 + ay3 * e3; m2 = mn2;
        float mnf = fmaxf(m0, m2), f0e = __expf(m0 - mnf), f2e = __expf(m2 - mnf);
        s0 = s0 * f0e + s2 * f2e; ax0 = ax0 * f0e + ax2 * f2e; ay0 = ay0 * f0e + ay2 * f2e;
    }
    float inv = 1.0f / (s0 + 1e-9f);

    float2 hv = *(const float2*)&h[(size_t)v * 128 + f0];
    float x0 = fmaf(ax0, inv, 2.f * hv.x);
    float x1 = fmaf(ay0, inv, 2.f * hv.y);

    float sum = x0 + x1, sq = x0 * x0 + x1 * x1;
#pragma unroll
    for (int d = 1; d < 64; d <<= 1) { sum += __shfl_xor(sum, d); sq += __shfl_xor(sq, d); }
    float mu = sum * (1.f / 128.f);
    float var = sq * (1.f / 128.f) - mu * mu;
    float rstd = rsqrtf(var + 1e-5f);
    float y0 = (x0 - mu) * rstd * ln_g[f0]     + ln_b[f0];
    float y1 = (x1 - mu) * rstd * ln_g[f0 + 1] + ln_b[f0 + 1];
    y0 = fmaxf(y0, 0.f); y1 = fmaxf(y1, 0.f);
    *(float2*)&h_out[(size_t)v * 128 + f0] = make_float2(y0, y1);
    h16_out[((size_t)v << 6) + lane] = pack2_bf16_rne(y0, y1);
}

// ---------------- epilogue ----------------
// copy node_emb to out + accumulate per-column partial sums (stride is mult of 32 float4s)
__global__ __launch_bounds__(256) void copy_and_mean(const float4* __restrict__ src,
                                                     float4* __restrict__ dst,
                                                     float* __restrict__ gacc, size_t n4) {
    int tid = threadIdx.x;
    size_t i = blockIdx.x * (size_t)256 + tid;
    size_t stride = (size_t)gridDim.x * 256;
    float ax = 0.f, ay = 0.f, az = 0.f, aw = 0.f;
    for (; i < n4; i += stride) {
        float4 v = src[i];
        dst[i] = v;
        ax += v.x; ay += v.y; az += v.z; aw += v.w;
    }
    __shared__ float4 sb[256];
    sb[tid] = make_float4(ax, ay, az, aw);
    __syncthreads();
    for (int off = 128; off >= 32; off >>= 1) {
        if (tid < off) {
            float4 o = sb[tid + off];
            sb[tid].x += o.x; sb[tid].y += o.y; sb[tid].z += o.z; sb[tid].w += o.w;
        }
        __syncthreads();
    }
    if (tid < 32) {
        float4 a = sb[tid];
        atomicAdd(&gacc[tid * 4 + 0], a.x);
        atomicAdd(&gacc[tid * 4 + 1], a.y);
        atomicAdd(&gacc[tid * 4 + 2], a.z);
        atomicAdd(&gacc[tid * 4 + 3], a.w);
    }
}

__global__ void graph_mean_final(const float* __restrict__ gacc, float* __restrict__ out, int n) {
    int c = threadIdx.x; // 128
    out[c] = gacc[c] / (float)n;
}

__global__ __launch_bounds__(256) void heads_kernel(
    const float* __restrict__ z,
    const float* __restrict__ Wa, const float* __restrict__ ba,
    const float* __restrict__ Wg, const float* __restrict__ bg,
    const float* __restrict__ Wal, const float* __restrict__ bal,
    const float* __restrict__ Wn, const float* __restrict__ bn,
    const float* __restrict__ Wt, const float* __restrict__ bt,
    float* __restrict__ logits, float* __restrict__ spawn, int n) {
    int v = (blockIdx.x * blockDim.x + threadIdx.x) >> 6;
    int lane = threadIdx.x & 63;
    if (v >= n) return;
    int f0 = lane * 2;
    float2 zv = *(const float2*)&z[(size_t)v * 128 + f0];
    float p0 = zv.x * Wa[f0 * 2]     + zv.y * Wa[(f0 + 1) * 2];
    float p1 = zv.x * Wa[f0 * 2 + 1] + zv.y * Wa[(f0 + 1) * 2 + 1];
    float p2 = zv.x * Wg[f0]  + zv.y * Wg[f0 + 1];
    float p3 = zv.x * Wal[f0] + zv.y * Wal[f0 + 1];
    float p4 = zv.x * Wn[f0]  + zv.y * Wn[f0 + 1];
    float p5 = zv.x * Wt[f0]  + zv.y * Wt[f0 + 1];
#pragma unroll
    for (int d = 1; d < 64; d <<= 1) {
        p0 += __shfl_xor(p0, d); p1 += __shfl_xor(p1, d); p2 += __shfl_xor(p2, d);
        p3 += __shfl_xor(p3, d); p4 += __shfl_xor(p4, d); p5 += __shfl_xor(p5, d);
    }
    if (lane == 0) {
        logits[(size_t)v * 2 + 0] = p0 + ba[0];
        logits[(size_t)v * 2 + 1] = p1 + ba[1];
        float gamma = 5.f / (1.f + __expf(-(p2 + bg[0])));
        float alpha = 2.f / (1.f + __expf(-(p3 + bal[0])));
        float noise = 1.f / (1.f + __expf(-(p4 + bn[0])));
        float theta = tanhf(p5 + bt[0]) * 3.14159265358979323846f;
        spawn[(size_t)v * 4 + 0] = gamma;
        spawn[(size_t)v * 4 + 1] = alpha;
        spawn[(size_t)v * 4 + 2] = noise;
        spawn[(size_t)v * 4 + 3] = theta;
    }
}

extern "C" void kernel_launch(void* const* d_in, const int* in_sizes, int n_in,
                              void* d_out, int out_size, void* d_ws, size_t ws_size,
                              hipStream_t stream) {
    const float* node_feats = (const float*)d_in[0];
    const int*   src  = (const int*)d_in[1];
    const int*   dst  = (const int*)d_in[2];
    const float* W_in = (const float*)d_in[3];
    const float* b_in = (const float*)d_in[4];
    const float* W_src = (const float*)d_in[5];
    const float* b_src = (const float*)d_in[6];
    const float* W_dst = (const float*)d_in[7];
    const float* b_dst = (const float*)d_in[8];
    const float* attn  = (const float*)d_in[9];
    const float* ln_g  = (const float*)d_in[10];
    const float* ln_b  = (const float*)d_in[11];
    const float* W1 = (const float*)d_in[12]; const float* b1 = (const float*)d_in[13];
    const float* W2 = (const float*)d_in[14]; const float* b2 = (const float*)d_in[15];
    const float* Wa = (const float*)d_in[16]; const float* ba = (const float*)d_in[17];
    const float* Wg = (const float*)d_in[18]; const float* bg = (const float*)d_in[19];
    const float* Wal = (const float*)d_in[20]; const float* bal = (const float*)d_in[21];
    const float* Wn = (const float*)d_in[22]; const float* bn = (const float*)d_in[23];
    const float* Wt = (const float*)d_in[24]; const float* bt = (const float*)d_in[25];

    const int n = in_sizes[0] / 32;  // 50000
    const int E = in_sizes[1];       // 1600000
    const int P = (n + 511) / 512;

    char* ws = (char*)d_ws;
    size_t off = 0;
    auto alloc = [&](size_t bytes) -> void* {
        void* p = ws + off;
        off = (off + bytes + 255) & ~(size_t)255;
        return p;
    };
    float* Bh0 = (float*)alloc((size_t)n * 128 * 4);
    float* Bh1 = (float*)alloc((size_t)n * 128 * 4);
    float* Bhd = (float*)alloc((size_t)n * 128 * 4);   // also reused for z
    unsigned short* h16  = (unsigned short*)alloc((size_t)n * 128 * 2);
    unsigned short* hs16 = (unsigned short*)alloc((size_t)n * 128 * 2); // also z1
    unsigned short* Wt16 = (unsigned short*)alloc((size_t)8 * 16384 * 2);
    int* deg  = (int*)alloc((size_t)n * 4);
    int* offs = (int*)alloc((size_t)(n + 1) * 4);
    int* woff = (int*)alloc((size_t)n * 4);
    int* csr  = (int*)alloc((size_t)E * 4);
    int* bsum = (int*)alloc((size_t)P * 4);
    int* bpre = (int*)alloc((size_t)P * 4);
    float* gacc = (float*)alloc(128 * 4);

    float* out = (float*)d_out;
    float* out_gemb   = out;
    float* out_nemb   = out + 128;
    float* out_logits = out + 128 + (size_t)n * 128;
    float* out_spawn  = out_logits + (size_t)n * 2;

    hipMemsetAsync(deg, 0, (size_t)n * 4, stream);
    hipMemsetAsync(gacc, 0, 128 * 4, stream);

    count_deg<<<(E + 255) / 256, 256, 0, stream>>>(dst, deg, E);
    block_sums<<<P, 512, 0, stream>>>(deg, bsum, n);
    scan_partials<<<1, 128, 0, stream>>>(bsum, bpre, P);
    scan_blocks<<<P, 512, 0, stream>>>(deg, bpre, offs, woff, n);
    fill_csr_xcd<<<1024, 256, 0, stream>>>(src, dst, woff, csr, E, n);

    prep_weights<<<8, 256, 0, stream>>>(W_src, W_dst, W1, W2, Wt16);

    int gemm_grid = (n + GR - 1) / GR;    // vector GEMM: 64 rows/block
    int mfma_grid = (n + 63) / 64;        // MFMA GEMM: 64 rows/block

    // input projection -> f32 h + bf16 mirror
    gemm_k<32, false, true, true><<<gemm_grid, 256, 0, stream>>>(node_feats, W_in, b_in, Bh0, h16, n);

    float* cur = Bh0;
    float* nxt = Bh1;
    for (int l = 0; l < 3; ++l) {
        gemm_mfma<false, false, true><<<mfma_grid, 256, 0, stream>>>(
            h16, Wt16 + (size_t)l * 16384, b_src + l * 128, nullptr, hs16, n);
        gemm_mfma<false, true, false><<<mfma_grid, 256, 0, stream>>>(
            h16, Wt16 + (size_t)(3 + l) * 16384, b_dst + l * 128, Bhd, nullptr, n);
        gat_aggregate<<<(n + 3) / 4, 256, 0, stream>>>(cur, hs16, Bhd, offs, csr,
                                                       attn + l * 128, ln_g + l * 128,
                                                       ln_b + l * 128, nxt, (unsigned*)h16, n);
        float* t = cur; cur = nxt; nxt = t;
    }
    // cur = final node embedding (f32); h16 = bf16 mirror

    gemm_mfma<true, false, true><<<mfma_grid, 256, 0, stream>>>(
        h16, Wt16 + (size_t)6 * 16384, b1, nullptr, hs16, n);           // z1 (bf16)
    gemm_mfma<true, true, false><<<mfma_grid, 256, 0, stream>>>(
        hs16, Wt16 + (size_t)7 * 16384, b2, Bhd, nullptr, n);           // z (f32)

    copy_and_mean<<<512, 256, 0, stream>>>((const float4*)cur, (float4*)out_nemb, gacc, (size_t)n * 32);
    graph_mean_final<<<1, 128, 0, stream>>>(gacc, out_gemb, n);
    heads_kernel<<<(n + 3) / 4, 256, 0, stream>>>(Bhd, Wa, ba, Wg, bg, Wal, bal,
                                                  Wn, bn, Wt, bt, out_logits, out_spawn, n);
}

// Round 6
// 703.338 us; speedup vs baseline: 1.8197x; 1.0839x over previous
//
#include <hip/hip_runtime.h>
#include <hip/hip_bf16.h>

#define HID 128
#define NHEAD 4

typedef __attribute__((ext_vector_type(8))) short bf16x8;
typedef __attribute__((ext_vector_type(4))) float f32x4;

// ---------------- CSR build ----------------
// XCD-partitioned histogram: group g touches only its 1/8 node range -> deg
// cachelines are owned by one XCD's L2.
__global__ __launch_bounds__(256) void count_deg_xcd(const int* __restrict__ dst,
                                                     int* __restrict__ deg, int E, int n) {
    int grp = blockIdx.x & 7;
    int blk = blockIdx.x >> 3;
    int nblk = gridDim.x >> 3;
    int lo = (int)(((long long)n * grp) >> 3);
    int hi = (int)(((long long)n * (grp + 1)) >> 3);
    for (int i = blk * 256 + threadIdx.x; i < E; i += nblk * 256) {
        int d = dst[i];
        if (d >= lo && d < hi) atomicAdd(&deg[d], 1);
    }
}

__global__ void block_sums(const int* __restrict__ deg, int* __restrict__ bsum, int n) {
    __shared__ int sbuf[512];
    int tid = threadIdx.x;
    int i = blockIdx.x * 512 + tid;
    sbuf[tid] = (i < n) ? deg[i] : 0;
    __syncthreads();
    for (int d = 256; d > 0; d >>= 1) {
        if (tid < d) sbuf[tid] += sbuf[tid + d];
        __syncthreads();
    }
    if (tid == 0) bsum[blockIdx.x] = sbuf[0];
}

__global__ void scan_partials(const int* __restrict__ bsum, int* __restrict__ bpre, int P) {
    __shared__ int buf[128];
    int tid = threadIdx.x; // 128 threads, P <= 128
    int v = (tid < P) ? bsum[tid] : 0;
    buf[tid] = v;
    __syncthreads();
    for (int d = 1; d < 128; d <<= 1) {
        int t = (tid >= d) ? buf[tid - d] : 0;
        __syncthreads();
        buf[tid] += t;
        __syncthreads();
    }
    if (tid < P) bpre[tid] = buf[tid] - v; // exclusive
}

__global__ void scan_blocks(const int* __restrict__ deg, const int* __restrict__ bpre,
                            int* __restrict__ offs, int* __restrict__ woff, int n) {
    __shared__ int sbuf[512];
    int tid = threadIdx.x;
    int i = blockIdx.x * 512 + tid;
    int v = (i < n) ? deg[i] : 0;
    sbuf[tid] = v;
    __syncthreads();
    for (int d = 1; d < 512; d <<= 1) {
        int t = (tid >= d) ? sbuf[tid - d] : 0;
        __syncthreads();
        sbuf[tid] += t;
        __syncthreads();
    }
    if (i < n) {
        int incl = bpre[blockIdx.x] + sbuf[tid];
        offs[i + 1] = incl;
        woff[i] = incl - v;
    }
    if (i == 0) offs[0] = 0;
}

__global__ __launch_bounds__(256) void fill_csr_xcd(
    const int* __restrict__ src, const int* __restrict__ dst,
    int* __restrict__ woff, int* __restrict__ csr_src, int E, int n) {
    int grp = blockIdx.x & 7;
    int blk = blockIdx.x >> 3;
    int nblk = gridDim.x >> 3;
    int lo = (int)(((long long)n * grp) >> 3);
    int hi = (int)(((long long)n * (grp + 1)) >> 3);
    for (int i = blk * 256 + threadIdx.x; i < E; i += nblk * 256) {
        int d = dst[i];
        if (d >= lo && d < hi) {
            int pos = atomicAdd(&woff[d], 1);
            csr_src[pos] = src[i];
        }
    }
}

// ---------------- helpers ----------------
__device__ __forceinline__ unsigned pack2_bf16_rne(float lo, float hi) {
    unsigned a = __float_as_uint(lo);
    a = (a + 0x7fffu + ((a >> 16) & 1u)) >> 16;
    unsigned b = __float_as_uint(hi);
    b = (b + 0x7fffu + ((b >> 16) & 1u)) & 0xffff0000u;
    return a | b;
}

__device__ __forceinline__ unsigned short bf16_rne(float x) {
    unsigned u = __float_as_uint(x);
    u = (u + 0x7fffu + ((u >> 16) & 1u)) >> 16;
    return (unsigned short)u;
}

// 16-lane row sum via DPP (compiler-managed hazards; DPP-combine folds to
// v_add_f32_dpp). Steps: xor1 (quad_perm[1,0,3,2]=0xB1), xor2
// (quad_perm[2,3,0,1]=0x4E), xor4 (row_half_mirror=0x141, valid since values
// are quad-uniform), xor8 (row_mirror=0x140, valid since half-uniform).
__device__ __forceinline__ float row_sum16(float x) {
    x += __int_as_float(__builtin_amdgcn_update_dpp(0, __float_as_int(x), 0xB1, 0xF, 0xF, true));
    x += __int_as_float(__builtin_amdgcn_update_dpp(0, __float_as_int(x), 0x4E, 0xF, 0xF, true));
    x += __int_as_float(__builtin_amdgcn_update_dpp(0, __float_as_int(x), 0x141, 0xF, 0xF, true));
    x += __int_as_float(__builtin_amdgcn_update_dpp(0, __float_as_int(x), 0x140, 0xF, 0xF, true));
    return x;
}

// Transpose+convert 8 [128,128] f32 weight mats to bf16 [N][K]
__global__ void prep_weights(const float* __restrict__ W_src, const float* __restrict__ W_dst,
                             const float* __restrict__ W1, const float* __restrict__ W2,
                             unsigned short* __restrict__ Wt) {
    int mat = blockIdx.x; // 0..7
    const float* Wf = (mat < 3) ? (W_src + (size_t)mat * 16384)
                    : (mat < 6) ? (W_dst + (size_t)(mat - 3) * 16384)
                    : (mat == 6) ? W1 : W2;
    unsigned short* out = Wt + (size_t)mat * 16384;
    for (int idx = threadIdx.x; idx < 16384; idx += blockDim.x) {
        int k = idx >> 7, nn = idx & 127;
        out[nn * 128 + k] = bf16_rne(Wf[idx]);
    }
}

// ---------------- vector GEMM (K=32 input projection) ----------------
#define GR 64
template <int K, bool RELU, bool F32OUT, bool BF16OUT>
__global__ __launch_bounds__(256) void gemm_k(const float* __restrict__ A,
                                              const float* __restrict__ W,
                                              const float* __restrict__ bias,
                                              float* __restrict__ Cf,
                                              unsigned short* __restrict__ C16, int n) {
    __shared__ __align__(16) float a_sh[GR * K];
    const int tid = threadIdx.x;
    const int tx = tid & 31;
    const int ty = tid >> 5;
    const int r0 = blockIdx.x * GR;

    for (int i = tid * 4; i < GR * K; i += 1024) {
        int r = i / K, k = i % K;
        int gr = r0 + r;
        float4 v = make_float4(0.f, 0.f, 0.f, 0.f);
        if (gr < n) v = *(const float4*)&A[(size_t)gr * K + k];
        *(float4*)&a_sh[i] = v;
    }
    __syncthreads();

    float4 acc[8];
#pragma unroll
    for (int r = 0; r < 8; ++r) acc[r] = make_float4(0.f, 0.f, 0.f, 0.f);

    const float* ab = &a_sh[ty * 8 * K];
    const float* wb = &W[tx * 4];

    for (int k = 0; k < K; k += 4) {
        float4 w0 = *(const float4*)&wb[(size_t)(k + 0) * 128];
        float4 w1 = *(const float4*)&wb[(size_t)(k + 1) * 128];
        float4 w2 = *(const float4*)&wb[(size_t)(k + 2) * 128];
        float4 w3 = *(const float4*)&wb[(size_t)(k + 3) * 128];
#pragma unroll
        for (int r = 0; r < 8; ++r) {
            float4 a4 = *(const float4*)&ab[r * K + k];
            acc[r].x = fmaf(a4.x, w0.x, acc[r].x);
            acc[r].y = fmaf(a4.x, w0.y, acc[r].y);
            acc[r].z = fmaf(a4.x, w0.z, acc[r].z);
            acc[r].w = fmaf(a4.x, w0.w, acc[r].w);
            acc[r].x = fmaf(a4.y, w1.x, acc[r].x);
            acc[r].y = fmaf(a4.y, w1.y, acc[r].y);
            acc[r].z = fmaf(a4.y, w1.z, acc[r].z);
            acc[r].w = fmaf(a4.y, w1.w, acc[r].w);
            acc[r].x = fmaf(a4.z, w2.x, acc[r].x);
            acc[r].y = fmaf(a4.z, w2.y, acc[r].y);
            acc[r].z = fmaf(a4.z, w2.z, acc[r].z);
            acc[r].w = fmaf(a4.z, w2.w, acc[r].w);
            acc[r].x = fmaf(a4.w, w3.x, acc[r].x);
            acc[r].y = fmaf(a4.w, w3.y, acc[r].y);
            acc[r].z = fmaf(a4.w, w3.z, acc[r].z);
            acc[r].w = fmaf(a4.w, w3.w, acc[r].w);
        }
    }

    float4 b4 = *(const float4*)&bias[tx * 4];
#pragma unroll
    for (int r = 0; r < 8; ++r) {
        int gr = r0 + ty * 8 + r;
        if (gr < n) {
            float4 o;
            o.x = acc[r].x + b4.x;
            o.y = acc[r].y + b4.y;
            o.z = acc[r].z + b4.z;
            o.w = acc[r].w + b4.w;
            if (RELU) {
                o.x = fmaxf(o.x, 0.f); o.y = fmaxf(o.y, 0.f);
                o.z = fmaxf(o.z, 0.f); o.w = fmaxf(o.w, 0.f);
            }
            if (F32OUT) *(float4*)&Cf[(size_t)gr * 128 + tx * 4] = o;
            if (BF16OUT) {
                uint2 st;
                st.x = pack2_bf16_rne(o.x, o.y);
                st.y = pack2_bf16_rne(o.z, o.w);
                *(uint2*)&C16[(size_t)gr * 128 + tx * 4] = st;
            }
        }
    }
}

// ---------------- MFMA GEMM (single output) ----------------
template <bool RELU, bool F32OUT, bool BF16OUT>
__global__ __launch_bounds__(256) void gemm_mfma(
    const unsigned short* __restrict__ A16,
    const unsigned short* __restrict__ Bt16,
    const float* __restrict__ bias,
    float* __restrict__ Cf, unsigned short* __restrict__ C16, int n) {
    const int wave = threadIdx.x >> 6;
    const int lane = threadIdx.x & 63;
    const int r = lane & 15, g = lane >> 4;
    const int m0 = blockIdx.x * 64 + wave * 16;
    int ra = m0 + r; if (ra > n - 1) ra = n - 1;
    const bf16x8* Arow = (const bf16x8*)(A16 + (size_t)ra * 128);
    bf16x8 a0 = Arow[g];
    bf16x8 a1 = Arow[4 + g];
    bf16x8 a2 = Arow[8 + g];
    bf16x8 a3 = Arow[12 + g];
#pragma unroll
    for (int ct = 0; ct < 8; ++ct) {
        const bf16x8* Brow = (const bf16x8*)(Bt16 + (size_t)(ct * 16 + r) * 128);
        f32x4 acc = {0.f, 0.f, 0.f, 0.f};
        acc = __builtin_amdgcn_mfma_f32_16x16x32_bf16(a0, Brow[g], acc, 0, 0, 0);
        acc = __builtin_amdgcn_mfma_f32_16x16x32_bf16(a1, Brow[4 + g], acc, 0, 0, 0);
        acc = __builtin_amdgcn_mfma_f32_16x16x32_bf16(a2, Brow[8 + g], acc, 0, 0, 0);
        acc = __builtin_amdgcn_mfma_f32_16x16x32_bf16(a3, Brow[12 + g], acc, 0, 0, 0);
        const int col = ct * 16 + r;
        const float bcol = bias[col];
#pragma unroll
        for (int j = 0; j < 4; ++j) {
            int row = m0 + g * 4 + j;
            if (row < n) {
                float v = acc[j] + bcol;
                if (RELU) v = fmaxf(v, 0.f);
                if (F32OUT) Cf[(size_t)row * 128 + col] = v;
                if (BF16OUT) C16[(size_t)row * 128 + col] = bf16_rne(v);
            }
        }
    }
}

// ---------------- MFMA GEMM dual: A read once, two B mats ----------------
// out1 = A @ B1^T + b1 -> bf16 (hs16); out2 = A @ B2^T + b2 -> f32 (hd)
__global__ __launch_bounds__(256) void gemm_mfma_dual(
    const unsigned short* __restrict__ A16,
    const unsigned short* __restrict__ B1t, const unsigned short* __restrict__ B2t,
    const float* __restrict__ bias1, const float* __restrict__ bias2,
    unsigned short* __restrict__ C1, float* __restrict__ C2, int n) {
    const int wave = threadIdx.x >> 6;
    const int lane = threadIdx.x & 63;
    const int r = lane & 15, g = lane >> 4;
    const int m0 = blockIdx.x * 64 + wave * 16;
    int ra = m0 + r; if (ra > n - 1) ra = n - 1;
    const bf16x8* Arow = (const bf16x8*)(A16 + (size_t)ra * 128);
    bf16x8 a0 = Arow[g];
    bf16x8 a1 = Arow[4 + g];
    bf16x8 a2 = Arow[8 + g];
    bf16x8 a3 = Arow[12 + g];
#pragma unroll
    for (int ct = 0; ct < 8; ++ct) {
        const int col = ct * 16 + r;
        {
            const bf16x8* Brow = (const bf16x8*)(B1t + (size_t)col * 128);
            f32x4 acc = {0.f, 0.f, 0.f, 0.f};
            acc = __builtin_amdgcn_mfma_f32_16x16x32_bf16(a0, Brow[g], acc, 0, 0, 0);
            acc = __builtin_amdgcn_mfma_f32_16x16x32_bf16(a1, Brow[4 + g], acc, 0, 0, 0);
            acc = __builtin_amdgcn_mfma_f32_16x16x32_bf16(a2, Brow[8 + g], acc, 0, 0, 0);
            acc = __builtin_amdgcn_mfma_f32_16x16x32_bf16(a3, Brow[12 + g], acc, 0, 0, 0);
            const float bcol = bias1[col];
#pragma unroll
            for (int j = 0; j < 4; ++j) {
                int row = m0 + g * 4 + j;
                if (row < n) C1[(size_t)row * 128 + col] = bf16_rne(acc[j] + bcol);
            }
        }
        {
            const bf16x8* Brow = (const bf16x8*)(B2t + (size_t)col * 128);
            f32x4 acc = {0.f, 0.f, 0.f, 0.f};
            acc = __builtin_amdgcn_mfma_f32_16x16x32_bf16(a0, Brow[g], acc, 0, 0, 0);
            acc = __builtin_amdgcn_mfma_f32_16x16x32_bf16(a1, Brow[4 + g], acc, 0, 0, 0);
            acc = __builtin_amdgcn_mfma_f32_16x16x32_bf16(a2, Brow[8 + g], acc, 0, 0, 0);
            acc = __builtin_amdgcn_mfma_f32_16x16x32_bf16(a3, Brow[12 + g], acc, 0, 0, 0);
            const float bcol = bias2[col];
#pragma unroll
            for (int j = 0; j < 4; ++j) {
                int row = m0 + g * 4 + j;
                if (row < n) C2[(size_t)row * 128 + col] = acc[j] + bcol;
            }
        }
    }
}

// ---------------- fused GATv2 aggregate + residuals + LayerNorm + ReLU ----------------
// one wave per node; lane holds feats 2l,2l+1; 16-lane head groups.
// log2-domain scores (log2e folded into attn), shared reference max across
// 4 unrolled states, DPP-fused score reduce.
__global__ __launch_bounds__(256) void gat_aggregate(
    const float* __restrict__ h,
    const unsigned short* __restrict__ hs16,
    const float* __restrict__ hd,
    const int* __restrict__ offs,
    const int* __restrict__ csr_src,
    const float* __restrict__ attn,
    const float* __restrict__ ln_g, const float* __restrict__ ln_b,
    float* __restrict__ h_out, unsigned* __restrict__ h16_out, int n) {
    int v = (blockIdx.x * blockDim.x + threadIdx.x) >> 6;
    int lane = threadIdx.x & 63;
    if (v >= n) return;
    const unsigned fb = (unsigned)lane << 2;
    int f0 = lane * 2;

    const float L2E = 1.4426950408889634f;
    float a0 = attn[f0] * L2E, a1 = attn[f0 + 1] * L2E;
    float2 hdv = *(const float2*)&hd[(size_t)v * 128 + f0];

    const char* hsb = (const char*)hs16;
    unsigned uv = *(const unsigned*)(hsb + ((size_t)(unsigned)v << 8) + fb);
    float svx = __uint_as_float(uv << 16);
    float svy = __uint_as_float(uv & 0xffff0000u);

    float t0 = svx + hdv.x; t0 = fmaxf(t0, 0.2f * t0);
    float t1 = svy + hdv.y; t1 = fmaxf(t1, 0.2f * t1);
    float m = row_sum16(fmaf(t1, a1, t0 * a0));  // self-loop score (log2 domain)

    float s0 = 1.0f, ax0 = svx, ay0 = svy;
    float s1 = 0.0f, ax1 = 0.f, ay1 = 0.f;
    float s2 = 0.0f, ax2 = 0.f, ay2 = 0.f;
    float s3 = 0.0f, ax3 = 0.f, ay3 = 0.f;

    int beg = offs[v], end = offs[v + 1];
    int i = beg;
    int end4 = beg + ((end - beg) & ~3);
    for (; i < end4; i += 4) {
        int u0 = csr_src[i], u1 = csr_src[i + 1], u2 = csr_src[i + 2], u3 = csr_src[i + 3];
        unsigned w0 = *(const unsigned*)(hsb + ((size_t)(unsigned)u0 << 8) + fb);
        unsigned w1 = *(const unsigned*)(hsb + ((size_t)(unsigned)u1 << 8) + fb);
        unsigned w2 = *(const unsigned*)(hsb + ((size_t)(unsigned)u2 << 8) + fb);
        unsigned w3 = *(const unsigned*)(hsb + ((size_t)(unsigned)u3 << 8) + fb);
        float h0x = __uint_as_float(w0 << 16), h0y = __uint_as_float(w0 & 0xffff0000u);
        float h1x = __uint_as_float(w1 << 16), h1y = __uint_as_float(w1 & 0xffff0000u);
        float h2x = __uint_as_float(w2 << 16), h2y = __uint_as_float(w2 & 0xffff0000u);
        float h3x = __uint_as_float(w3 << 16), h3y = __uint_as_float(w3 & 0xffff0000u);
        float q0x = h0x + hdv.x; q0x = fmaxf(q0x, 0.2f * q0x);
        float q0y = h0y + hdv.y; q0y = fmaxf(q0y, 0.2f * q0y);
        float q1x = h1x + hdv.x; q1x = fmaxf(q1x, 0.2f * q1x);
        float q1y = h1y + hdv.y; q1y = fmaxf(q1y, 0.2f * q1y);
        float q2x = h2x + hdv.x; q2x = fmaxf(q2x, 0.2f * q2x);
        float q2y = h2y + hdv.y; q2y = fmaxf(q2y, 0.2f * q2y);
        float q3x = h3x + hdv.x; q3x = fmaxf(q3x, 0.2f * q3x);
        float q3y = h3y + hdv.y; q3y = fmaxf(q3y, 0.2f * q3y);
        float sc0 = row_sum16(fmaf(q0y, a1, q0x * a0));
        float sc1 = row_sum16(fmaf(q1y, a1, q1x * a0));
        float sc2 = row_sum16(fmaf(q2y, a1, q2x * a0));
        float sc3 = row_sum16(fmaf(q3y, a1, q3x * a0));
        float d0 = sc0 - m, d1 = sc1 - m, d2 = sc2 - m, d3 = sc3 - m;
        float dm = fmaxf(fmaxf(d0, d1), fmaxf(d2, d3));
        if (__builtin_expect(__any(dm > 8.f), 0)) {
            float mn = m + fmaxf(dm, 0.f);
            float rr = exp2f(m - mn);
            s0 *= rr; ax0 *= rr; ay0 *= rr;
            s1 *= rr; ax1 *= rr; ay1 *= rr;
            s2 *= rr; ax2 *= rr; ay2 *= rr;
            s3 *= rr; ax3 *= rr; ay3 *= rr;
            m = mn;
            d0 = sc0 - m; d1 = sc1 - m; d2 = sc2 - m; d3 = sc3 - m;
        }
        float e0 = exp2f(d0), e1 = exp2f(d1), e2 = exp2f(d2), e3 = exp2f(d3);
        s0 += e0; ax0 = fmaf(e0, h0x, ax0); ay0 = fmaf(e0, h0y, ay0);
        s1 += e1; ax1 = fmaf(e1, h1x, ax1); ay1 = fmaf(e1, h1y, ay1);
        s2 += e2; ax2 = fmaf(e2, h2x, ax2); ay2 = fmaf(e2, h2y, ay2);
        s3 += e3; ax3 = fmaf(e3, h3x, ax3); ay3 = fmaf(e3, h3y, ay3);
    }
    for (; i < end; ++i) {
        int u0 = csr_src[i];
        unsigned w0 = *(const unsigned*)(hsb + ((size_t)(unsigned)u0 << 8) + fb);
        float h0x = __uint_as_float(w0 << 16), h0y = __uint_as_float(w0 & 0xffff0000u);
        float q0x = h0x + hdv.x; q0x = fmaxf(q0x, 0.2f * q0x);
        float q0y = h0y + hdv.y; q0y = fmaxf(q0y, 0.2f * q0y);
        float sc0 = row_sum16(fmaf(q0y, a1, q0x * a0));
        float d0 = sc0 - m;
        if (__builtin_expect(__any(d0 > 8.f), 0)) {
            float mn = m + fmaxf(d0, 0.f);
            float rr = exp2f(m - mn);
            s0 *= rr; ax0 *= rr; ay0 *= rr;
            s1 *= rr; ax1 *= rr; ay1 *= rr;
            s2 *= rr; ax2 *= rr; ay2 *= rr;
            s3 *= rr; ax3 *= rr; ay3 *= rr;
            m = mn;
            d0 = sc0 - m;
        }
        float e0 = exp2f(d0);
        s0 += e0; ax0 = fmaf(e0, h0x, ax0); ay0 = fmaf(e0, h0y, ay0);
    }
    // merge (shared m -> plain adds)
    float s  = (s0 + s1) + (s2 + s3);
    float ax = (ax0 + ax1) + (ax2 + ax3);
    float ay = (ay0 + ay1) + (ay2 + ay3);
    float inv = 1.0f / (s + 1e-9f);

    float2 hv = *(const float2*)&h[(size_t)v * 128 + f0];
    float x0 = fmaf(ax, inv, 2.f * hv.x);
    float x1 = fmaf(ay, inv, 2.f * hv.y);

    float sum = x0 + x1, sq = x0 * x0 + x1 * x1;
#pragma unroll
    for (int d = 1; d < 64; d <<= 1) { sum += __shfl_xor(sum, d); sq += __shfl_xor(sq, d); }
    float mu = sum * (1.f / 128.f);
    float var = sq * (1.f / 128.f) - mu * mu;
    float rstd = rsqrtf(var + 1e-5f);
    float y0 = (x0 - mu) * rstd * ln_g[f0]     + ln_b[f0];
    float y1 = (x1 - mu) * rstd * ln_g[f0 + 1] + ln_b[f0 + 1];
    y0 = fmaxf(y0, 0.f); y1 = fmaxf(y1, 0.f);
    *(float2*)&h_out[(size_t)v * 128 + f0] = make_float2(y0, y1);
    h16_out[((size_t)v << 6) + lane] = pack2_bf16_rne(y0, y1);
}

// ---------------- epilogue ----------------
__global__ __launch_bounds__(256) void mean_partial(const float4* __restrict__ src,
                                                    float* __restrict__ gacc, size_t n4) {
    int tid = threadIdx.x;
    size_t i = blockIdx.x * (size_t)256 + tid;
    size_t stride = (size_t)gridDim.x * 256;
    float ax = 0.f, ay = 0.f, az = 0.f, aw = 0.f;
    for (; i < n4; i += stride) {
        float4 v = src[i];
        ax += v.x; ay += v.y; az += v.z; aw += v.w;
    }
    __shared__ float4 sb[256];
    sb[tid] = make_float4(ax, ay, az, aw);
    __syncthreads();
    for (int off = 128; off >= 32; off >>= 1) {
        if (tid < off) {
            float4 o = sb[tid + off];
            sb[tid].x += o.x; sb[tid].y += o.y; sb[tid].z += o.z; sb[tid].w += o.w;
        }
        __syncthreads();
    }
    if (tid < 32) {
        float4 a = sb[tid];
        atomicAdd(&gacc[tid * 4 + 0], a.x);
        atomicAdd(&gacc[tid * 4 + 1], a.y);
        atomicAdd(&gacc[tid * 4 + 2], a.z);
        atomicAdd(&gacc[tid * 4 + 3], a.w);
    }
}

__global__ void graph_mean_final(const float* __restrict__ gacc, float* __restrict__ out, int n) {
    int c = threadIdx.x; // 128
    out[c] = gacc[c] / (float)n;
}

__global__ __launch_bounds__(256) void heads_kernel(
    const float* __restrict__ z,
    const float* __restrict__ Wa, const float* __restrict__ ba,
    const float* __restrict__ Wg, const float* __restrict__ bg,
    const float* __restrict__ Wal, const float* __restrict__ bal,
    const float* __restrict__ Wn, const float* __restrict__ bn,
    const float* __restrict__ Wt, const float* __restrict__ bt,
    float* __restrict__ logits, float* __restrict__ spawn, int n) {
    int v = (blockIdx.x * blockDim.x + threadIdx.x) >> 6;
    int lane = threadIdx.x & 63;
    if (v >= n) return;
    int f0 = lane * 2;
    float2 zv = *(const float2*)&z[(size_t)v * 128 + f0];
    float p0 = zv.x * Wa[f0 * 2]     + zv.y * Wa[(f0 + 1) * 2];
    float p1 = zv.x * Wa[f0 * 2 + 1] + zv.y * Wa[(f0 + 1) * 2 + 1];
    float p2 = zv.x * Wg[f0]  + zv.y * Wg[f0 + 1];
    float p3 = zv.x * Wal[f0] + zv.y * Wal[f0 + 1];
    float p4 = zv.x * Wn[f0]  + zv.y * Wn[f0 + 1];
    float p5 = zv.x * Wt[f0]  + zv.y * Wt[f0 + 1];
#pragma unroll
    for (int d = 1; d < 64; d <<= 1) {
        p0 += __shfl_xor(p0, d); p1 += __shfl_xor(p1, d); p2 += __shfl_xor(p2, d);
        p3 += __shfl_xor(p3, d); p4 += __shfl_xor(p4, d); p5 += __shfl_xor(p5, d);
    }
    if (lane == 0) {
        logits[(size_t)v * 2 + 0] = p0 + ba[0];
        logits[(size_t)v * 2 + 1] = p1 + ba[1];
        float gamma = 5.f / (1.f + __expf(-(p2 + bg[0])));
        float alpha = 2.f / (1.f + __expf(-(p3 + bal[0])));
        float noise = 1.f / (1.f + __expf(-(p4 + bn[0])));
        float theta = tanhf(p5 + bt[0]) * 3.14159265358979323846f;
        spawn[(size_t)v * 4 + 0] = gamma;
        spawn[(size_t)v * 4 + 1] = alpha;
        spawn[(size_t)v * 4 + 2] = noise;
        spawn[(size_t)v * 4 + 3] = theta;
    }
}

extern "C" void kernel_launch(void* const* d_in, const int* in_sizes, int n_in,
                              void* d_out, int out_size, void* d_ws, size_t ws_size,
                              hipStream_t stream) {
    const float* node_feats = (const float*)d_in[0];
    const int*   src  = (const int*)d_in[1];
    const int*   dst  = (const int*)d_in[2];
    const float* W_in = (const float*)d_in[3];
    const float* b_in = (const float*)d_in[4];
    const float* W_src = (const float*)d_in[5];
    const float* b_src = (const float*)d_in[6];
    const float* W_dst = (const float*)d_in[7];
    const float* b_dst = (const float*)d_in[8];
    const float* attn  = (const float*)d_in[9];
    const float* ln_g  = (const float*)d_in[10];
    const float* ln_b  = (const float*)d_in[11];
    const float* W1 = (const float*)d_in[12]; const float* b1 = (const float*)d_in[13];
    const float* W2 = (const float*)d_in[14]; const float* b2 = (const float*)d_in[15];
    const float* Wa = (const float*)d_in[16]; const float* ba = (const float*)d_in[17];
    const float* Wg = (const float*)d_in[18]; const float* bg = (const float*)d_in[19];
    const float* Wal = (const float*)d_in[20]; const float* bal = (const float*)d_in[21];
    const float* Wn = (const float*)d_in[22]; const float* bn = (const float*)d_in[23];
    const float* Wt = (const float*)d_in[24]; const float* bt = (const float*)d_in[25];

    const int n = in_sizes[0] / 32;  // 50000
    const int E = in_sizes[1];       // 1600000
    const int P = (n + 511) / 512;

    char* ws = (char*)d_ws;
    size_t off = 0;
    auto alloc = [&](size_t bytes) -> void* {
        void* p = ws + off;
        off = (off + bytes + 255) & ~(size_t)255;
        return p;
    };
    float* Bh0 = (float*)alloc((size_t)n * 128 * 4);
    float* Bh1 = (float*)alloc((size_t)n * 128 * 4);
    float* Bhd = (float*)alloc((size_t)n * 128 * 4);   // hd, later z
    unsigned short* h16  = (unsigned short*)alloc((size_t)n * 128 * 2);
    unsigned short* hs16 = (unsigned short*)alloc((size_t)n * 128 * 2); // also z1
    unsigned short* Wt16 = (unsigned short*)alloc((size_t)8 * 16384 * 2);
    int* deg  = (int*)alloc((size_t)n * 4);
    int* offs = (int*)alloc((size_t)(n + 1) * 4);
    int* woff = (int*)alloc((size_t)n * 4);
    int* csr  = (int*)alloc((size_t)E * 4);
    int* bsum = (int*)alloc((size_t)P * 4);
    int* bpre = (int*)alloc((size_t)P * 4);
    float* gacc = (float*)alloc(128 * 4);

    float* out = (float*)d_out;
    float* out_gemb   = out;
    float* out_nemb   = out + 128;
    float* out_logits = out + 128 + (size_t)n * 128;
    float* out_spawn  = out_logits + (size_t)n * 2;

    hipMemsetAsync(deg, 0, (size_t)n * 4, stream);
    hipMemsetAsync(gacc, 0, 128 * 4, stream);

    count_deg_xcd<<<1024, 256, 0, stream>>>(dst, deg, E, n);
    block_sums<<<P, 512, 0, stream>>>(deg, bsum, n);
    scan_partials<<<1, 128, 0, stream>>>(bsum, bpre, P);
    scan_blocks<<<P, 512, 0, stream>>>(deg, bpre, offs, woff, n);
    fill_csr_xcd<<<1024, 256, 0, stream>>>(src, dst, woff, csr, E, n);

    prep_weights<<<8, 256, 0, stream>>>(W_src, W_dst, W1, W2, Wt16);

    int gemm_grid = (n + GR - 1) / GR;
    int mfma_grid = (n + 63) / 64;

    // input projection -> f32 h + bf16 mirror
    gemm_k<32, false, true, true><<<gemm_grid, 256, 0, stream>>>(node_feats, W_in, b_in, Bh0, h16, n);

    float* cur = Bh0;
    for (int l = 0; l < 3; ++l) {
        gemm_mfma_dual<<<mfma_grid, 256, 0, stream>>>(
            h16, Wt16 + (size_t)l * 16384, Wt16 + (size_t)(3 + l) * 16384,
            b_src + l * 128, b_dst + l * 128, hs16, Bhd, n);
        float* nxt = (l == 2) ? out_nemb : ((cur == Bh0) ? Bh1 : Bh0);
        gat_aggregate<<<(n + 3) / 4, 256, 0, stream>>>(cur, hs16, Bhd, offs, csr,
                                                       attn + l * 128, ln_g + l * 128,
                                                       ln_b + l * 128, nxt, (unsigned*)h16, n);
        cur = nxt;
    }
    // cur == out_nemb (final node embedding, f32); h16 = bf16 mirror

    gemm_mfma<true, false, true><<<mfma_grid, 256, 0, stream>>>(
        h16, Wt16 + (size_t)6 * 16384, b1, nullptr, hs16, n);           // z1 (bf16)
    gemm_mfma<true, true, false><<<mfma_grid, 256, 0, stream>>>(
        hs16, Wt16 + (size_t)7 * 16384, b2, Bhd, nullptr, n);           // z (f32)

    mean_partial<<<512, 256, 0, stream>>>((const float4*)out_nemb, gacc, (size_t)n * 32);
    graph_mean_final<<<1, 128, 0, stream>>>(gacc, out_gemb, n);
    heads_kernel<<<(n + 3) / 4, 256, 0, stream>>>(Bhd, Wa, ba, Wg, bg, Wal, bal,
                                                  Wn, bn, Wt, bt, out_logits, out_spawn, n);
}

// Round 7
// 699.522 us; speedup vs baseline: 1.8296x; 1.0055x over previous
//
#include <hip/hip_runtime.h>
#include <hip/hip_bf16.h>

#define HID 128
#define NHEAD 4

typedef __attribute__((ext_vector_type(8))) short bf16x8;
typedef __attribute__((ext_vector_type(4))) float f32x4;

// ---------------- CSR build ----------------
__global__ __launch_bounds__(256) void count_deg_xcd(const int* __restrict__ dst,
                                                     int* __restrict__ deg, int E, int n) {
    int grp = blockIdx.x & 7;
    int blk = blockIdx.x >> 3;
    int nblk = gridDim.x >> 3;
    int lo = (int)(((long long)n * grp) >> 3);
    int hi = (int)(((long long)n * (grp + 1)) >> 3);
    for (int i = blk * 256 + threadIdx.x; i < E; i += nblk * 256) {
        int d = dst[i];
        if (d >= lo && d < hi) atomicAdd(&deg[d], 1);
    }
}

__global__ void block_sums(const int* __restrict__ deg, int* __restrict__ bsum, int n) {
    __shared__ int sbuf[512];
    int tid = threadIdx.x;
    int i = blockIdx.x * 512 + tid;
    sbuf[tid] = (i < n) ? deg[i] : 0;
    __syncthreads();
    for (int d = 256; d > 0; d >>= 1) {
        if (tid < d) sbuf[tid] += sbuf[tid + d];
        __syncthreads();
    }
    if (tid == 0) bsum[blockIdx.x] = sbuf[0];
}

__global__ void scan_partials(const int* __restrict__ bsum, int* __restrict__ bpre, int P) {
    __shared__ int buf[128];
    int tid = threadIdx.x; // 128 threads, P <= 128
    int v = (tid < P) ? bsum[tid] : 0;
    buf[tid] = v;
    __syncthreads();
    for (int d = 1; d < 128; d <<= 1) {
        int t = (tid >= d) ? buf[tid - d] : 0;
        __syncthreads();
        buf[tid] += t;
        __syncthreads();
    }
    if (tid < P) bpre[tid] = buf[tid] - v; // exclusive
}

__global__ void scan_blocks(const int* __restrict__ deg, const int* __restrict__ bpre,
                            int* __restrict__ offs, int* __restrict__ woff, int n) {
    __shared__ int sbuf[512];
    int tid = threadIdx.x;
    int i = blockIdx.x * 512 + tid;
    int v = (i < n) ? deg[i] : 0;
    sbuf[tid] = v;
    __syncthreads();
    for (int d = 1; d < 512; d <<= 1) {
        int t = (tid >= d) ? sbuf[tid - d] : 0;
        __syncthreads();
        sbuf[tid] += t;
        __syncthreads();
    }
    if (i < n) {
        int incl = bpre[blockIdx.x] + sbuf[tid];
        offs[i + 1] = incl;
        woff[i] = incl - v;
    }
    if (i == 0) offs[0] = 0;
}

__global__ __launch_bounds__(256) void fill_csr_xcd(
    const int* __restrict__ src, const int* __restrict__ dst,
    int* __restrict__ woff, int* __restrict__ csr_src, int E, int n) {
    int grp = blockIdx.x & 7;
    int blk = blockIdx.x >> 3;
    int nblk = gridDim.x >> 3;
    int lo = (int)(((long long)n * grp) >> 3);
    int hi = (int)(((long long)n * (grp + 1)) >> 3);
    for (int i = blk * 256 + threadIdx.x; i < E; i += nblk * 256) {
        int d = dst[i];
        if (d >= lo && d < hi) {
            int pos = atomicAdd(&woff[d], 1);
            csr_src[pos] = src[i];
        }
    }
}

// ---------------- helpers ----------------
__device__ __forceinline__ unsigned pack2_bf16_rne(float lo, float hi) {
    unsigned a = __float_as_uint(lo);
    a = (a + 0x7fffu + ((a >> 16) & 1u)) >> 16;
    unsigned b = __float_as_uint(hi);
    b = (b + 0x7fffu + ((b >> 16) & 1u)) & 0xffff0000u;
    return a | b;
}

__device__ __forceinline__ unsigned short bf16_rne(float x) {
    unsigned u = __float_as_uint(x);
    u = (u + 0x7fffu + ((u >> 16) & 1u)) >> 16;
    return (unsigned short)u;
}

// 8-lane group sum via DPP: xor1 (quad_perm[1,0,3,2]=0xB1), xor2
// (quad_perm[2,3,0,1]=0x4E), xor4 (row_half_mirror=0x141, valid since values
// are quad-uniform by then).
__device__ __forceinline__ float row_sum8(float x) {
    x += __int_as_float(__builtin_amdgcn_update_dpp(0, __float_as_int(x), 0xB1, 0xF, 0xF, true));
    x += __int_as_float(__builtin_amdgcn_update_dpp(0, __float_as_int(x), 0x4E, 0xF, 0xF, true));
    x += __int_as_float(__builtin_amdgcn_update_dpp(0, __float_as_int(x), 0x141, 0xF, 0xF, true));
    return x;
}

// Transpose+convert 8 [128,128] f32 weight mats to bf16 [N][K]
__global__ void prep_weights(const float* __restrict__ W_src, const float* __restrict__ W_dst,
                             const float* __restrict__ W1, const float* __restrict__ W2,
                             unsigned short* __restrict__ Wt) {
    int mat = blockIdx.x; // 0..7
    const float* Wf = (mat < 3) ? (W_src + (size_t)mat * 16384)
                    : (mat < 6) ? (W_dst + (size_t)(mat - 3) * 16384)
                    : (mat == 6) ? W1 : W2;
    unsigned short* out = Wt + (size_t)mat * 16384;
    for (int idx = threadIdx.x; idx < 16384; idx += blockDim.x) {
        int k = idx >> 7, nn = idx & 127;
        out[nn * 128 + k] = bf16_rne(Wf[idx]);
    }
}

// ---------------- vector GEMM (K=32 input projection) ----------------
#define GR 64
template <int K, bool RELU, bool F32OUT, bool BF16OUT>
__global__ __launch_bounds__(256) void gemm_k(const float* __restrict__ A,
                                              const float* __restrict__ W,
                                              const float* __restrict__ bias,
                                              float* __restrict__ Cf,
                                              unsigned short* __restrict__ C16, int n) {
    __shared__ __align__(16) float a_sh[GR * K];
    const int tid = threadIdx.x;
    const int tx = tid & 31;
    const int ty = tid >> 5;
    const int r0 = blockIdx.x * GR;

    for (int i = tid * 4; i < GR * K; i += 1024) {
        int r = i / K, k = i % K;
        int gr = r0 + r;
        float4 v = make_float4(0.f, 0.f, 0.f, 0.f);
        if (gr < n) v = *(const float4*)&A[(size_t)gr * K + k];
        *(float4*)&a_sh[i] = v;
    }
    __syncthreads();

    float4 acc[8];
#pragma unroll
    for (int r = 0; r < 8; ++r) acc[r] = make_float4(0.f, 0.f, 0.f, 0.f);

    const float* ab = &a_sh[ty * 8 * K];
    const float* wb = &W[tx * 4];

    for (int k = 0; k < K; k += 4) {
        float4 w0 = *(const float4*)&wb[(size_t)(k + 0) * 128];
        float4 w1 = *(const float4*)&wb[(size_t)(k + 1) * 128];
        float4 w2 = *(const float4*)&wb[(size_t)(k + 2) * 128];
        float4 w3 = *(const float4*)&wb[(size_t)(k + 3) * 128];
#pragma unroll
        for (int r = 0; r < 8; ++r) {
            float4 a4 = *(const float4*)&ab[r * K + k];
            acc[r].x = fmaf(a4.x, w0.x, acc[r].x);
            acc[r].y = fmaf(a4.x, w0.y, acc[r].y);
            acc[r].z = fmaf(a4.x, w0.z, acc[r].z);
            acc[r].w = fmaf(a4.x, w0.w, acc[r].w);
            acc[r].x = fmaf(a4.y, w1.x, acc[r].x);
            acc[r].y = fmaf(a4.y, w1.y, acc[r].y);
            acc[r].z = fmaf(a4.y, w1.z, acc[r].z);
            acc[r].w = fmaf(a4.y, w1.w, acc[r].w);
            acc[r].x = fmaf(a4.z, w2.x, acc[r].x);
            acc[r].y = fmaf(a4.z, w2.y, acc[r].y);
            acc[r].z = fmaf(a4.z, w2.z, acc[r].z);
            acc[r].w = fmaf(a4.z, w2.w, acc[r].w);
            acc[r].x = fmaf(a4.w, w3.x, acc[r].x);
            acc[r].y = fmaf(a4.w, w3.y, acc[r].y);
            acc[r].z = fmaf(a4.w, w3.z, acc[r].z);
            acc[r].w = fmaf(a4.w, w3.w, acc[r].w);
        }
    }

    float4 b4 = *(const float4*)&bias[tx * 4];
#pragma unroll
    for (int r = 0; r < 8; ++r) {
        int gr = r0 + ty * 8 + r;
        if (gr < n) {
            float4 o;
            o.x = acc[r].x + b4.x;
            o.y = acc[r].y + b4.y;
            o.z = acc[r].z + b4.z;
            o.w = acc[r].w + b4.w;
            if (RELU) {
                o.x = fmaxf(o.x, 0.f); o.y = fmaxf(o.y, 0.f);
                o.z = fmaxf(o.z, 0.f); o.w = fmaxf(o.w, 0.f);
            }
            if (F32OUT) *(float4*)&Cf[(size_t)gr * 128 + tx * 4] = o;
            if (BF16OUT) {
                uint2 st;
                st.x = pack2_bf16_rne(o.x, o.y);
                st.y = pack2_bf16_rne(o.z, o.w);
                *(uint2*)&C16[(size_t)gr * 128 + tx * 4] = st;
            }
        }
    }
}

// ---------------- MFMA GEMM (single output) ----------------
template <bool RELU, bool F32OUT, bool BF16OUT>
__global__ __launch_bounds__(256) void gemm_mfma(
    const unsigned short* __restrict__ A16,
    const unsigned short* __restrict__ Bt16,
    const float* __restrict__ bias,
    float* __restrict__ Cf, unsigned short* __restrict__ C16, int n) {
    const int wave = threadIdx.x >> 6;
    const int lane = threadIdx.x & 63;
    const int r = lane & 15, g = lane >> 4;
    const int m0 = blockIdx.x * 64 + wave * 16;
    int ra = m0 + r; if (ra > n - 1) ra = n - 1;
    const bf16x8* Arow = (const bf16x8*)(A16 + (size_t)ra * 128);
    bf16x8 a0 = Arow[g];
    bf16x8 a1 = Arow[4 + g];
    bf16x8 a2 = Arow[8 + g];
    bf16x8 a3 = Arow[12 + g];
#pragma unroll
    for (int ct = 0; ct < 8; ++ct) {
        const bf16x8* Brow = (const bf16x8*)(Bt16 + (size_t)(ct * 16 + r) * 128);
        f32x4 acc = {0.f, 0.f, 0.f, 0.f};
        acc = __builtin_amdgcn_mfma_f32_16x16x32_bf16(a0, Brow[g], acc, 0, 0, 0);
        acc = __builtin_amdgcn_mfma_f32_16x16x32_bf16(a1, Brow[4 + g], acc, 0, 0, 0);
        acc = __builtin_amdgcn_mfma_f32_16x16x32_bf16(a2, Brow[8 + g], acc, 0, 0, 0);
        acc = __builtin_amdgcn_mfma_f32_16x16x32_bf16(a3, Brow[12 + g], acc, 0, 0, 0);
        const int col = ct * 16 + r;
        const float bcol = bias[col];
#pragma unroll
        for (int j = 0; j < 4; ++j) {
            int row = m0 + g * 4 + j;
            if (row < n) {
                float v = acc[j] + bcol;
                if (RELU) v = fmaxf(v, 0.f);
                if (F32OUT) Cf[(size_t)row * 128 + col] = v;
                if (BF16OUT) C16[(size_t)row * 128 + col] = bf16_rne(v);
            }
        }
    }
}

// ---------------- MFMA GEMM dual: A read once, two B mats ----------------
__global__ __launch_bounds__(256) void gemm_mfma_dual(
    const unsigned short* __restrict__ A16,
    const unsigned short* __restrict__ B1t, const unsigned short* __restrict__ B2t,
    const float* __restrict__ bias1, const float* __restrict__ bias2,
    unsigned short* __restrict__ C1, float* __restrict__ C2, int n) {
    const int wave = threadIdx.x >> 6;
    const int lane = threadIdx.x & 63;
    const int r = lane & 15, g = lane >> 4;
    const int m0 = blockIdx.x * 64 + wave * 16;
    int ra = m0 + r; if (ra > n - 1) ra = n - 1;
    const bf16x8* Arow = (const bf16x8*)(A16 + (size_t)ra * 128);
    bf16x8 a0 = Arow[g];
    bf16x8 a1 = Arow[4 + g];
    bf16x8 a2 = Arow[8 + g];
    bf16x8 a3 = Arow[12 + g];
#pragma unroll
    for (int ct = 0; ct < 8; ++ct) {
        const int col = ct * 16 + r;
        {
            const bf16x8* Brow = (const bf16x8*)(B1t + (size_t)col * 128);
            f32x4 acc = {0.f, 0.f, 0.f, 0.f};
            acc = __builtin_amdgcn_mfma_f32_16x16x32_bf16(a0, Brow[g], acc, 0, 0, 0);
            acc = __builtin_amdgcn_mfma_f32_16x16x32_bf16(a1, Brow[4 + g], acc, 0, 0, 0);
            acc = __builtin_amdgcn_mfma_f32_16x16x32_bf16(a2, Brow[8 + g], acc, 0, 0, 0);
            acc = __builtin_amdgcn_mfma_f32_16x16x32_bf16(a3, Brow[12 + g], acc, 0, 0, 0);
            const float bcol = bias1[col];
#pragma unroll
            for (int j = 0; j < 4; ++j) {
                int row = m0 + g * 4 + j;
                if (row < n) C1[(size_t)row * 128 + col] = bf16_rne(acc[j] + bcol);
            }
        }
        {
            const bf16x8* Brow = (const bf16x8*)(B2t + (size_t)col * 128);
            f32x4 acc = {0.f, 0.f, 0.f, 0.f};
            acc = __builtin_amdgcn_mfma_f32_16x16x32_bf16(a0, Brow[g], acc, 0, 0, 0);
            acc = __builtin_amdgcn_mfma_f32_16x16x32_bf16(a1, Brow[4 + g], acc, 0, 0, 0);
            acc = __builtin_amdgcn_mfma_f32_16x16x32_bf16(a2, Brow[8 + g], acc, 0, 0, 0);
            acc = __builtin_amdgcn_mfma_f32_16x16x32_bf16(a3, Brow[12 + g], acc, 0, 0, 0);
            const float bcol = bias2[col];
#pragma unroll
            for (int j = 0; j < 4; ++j) {
                int row = m0 + g * 4 + j;
                if (row < n) C2[(size_t)row * 128 + col] = acc[j] + bcol;
            }
        }
    }
}

// ---------------- fused GATv2 aggregate + residuals + LayerNorm + ReLU ----------------
// one wave per node, TWO edges per wave: lanes 0-31 edge A, lanes 32-63 edge B.
// lane owns 4 features f0 = (lane&31)*4; head = (lane&31)>>3 -> 8-lane groups.
// log2-domain scores, shared reference max across halves+states (m identical in
// both halves: self-score computed identically; rescale uses cross-half max).
__global__ __launch_bounds__(256) void gat_aggregate(
    const float* __restrict__ h,
    const unsigned short* __restrict__ hs16,
    const float* __restrict__ hd,
    const int* __restrict__ offs,
    const int* __restrict__ csr_src,
    const float* __restrict__ attn,
    const float* __restrict__ ln_g, const float* __restrict__ ln_b,
    float* __restrict__ h_out, unsigned* __restrict__ h16_out, int n) {
    int v = (blockIdx.x * blockDim.x + threadIdx.x) >> 6;
    int lane = threadIdx.x & 63;
    if (v >= n) return;
    const int lh = lane & 31;
    const int half = lane >> 5;
    const int f0 = lh * 4;
    const unsigned fb = (unsigned)lh << 3; // byte offset into 256B bf16 row

    const float L2E = 1.4426950408889634f;
    float4 av = *(const float4*)&attn[f0];
    av.x *= L2E; av.y *= L2E; av.z *= L2E; av.w *= L2E;
    float4 hdv = *(const float4*)&hd[(size_t)v * 128 + f0];

    const char* hsb = (const char*)hs16;
    uint2 uv = *(const uint2*)(hsb + ((size_t)(unsigned)v << 8) + fb);
    float sv0 = __uint_as_float(uv.x << 16), sv1 = __uint_as_float(uv.x & 0xffff0000u);
    float sv2 = __uint_as_float(uv.y << 16), sv3 = __uint_as_float(uv.y & 0xffff0000u);

    // self-loop score (identical in both halves) -> reference max
    float t0 = sv0 + hdv.x; t0 = fmaxf(t0, 0.2f * t0);
    float t1 = sv1 + hdv.y; t1 = fmaxf(t1, 0.2f * t1);
    float t2 = sv2 + hdv.z; t2 = fmaxf(t2, 0.2f * t2);
    float t3 = sv3 + hdv.w; t3 = fmaxf(t3, 0.2f * t3);
    float m = row_sum8(fmaf(t3, av.w, fmaf(t2, av.z, fmaf(t1, av.y, t0 * av.x))));

    // two states per lane; self-loop only in half 0's state0
    float s0 = half ? 0.f : 1.f;
    float ax0 = half ? 0.f : sv0, ay0 = half ? 0.f : sv1;
    float az0 = half ? 0.f : sv2, aw0 = half ? 0.f : sv3;
    float s1 = 0.f, ax1 = 0.f, ay1 = 0.f, az1 = 0.f, aw1 = 0.f;

    int beg = offs[v], end = offs[v + 1];
    int i = beg;
    int end4 = beg + ((end - beg) & ~3);
    for (; i < end4; i += 4) {
        int ia = i + 2 * half;                 // half 0: edges i,i+1; half 1: i+2,i+3
        int ua = csr_src[ia], ub = csr_src[ia + 1];
        uint2 wa = *(const uint2*)(hsb + ((size_t)(unsigned)ua << 8) + fb);
        uint2 wb = *(const uint2*)(hsb + ((size_t)(unsigned)ub << 8) + fb);
        float a0f = __uint_as_float(wa.x << 16), a1f = __uint_as_float(wa.x & 0xffff0000u);
        float a2f = __uint_as_float(wa.y << 16), a3f = __uint_as_float(wa.y & 0xffff0000u);
        float b0f = __uint_as_float(wb.x << 16), b1f = __uint_as_float(wb.x & 0xffff0000u);
        float b2f = __uint_as_float(wb.y << 16), b3f = __uint_as_float(wb.y & 0xffff0000u);
        float qa0 = a0f + hdv.x; qa0 = fmaxf(qa0, 0.2f * qa0);
        float qa1 = a1f + hdv.y; qa1 = fmaxf(qa1, 0.2f * qa1);
        float qa2 = a2f + hdv.z; qa2 = fmaxf(qa2, 0.2f * qa2);
        float qa3 = a3f + hdv.w; qa3 = fmaxf(qa3, 0.2f * qa3);
        float qb0 = b0f + hdv.x; qb0 = fmaxf(qb0, 0.2f * qb0);
        float qb1 = b1f + hdv.y; qb1 = fmaxf(qb1, 0.2f * qb1);
        float qb2 = b2f + hdv.z; qb2 = fmaxf(qb2, 0.2f * qb2);
        float qb3 = b3f + hdv.w; qb3 = fmaxf(qb3, 0.2f * qb3);
        float sca = row_sum8(fmaf(qa3, av.w, fmaf(qa2, av.z, fmaf(qa1, av.y, qa0 * av.x))));
        float scb = row_sum8(fmaf(qb3, av.w, fmaf(qb2, av.z, fmaf(qb1, av.y, qb0 * av.x))));
        float da = sca - m, db = scb - m;
        float dm = fmaxf(da, db);
        if (__builtin_expect(__any(dm > 8.f), 0)) {
            float dmx = fmaxf(dm, __shfl_xor(dm, 32));   // per-head, cross-half
            float mn = m + fmaxf(dmx, 0.f);
            float rr = exp2f(m - mn);
            s0 *= rr; ax0 *= rr; ay0 *= rr; az0 *= rr; aw0 *= rr;
            s1 *= rr; ax1 *= rr; ay1 *= rr; az1 *= rr; aw1 *= rr;
            m = mn; da = sca - m; db = scb - m;
        }
        float ea = exp2f(da), eb = exp2f(db);
        s0 += ea;
        ax0 = fmaf(ea, a0f, ax0); ay0 = fmaf(ea, a1f, ay0);
        az0 = fmaf(ea, a2f, az0); aw0 = fmaf(ea, a3f, aw0);
        s1 += eb;
        ax1 = fmaf(eb, b0f, ax1); ay1 = fmaf(eb, b1f, ay1);
        az1 = fmaf(eb, b2f, az1); aw1 = fmaf(eb, b3f, aw1);
    }
    for (; i < end; ++i) { // tail: both halves same edge; half 1 contributes 0
        int u = csr_src[i];
        uint2 w = *(const uint2*)(hsb + ((size_t)(unsigned)u << 8) + fb);
        float c0 = __uint_as_float(w.x << 16), c1 = __uint_as_float(w.x & 0xffff0000u);
        float c2 = __uint_as_float(w.y << 16), c3 = __uint_as_float(w.y & 0xffff0000u);
        float q0 = c0 + hdv.x; q0 = fmaxf(q0, 0.2f * q0);
        float q1 = c1 + hdv.y; q1 = fmaxf(q1, 0.2f * q1);
        float q2 = c2 + hdv.z; q2 = fmaxf(q2, 0.2f * q2);
        float q3 = c3 + hdv.w; q3 = fmaxf(q3, 0.2f * q3);
        float sc = row_sum8(fmaf(q3, av.w, fmaf(q2, av.z, fmaf(q1, av.y, q0 * av.x))));
        float d0 = sc - m;
        if (__builtin_expect(__any(d0 > 8.f), 0)) {
            float mn = m + fmaxf(d0, 0.f);
            float rr = exp2f(m - mn);
            s0 *= rr; ax0 *= rr; ay0 *= rr; az0 *= rr; aw0 *= rr;
            s1 *= rr; ax1 *= rr; ay1 *= rr; az1 *= rr; aw1 *= rr;
            m = mn; d0 = sc - m;
        }
        float e = half ? 0.f : exp2f(d0);
        s0 += e;
        ax0 = fmaf(e, c0, ax0); ay0 = fmaf(e, c1, ay0);
        az0 = fmaf(e, c2, az0); aw0 = fmaf(e, c3, aw0);
    }
    // merge states (shared m) then cross-half
    float s  = s0 + s1;
    float ax = ax0 + ax1, ay = ay0 + ay1, az = az0 + az1, aw = aw0 + aw1;
    s  += __shfl_xor(s, 32);
    ax += __shfl_xor(ax, 32); ay += __shfl_xor(ay, 32);
    az += __shfl_xor(az, 32); aw += __shfl_xor(aw, 32);
    float inv = 1.0f / (s + 1e-9f);

    float4 hv = *(const float4*)&h[(size_t)v * 128 + f0];
    float x0 = fmaf(ax, inv, 2.f * hv.x);
    float x1 = fmaf(ay, inv, 2.f * hv.y);
    float x2 = fmaf(az, inv, 2.f * hv.z);
    float x3 = fmaf(aw, inv, 2.f * hv.w);

    // LayerNorm: halves hold identical x -> 64-lane reduce counts each feat 2x
    float sum = (x0 + x1) + (x2 + x3);
    float sq = fmaf(x0, x0, fmaf(x1, x1, fmaf(x2, x2, x3 * x3)));
#pragma unroll
    for (int d = 1; d < 64; d <<= 1) { sum += __shfl_xor(sum, d); sq += __shfl_xor(sq, d); }
    float mu = sum * (1.f / 256.f);
    float var = sq * (1.f / 256.f) - mu * mu;
    float rstd = rsqrtf(var + 1e-5f);
    float4 g4 = *(const float4*)&ln_g[f0];
    float4 b4 = *(const float4*)&ln_b[f0];
    float y0 = fmaxf(fmaf((x0 - mu) * rstd, g4.x, b4.x), 0.f);
    float y1 = fmaxf(fmaf((x1 - mu) * rstd, g4.y, b4.y), 0.f);
    float y2 = fmaxf(fmaf((x2 - mu) * rstd, g4.z, b4.z), 0.f);
    float y3 = fmaxf(fmaf((x3 - mu) * rstd, g4.w, b4.w), 0.f);
    if (half == 0) {
        *(float4*)&h_out[(size_t)v * 128 + f0] = make_float4(y0, y1, y2, y3);
        uint2 st;
        st.x = pack2_bf16_rne(y0, y1);
        st.y = pack2_bf16_rne(y2, y3);
        *(uint2*)((char*)h16_out + ((size_t)v << 8) + fb) = st;
    }
}

// ---------------- epilogue ----------------
__global__ __launch_bounds__(256) void mean_partial(const float4* __restrict__ src,
                                                    float* __restrict__ gacc, size_t n4) {
    int tid = threadIdx.x;
    size_t i = blockIdx.x * (size_t)256 + tid;
    size_t stride = (size_t)gridDim.x * 256;
    float ax = 0.f, ay = 0.f, az = 0.f, aw = 0.f;
    for (; i < n4; i += stride) {
        float4 v = src[i];
        ax += v.x; ay += v.y; az += v.z; aw += v.w;
    }
    __shared__ float4 sb[256];
    sb[tid] = make_float4(ax, ay, az, aw);
    __syncthreads();
    for (int off = 128; off >= 32; off >>= 1) {
        if (tid < off) {
            float4 o = sb[tid + off];
            sb[tid].x += o.x; sb[tid].y += o.y; sb[tid].z += o.z; sb[tid].w += o.w;
        }
        __syncthreads();
    }
    if (tid < 32) {
        float4 a = sb[tid];
        atomicAdd(&gacc[tid * 4 + 0], a.x);
        atomicAdd(&gacc[tid * 4 + 1], a.y);
        atomicAdd(&gacc[tid * 4 + 2], a.z);
        atomicAdd(&gacc[tid * 4 + 3], a.w);
    }
}

__global__ void graph_mean_final(const float* __restrict__ gacc, float* __restrict__ out, int n) {
    int c = threadIdx.x; // 128
    out[c] = gacc[c] / (float)n;
}

__global__ __launch_bounds__(256) void heads_kernel(
    const float* __restrict__ z,
    const float* __restrict__ Wa, const float* __restrict__ ba,
    const float* __restrict__ Wg, const float* __restrict__ bg,
    const float* __restrict__ Wal, const float* __restrict__ bal,
    const float* __restrict__ Wn, const float* __restrict__ bn,
    const float* __restrict__ Wt, const float* __restrict__ bt,
    float* __restrict__ logits, float* __restrict__ spawn, int n) {
    int v = (blockIdx.x * blockDim.x + threadIdx.x) >> 6;
    int lane = threadIdx.x & 63;
    if (v >= n) return;
    int f0 = lane * 2;
    float2 zv = *(const float2*)&z[(size_t)v * 128 + f0];
    float p0 = zv.x * Wa[f0 * 2]     + zv.y * Wa[(f0 + 1) * 2];
    float p1 = zv.x * Wa[f0 * 2 + 1] + zv.y * Wa[(f0 + 1) * 2 + 1];
    float p2 = zv.x * Wg[f0]  + zv.y * Wg[f0 + 1];
    float p3 = zv.x * Wal[f0] + zv.y * Wal[f0 + 1];
    float p4 = zv.x * Wn[f0]  + zv.y * Wn[f0 + 1];
    float p5 = zv.x * Wt[f0]  + zv.y * Wt[f0 + 1];
#pragma unroll
    for (int d = 1; d < 64; d <<= 1) {
        p0 += __shfl_xor(p0, d); p1 += __shfl_xor(p1, d); p2 += __shfl_xor(p2, d);
        p3 += __shfl_xor(p3, d); p4 += __shfl_xor(p4, d); p5 += __shfl_xor(p5, d);
    }
    if (lane == 0) {
        logits[(size_t)v * 2 + 0] = p0 + ba[0];
        logits[(size_t)v * 2 + 1] = p1 + ba[1];
        float gamma = 5.f / (1.f + __expf(-(p2 + bg[0])));
        float alpha = 2.f / (1.f + __expf(-(p3 + bal[0])));
        float noise = 1.f / (1.f + __expf(-(p4 + bn[0])));
        float theta = tanhf(p5 + bt[0]) * 3.14159265358979323846f;
        spawn[(size_t)v * 4 + 0] = gamma;
        spawn[(size_t)v * 4 + 1] = alpha;
        spawn[(size_t)v * 4 + 2] = noise;
        spawn[(size_t)v * 4 + 3] = theta;
    }
}

extern "C" void kernel_launch(void* const* d_in, const int* in_sizes, int n_in,
                              void* d_out, int out_size, void* d_ws, size_t ws_size,
                              hipStream_t stream) {
    const float* node_feats = (const float*)d_in[0];
    const int*   src  = (const int*)d_in[1];
    const int*   dst  = (const int*)d_in[2];
    const float* W_in = (const float*)d_in[3];
    const float* b_in = (const float*)d_in[4];
    const float* W_src = (const float*)d_in[5];
    const float* b_src = (const float*)d_in[6];
    const float* W_dst = (const float*)d_in[7];
    const float* b_dst = (const float*)d_in[8];
    const float* attn  = (const float*)d_in[9];
    const float* ln_g  = (const float*)d_in[10];
    const float* ln_b  = (const float*)d_in[11];
    const float* W1 = (const float*)d_in[12]; const float* b1 = (const float*)d_in[13];
    const float* W2 = (const float*)d_in[14]; const float* b2 = (const float*)d_in[15];
    const float* Wa = (const float*)d_in[16]; const float* ba = (const float*)d_in[17];
    const float* Wg = (const float*)d_in[18]; const float* bg = (const float*)d_in[19];
    const float* Wal = (const float*)d_in[20]; const float* bal = (const float*)d_in[21];
    const float* Wn = (const float*)d_in[22]; const float* bn = (const float*)d_in[23];
    const float* Wt = (const float*)d_in[24]; const float* bt = (const float*)d_in[25];

    const int n = in_sizes[0] / 32;  // 50000
    const int E = in_sizes[1];       // 1600000
    const int P = (n + 511) / 512;

    char* ws = (char*)d_ws;
    size_t off = 0;
    auto alloc = [&](size_t bytes) -> void* {
        void* p = ws + off;
        off = (off + bytes + 255) & ~(size_t)255;
        return p;
    };
    float* Bh0 = (float*)alloc((size_t)n * 128 * 4);
    float* Bh1 = (float*)alloc((size_t)n * 128 * 4);
    float* Bhd = (float*)alloc((size_t)n * 128 * 4);   // hd, later z
    unsigned short* h16  = (unsigned short*)alloc((size_t)n * 128 * 2);
    unsigned short* hs16 = (unsigned short*)alloc((size_t)n * 128 * 2); // also z1
    unsigned short* Wt16 = (unsigned short*)alloc((size_t)8 * 16384 * 2);
    int* deg  = (int*)alloc((size_t)n * 4);
    int* offs = (int*)alloc((size_t)(n + 1) * 4);
    int* woff = (int*)alloc((size_t)n * 4);
    int* csr  = (int*)alloc((size_t)E * 4);
    int* bsum = (int*)alloc((size_t)P * 4);
    int* bpre = (int*)alloc((size_t)P * 4);
    float* gacc = (float*)alloc(128 * 4);

    float* out = (float*)d_out;
    float* out_gemb   = out;
    float* out_nemb   = out + 128;
    float* out_logits = out + 128 + (size_t)n * 128;
    float* out_spawn  = out_logits + (size_t)n * 2;

    hipMemsetAsync(deg, 0, (size_t)n * 4, stream);
    hipMemsetAsync(gacc, 0, 128 * 4, stream);

    count_deg_xcd<<<1024, 256, 0, stream>>>(dst, deg, E, n);
    block_sums<<<P, 512, 0, stream>>>(deg, bsum, n);
    scan_partials<<<1, 128, 0, stream>>>(bsum, bpre, P);
    scan_blocks<<<P, 512, 0, stream>>>(deg, bpre, offs, woff, n);
    fill_csr_xcd<<<1024, 256, 0, stream>>>(src, dst, woff, csr, E, n);

    prep_weights<<<8, 256, 0, stream>>>(W_src, W_dst, W1, W2, Wt16);

    int gemm_grid = (n + GR - 1) / GR;
    int mfma_grid = (n + 63) / 64;

    // input projection -> f32 h + bf16 mirror
    gemm_k<32, false, true, true><<<gemm_grid, 256, 0, stream>>>(node_feats, W_in, b_in, Bh0, h16, n);

    float* cur = Bh0;
    for (int l = 0; l < 3; ++l) {
        gemm_mfma_dual<<<mfma_grid, 256, 0, stream>>>(
            h16, Wt16 + (size_t)l * 16384, Wt16 + (size_t)(3 + l) * 16384,
            b_src + l * 128, b_dst + l * 128, hs16, Bhd, n);
        float* nxt = (l == 2) ? out_nemb : ((cur == Bh0) ? Bh1 : Bh0);
        gat_aggregate<<<(n + 3) / 4, 256, 0, stream>>>(cur, hs16, Bhd, offs, csr,
                                                       attn + l * 128, ln_g + l * 128,
                                                       ln_b + l * 128, nxt, (unsigned*)h16, n);
        cur = nxt;
    }
    // cur == out_nemb (final node embedding, f32); h16 = bf16 mirror

    gemm_mfma<true, false, true><<<mfma_grid, 256, 0, stream>>>(
        h16, Wt16 + (size_t)6 * 16384, b1, nullptr, hs16, n);           // z1 (bf16)
    gemm_mfma<true, true, false><<<mfma_grid, 256, 0, stream>>>(
        hs16, Wt16 + (size_t)7 * 16384, b2, Bhd, nullptr, n);           // z (f32)

    mean_partial<<<512, 256, 0, stream>>>((const float4*)out_nemb, gacc, (size_t)n * 32);
    graph_mean_final<<<1, 128, 0, stream>>>(gacc, out_gemb, n);
    heads_kernel<<<(n + 3) / 4, 256, 0, stream>>>(Bhd, Wa, ba, Wg, bg, Wal, bal,
                                                  Wn, bn, Wt, bt, out_logits, out_spawn, n);
}

// Round 8
// 687.923 us; speedup vs baseline: 1.8605x; 1.0169x over previous
//
#include <hip/hip_runtime.h>
#include <hip/hip_bf16.h>

#define HID 128
#define NHEAD 4

typedef __attribute__((ext_vector_type(8))) short bf16x8;
typedef __attribute__((ext_vector_type(4))) float f32x4;
typedef __attribute__((ext_vector_type(2))) float f32x2;

// ---------------- CSR build ----------------
__global__ __launch_bounds__(256) void count_deg_xcd(const int* __restrict__ dst,
                                                     int* __restrict__ deg, int E, int n) {
    int grp = blockIdx.x & 7;
    int blk = blockIdx.x >> 3;
    int nblk = gridDim.x >> 3;
    int lo = (int)(((long long)n * grp) >> 3);
    int hi = (int)(((long long)n * (grp + 1)) >> 3);
    for (int i = blk * 256 + threadIdx.x; i < E; i += nblk * 256) {
        int d = dst[i];
        if (d >= lo && d < hi) atomicAdd(&deg[d], 1);
    }
}

__global__ void block_sums(const int* __restrict__ deg, int* __restrict__ bsum, int n) {
    __shared__ int sbuf[512];
    int tid = threadIdx.x;
    int i = blockIdx.x * 512 + tid;
    sbuf[tid] = (i < n) ? deg[i] : 0;
    __syncthreads();
    for (int d = 256; d > 0; d >>= 1) {
        if (tid < d) sbuf[tid] += sbuf[tid + d];
        __syncthreads();
    }
    if (tid == 0) bsum[blockIdx.x] = sbuf[0];
}

__global__ void scan_partials(const int* __restrict__ bsum, int* __restrict__ bpre, int P) {
    __shared__ int buf[128];
    int tid = threadIdx.x; // 128 threads, P <= 128
    int v = (tid < P) ? bsum[tid] : 0;
    buf[tid] = v;
    __syncthreads();
    for (int d = 1; d < 128; d <<= 1) {
        int t = (tid >= d) ? buf[tid - d] : 0;
        __syncthreads();
        buf[tid] += t;
        __syncthreads();
    }
    if (tid < P) bpre[tid] = buf[tid] - v; // exclusive
}

__global__ void scan_blocks(const int* __restrict__ deg, const int* __restrict__ bpre,
                            int* __restrict__ offs, int* __restrict__ woff, int n) {
    __shared__ int sbuf[512];
    int tid = threadIdx.x;
    int i = blockIdx.x * 512 + tid;
    int v = (i < n) ? deg[i] : 0;
    sbuf[tid] = v;
    __syncthreads();
    for (int d = 1; d < 512; d <<= 1) {
        int t = (tid >= d) ? sbuf[tid - d] : 0;
        __syncthreads();
        sbuf[tid] += t;
        __syncthreads();
    }
    if (i < n) {
        int incl = bpre[blockIdx.x] + sbuf[tid];
        offs[i + 1] = incl;
        woff[i] = incl - v;
    }
    if (i == 0) offs[0] = 0;
}

__global__ __launch_bounds__(256) void fill_csr_xcd(
    const int* __restrict__ src, const int* __restrict__ dst,
    int* __restrict__ woff, int* __restrict__ csr_src, int E, int n) {
    int grp = blockIdx.x & 7;
    int blk = blockIdx.x >> 3;
    int nblk = gridDim.x >> 3;
    int lo = (int)(((long long)n * grp) >> 3);
    int hi = (int)(((long long)n * (grp + 1)) >> 3);
    for (int i = blk * 256 + threadIdx.x; i < E; i += nblk * 256) {
        int d = dst[i];
        if (d >= lo && d < hi) {
            int pos = atomicAdd(&woff[d], 1);
            csr_src[pos] = src[i];
        }
    }
}

// ---------------- helpers ----------------
__device__ __forceinline__ unsigned pack2_bf16_rne(float lo, float hi) {
    unsigned a = __float_as_uint(lo);
    a = (a + 0x7fffu + ((a >> 16) & 1u)) >> 16;
    unsigned b = __float_as_uint(hi);
    b = (b + 0x7fffu + ((b >> 16) & 1u)) & 0xffff0000u;
    return a | b;
}

__device__ __forceinline__ unsigned short bf16_rne(float x) {
    unsigned u = __float_as_uint(x);
    u = (u + 0x7fffu + ((u >> 16) & 1u)) >> 16;
    return (unsigned short)u;
}

__device__ __forceinline__ f32x2 unpack_bf(unsigned u) {
    f32x2 r;
    r.x = __uint_as_float(u << 16);
    r.y = __uint_as_float(u & 0xffff0000u);
    return r;
}

__device__ __forceinline__ f32x2 leaky2(f32x2 q) {
    return __builtin_elementwise_max(q, q * 0.2f);
}

// 4-lane group sum via DPP: xor1 (quad_perm[1,0,3,2]=0xB1), xor2
// (quad_perm[2,3,0,1]=0x4E).
__device__ __forceinline__ float row_sum4(float x) {
    x += __int_as_float(__builtin_amdgcn_update_dpp(0, __float_as_int(x), 0xB1, 0xF, 0xF, true));
    x += __int_as_float(__builtin_amdgcn_update_dpp(0, __float_as_int(x), 0x4E, 0xF, 0xF, true));
    return x;
}

// Transpose+convert 8 [128,128] f32 weight mats to bf16 [N][K]
__global__ void prep_weights(const float* __restrict__ W_src, const float* __restrict__ W_dst,
                             const float* __restrict__ W1, const float* __restrict__ W2,
                             unsigned short* __restrict__ Wt) {
    int mat = blockIdx.x; // 0..7
    const float* Wf = (mat < 3) ? (W_src + (size_t)mat * 16384)
                    : (mat < 6) ? (W_dst + (size_t)(mat - 3) * 16384)
                    : (mat == 6) ? W1 : W2;
    unsigned short* out = Wt + (size_t)mat * 16384;
    for (int idx = threadIdx.x; idx < 16384; idx += blockDim.x) {
        int k = idx >> 7, nn = idx & 127;
        out[nn * 128 + k] = bf16_rne(Wf[idx]);
    }
}

// ---------------- vector GEMM (K=32 input projection) ----------------
#define GR 64
template <int K, bool RELU, bool F32OUT, bool BF16OUT>
__global__ __launch_bounds__(256) void gemm_k(const float* __restrict__ A,
                                              const float* __restrict__ W,
                                              const float* __restrict__ bias,
                                              float* __restrict__ Cf,
                                              unsigned short* __restrict__ C16, int n) {
    __shared__ __align__(16) float a_sh[GR * K];
    const int tid = threadIdx.x;
    const int tx = tid & 31;
    const int ty = tid >> 5;
    const int r0 = blockIdx.x * GR;

    for (int i = tid * 4; i < GR * K; i += 1024) {
        int r = i / K, k = i % K;
        int gr = r0 + r;
        float4 v = make_float4(0.f, 0.f, 0.f, 0.f);
        if (gr < n) v = *(const float4*)&A[(size_t)gr * K + k];
        *(float4*)&a_sh[i] = v;
    }
    __syncthreads();

    float4 acc[8];
#pragma unroll
    for (int r = 0; r < 8; ++r) acc[r] = make_float4(0.f, 0.f, 0.f, 0.f);

    const float* ab = &a_sh[ty * 8 * K];
    const float* wb = &W[tx * 4];

    for (int k = 0; k < K; k += 4) {
        float4 w0 = *(const float4*)&wb[(size_t)(k + 0) * 128];
        float4 w1 = *(const float4*)&wb[(size_t)(k + 1) * 128];
        float4 w2 = *(const float4*)&wb[(size_t)(k + 2) * 128];
        float4 w3 = *(const float4*)&wb[(size_t)(k + 3) * 128];
#pragma unroll
        for (int r = 0; r < 8; ++r) {
            float4 a4 = *(const float4*)&ab[r * K + k];
            acc[r].x = fmaf(a4.x, w0.x, acc[r].x);
            acc[r].y = fmaf(a4.x, w0.y, acc[r].y);
            acc[r].z = fmaf(a4.x, w0.z, acc[r].z);
            acc[r].w = fmaf(a4.x, w0.w, acc[r].w);
            acc[r].x = fmaf(a4.y, w1.x, acc[r].x);
            acc[r].y = fmaf(a4.y, w1.y, acc[r].y);
            acc[r].z = fmaf(a4.y, w1.z, acc[r].z);
            acc[r].w = fmaf(a4.y, w1.w, acc[r].w);
            acc[r].x = fmaf(a4.z, w2.x, acc[r].x);
            acc[r].y = fmaf(a4.z, w2.y, acc[r].y);
            acc[r].z = fmaf(a4.z, w2.z, acc[r].z);
            acc[r].w = fmaf(a4.z, w2.w, acc[r].w);
            acc[r].x = fmaf(a4.w, w3.x, acc[r].x);
            acc[r].y = fmaf(a4.w, w3.y, acc[r].y);
            acc[r].z = fmaf(a4.w, w3.z, acc[r].z);
            acc[r].w = fmaf(a4.w, w3.w, acc[r].w);
        }
    }

    float4 b4 = *(const float4*)&bias[tx * 4];
#pragma unroll
    for (int r = 0; r < 8; ++r) {
        int gr = r0 + ty * 8 + r;
        if (gr < n) {
            float4 o;
            o.x = acc[r].x + b4.x;
            o.y = acc[r].y + b4.y;
            o.z = acc[r].z + b4.z;
            o.w = acc[r].w + b4.w;
            if (RELU) {
                o.x = fmaxf(o.x, 0.f); o.y = fmaxf(o.y, 0.f);
                o.z = fmaxf(o.z, 0.f); o.w = fmaxf(o.w, 0.f);
            }
            if (F32OUT) *(float4*)&Cf[(size_t)gr * 128 + tx * 4] = o;
            if (BF16OUT) {
                uint2 st;
                st.x = pack2_bf16_rne(o.x, o.y);
                st.y = pack2_bf16_rne(o.z, o.w);
                *(uint2*)&C16[(size_t)gr * 128 + tx * 4] = st;
            }
        }
    }
}

// ---------------- MFMA GEMM (single output) ----------------
template <bool RELU, bool F32OUT, bool BF16OUT>
__global__ __launch_bounds__(256) void gemm_mfma(
    const unsigned short* __restrict__ A16,
    const unsigned short* __restrict__ Bt16,
    const float* __restrict__ bias,
    float* __restrict__ Cf, unsigned short* __restrict__ C16, int n) {
    const int wave = threadIdx.x >> 6;
    const int lane = threadIdx.x & 63;
    const int r = lane & 15, g = lane >> 4;
    const int m0 = blockIdx.x * 64 + wave * 16;
    int ra = m0 + r; if (ra > n - 1) ra = n - 1;
    const bf16x8* Arow = (const bf16x8*)(A16 + (size_t)ra * 128);
    bf16x8 a0 = Arow[g];
    bf16x8 a1 = Arow[4 + g];
    bf16x8 a2 = Arow[8 + g];
    bf16x8 a3 = Arow[12 + g];
#pragma unroll
    for (int ct = 0; ct < 8; ++ct) {
        const bf16x8* Brow = (const bf16x8*)(Bt16 + (size_t)(ct * 16 + r) * 128);
        f32x4 acc = {0.f, 0.f, 0.f, 0.f};
        acc = __builtin_amdgcn_mfma_f32_16x16x32_bf16(a0, Brow[g], acc, 0, 0, 0);
        acc = __builtin_amdgcn_mfma_f32_16x16x32_bf16(a1, Brow[4 + g], acc, 0, 0, 0);
        acc = __builtin_amdgcn_mfma_f32_16x16x32_bf16(a2, Brow[8 + g], acc, 0, 0, 0);
        acc = __builtin_amdgcn_mfma_f32_16x16x32_bf16(a3, Brow[12 + g], acc, 0, 0, 0);
        const int col = ct * 16 + r;
        const float bcol = bias[col];
#pragma unroll
        for (int j = 0; j < 4; ++j) {
            int row = m0 + g * 4 + j;
            if (row < n) {
                float v = acc[j] + bcol;
                if (RELU) v = fmaxf(v, 0.f);
                if (F32OUT) Cf[(size_t)row * 128 + col] = v;
                if (BF16OUT) C16[(size_t)row * 128 + col] = bf16_rne(v);
            }
        }
    }
}

// ---------------- MFMA GEMM dual: A read once, two B mats, both bf16 out ----------------
__global__ __launch_bounds__(256) void gemm_mfma_dual(
    const unsigned short* __restrict__ A16,
    const unsigned short* __restrict__ B1t, const unsigned short* __restrict__ B2t,
    const float* __restrict__ bias1, const float* __restrict__ bias2,
    unsigned short* __restrict__ C1, unsigned short* __restrict__ C2, int n) {
    const int wave = threadIdx.x >> 6;
    const int lane = threadIdx.x & 63;
    const int r = lane & 15, g = lane >> 4;
    const int m0 = blockIdx.x * 64 + wave * 16;
    int ra = m0 + r; if (ra > n - 1) ra = n - 1;
    const bf16x8* Arow = (const bf16x8*)(A16 + (size_t)ra * 128);
    bf16x8 a0 = Arow[g];
    bf16x8 a1 = Arow[4 + g];
    bf16x8 a2 = Arow[8 + g];
    bf16x8 a3 = Arow[12 + g];
#pragma unroll
    for (int ct = 0; ct < 8; ++ct) {
        const int col = ct * 16 + r;
        {
            const bf16x8* Brow = (const bf16x8*)(B1t + (size_t)col * 128);
            f32x4 acc = {0.f, 0.f, 0.f, 0.f};
            acc = __builtin_amdgcn_mfma_f32_16x16x32_bf16(a0, Brow[g], acc, 0, 0, 0);
            acc = __builtin_amdgcn_mfma_f32_16x16x32_bf16(a1, Brow[4 + g], acc, 0, 0, 0);
            acc = __builtin_amdgcn_mfma_f32_16x16x32_bf16(a2, Brow[8 + g], acc, 0, 0, 0);
            acc = __builtin_amdgcn_mfma_f32_16x16x32_bf16(a3, Brow[12 + g], acc, 0, 0, 0);
            const float bcol = bias1[col];
#pragma unroll
            for (int j = 0; j < 4; ++j) {
                int row = m0 + g * 4 + j;
                if (row < n) C1[(size_t)row * 128 + col] = bf16_rne(acc[j] + bcol);
            }
        }
        {
            const bf16x8* Brow = (const bf16x8*)(B2t + (size_t)col * 128);
            f32x4 acc = {0.f, 0.f, 0.f, 0.f};
            acc = __builtin_amdgcn_mfma_f32_16x16x32_bf16(a0, Brow[g], acc, 0, 0, 0);
            acc = __builtin_amdgcn_mfma_f32_16x16x32_bf16(a1, Brow[4 + g], acc, 0, 0, 0);
            acc = __builtin_amdgcn_mfma_f32_16x16x32_bf16(a2, Brow[8 + g], acc, 0, 0, 0);
            acc = __builtin_amdgcn_mfma_f32_16x16x32_bf16(a3, Brow[12 + g], acc, 0, 0, 0);
            const float bcol = bias2[col];
#pragma unroll
            for (int j = 0; j < 4; ++j) {
                int row = m0 + g * 4 + j;
                if (row < n) C2[(size_t)row * 128 + col] = bf16_rne(acc[j] + bcol);
            }
        }
    }
}

// ---------------- fused GATv2 aggregate + residuals + LayerNorm + ReLU ----------------
// one wave per node, FOUR edges per wave: quarter q = lane>>4 owns edge i+q.
// lane owns 8 features f0 = (lane&15)*8; head = (lane&15)>>2 -> 4-lane groups.
// log2-domain scores, packed f32 feature math (v_pk_*), shared reference max.
__global__ __launch_bounds__(256) void gat_aggregate(
    const float* __restrict__ h,             // [n,128] f32 (residual)
    const unsigned short* __restrict__ hs16, // [n,128] bf16 (gathered)
    const unsigned short* __restrict__ hd16, // [n,128] bf16 (scores only)
    const int* __restrict__ offs,
    const int* __restrict__ csr_src,
    const float* __restrict__ attn,
    const float* __restrict__ ln_g, const float* __restrict__ ln_b,
    float* __restrict__ h_out, unsigned* __restrict__ h16_out, int n) {
    int v = (blockIdx.x * blockDim.x + threadIdx.x) >> 6;
    int lane = threadIdx.x & 63;
    if (v >= n) return;
    const int lh = lane & 15;
    const int quarter = lane >> 4;
    const int f0 = lh * 8;
    const unsigned fb = (unsigned)lh << 4; // byte offset into 256B bf16 row

    const float L2E = 1.4426950408889634f;
    f32x2 av0, av1, av2, av3;
    {
        float4 aa = *(const float4*)&attn[f0];
        float4 ab = *(const float4*)&attn[f0 + 4];
        av0 = (f32x2){aa.x, aa.y} * L2E; av1 = (f32x2){aa.z, aa.w} * L2E;
        av2 = (f32x2){ab.x, ab.y} * L2E; av3 = (f32x2){ab.z, ab.w} * L2E;
    }
    const char* hsb = (const char*)hs16;
    f32x2 hd0, hd1, hd2, hd3;
    {
        uint4 wd = *(const uint4*)((const char*)hd16 + ((size_t)(unsigned)v << 8) + fb);
        hd0 = unpack_bf(wd.x); hd1 = unpack_bf(wd.y);
        hd2 = unpack_bf(wd.z); hd3 = unpack_bf(wd.w);
    }
    // self-loop (identical in all quarters)
    uint4 wv = *(const uint4*)(hsb + ((size_t)(unsigned)v << 8) + fb);
    f32x2 sv0 = unpack_bf(wv.x), sv1 = unpack_bf(wv.y);
    f32x2 sv2 = unpack_bf(wv.z), sv3 = unpack_bf(wv.w);
    float m;
    {
        f32x2 q0 = leaky2(sv0 + hd0), q1 = leaky2(sv1 + hd1);
        f32x2 q2 = leaky2(sv2 + hd2), q3 = leaky2(sv3 + hd3);
        f32x2 dt = q0 * av0; dt += q1 * av1; dt += q2 * av2; dt += q3 * av3;
        m = row_sum4(dt.x + dt.y);
    }
    const bool q0lane = (quarter == 0);
    float s = q0lane ? 1.f : 0.f;
    f32x2 acc0 = q0lane ? sv0 : (f32x2){0.f, 0.f};
    f32x2 acc1 = q0lane ? sv1 : (f32x2){0.f, 0.f};
    f32x2 acc2 = q0lane ? sv2 : (f32x2){0.f, 0.f};
    f32x2 acc3 = q0lane ? sv3 : (f32x2){0.f, 0.f};

    int beg = offs[v], end = offs[v + 1];
    int i = beg;
    int end4 = beg + ((end - beg) & ~3);
    for (; i < end4; i += 4) {
        int u = csr_src[i + quarter];
        uint4 w = *(const uint4*)(hsb + ((size_t)(unsigned)u << 8) + fb);
        f32x2 g0 = unpack_bf(w.x), g1 = unpack_bf(w.y);
        f32x2 g2 = unpack_bf(w.z), g3 = unpack_bf(w.w);
        f32x2 p0 = leaky2(g0 + hd0), p1 = leaky2(g1 + hd1);
        f32x2 p2 = leaky2(g2 + hd2), p3 = leaky2(g3 + hd3);
        f32x2 dt = p0 * av0; dt += p1 * av1; dt += p2 * av2; dt += p3 * av3;
        float sc = row_sum4(dt.x + dt.y);
        float d0 = sc - m;
        if (__builtin_expect(__any(d0 > 8.f), 0)) {
            float dmx = fmaxf(d0, __shfl_xor(d0, 16));
            dmx = fmaxf(dmx, __shfl_xor(dmx, 32));
            float mn = m + fmaxf(dmx, 0.f);
            float rr = exp2f(m - mn);
            s *= rr; acc0 *= rr; acc1 *= rr; acc2 *= rr; acc3 *= rr;
            m = mn; d0 = sc - m;
        }
        float e = exp2f(d0);
        s += e;
        acc0 += g0 * e; acc1 += g1 * e; acc2 += g2 * e; acc3 += g3 * e;
    }
    for (; i < end; ++i) { // tail: all quarters same edge; only quarter 0 adds
        int u = csr_src[i];
        uint4 w = *(const uint4*)(hsb + ((size_t)(unsigned)u << 8) + fb);
        f32x2 g0 = unpack_bf(w.x), g1 = unpack_bf(w.y);
        f32x2 g2 = unpack_bf(w.z), g3 = unpack_bf(w.w);
        f32x2 p0 = leaky2(g0 + hd0), p1 = leaky2(g1 + hd1);
        f32x2 p2 = leaky2(g2 + hd2), p3 = leaky2(g3 + hd3);
        f32x2 dt = p0 * av0; dt += p1 * av1; dt += p2 * av2; dt += p3 * av3;
        float sc = row_sum4(dt.x + dt.y);
        float d0 = sc - m;
        if (__builtin_expect(__any(d0 > 8.f), 0)) {
            float mn = m + fmaxf(d0, 0.f);   // d0 uniform across quarters here
            float rr = exp2f(m - mn);
            s *= rr; acc0 *= rr; acc1 *= rr; acc2 *= rr; acc3 *= rr;
            m = mn; d0 = sc - m;
        }
        float e = q0lane ? exp2f(d0) : 0.f;
        s += e;
        acc0 += g0 * e; acc1 += g1 * e; acc2 += g2 * e; acc3 += g3 * e;
    }
    // cross-quarter merge (shared m -> plain adds)
#pragma unroll
    for (int d = 16; d <= 32; d <<= 1) {
        s += __shfl_xor(s, d);
        acc0.x += __shfl_xor(acc0.x, d); acc0.y += __shfl_xor(acc0.y, d);
        acc1.x += __shfl_xor(acc1.x, d); acc1.y += __shfl_xor(acc1.y, d);
        acc2.x += __shfl_xor(acc2.x, d); acc2.y += __shfl_xor(acc2.y, d);
        acc3.x += __shfl_xor(acc3.x, d); acc3.y += __shfl_xor(acc3.y, d);
    }
    float inv = 1.0f / (s + 1e-9f);

    f32x2 hv0, hv1, hv2, hv3;
    {
        float4 ha = *(const float4*)&h[(size_t)v * 128 + f0];
        float4 hb = *(const float4*)&h[(size_t)v * 128 + f0 + 4];
        hv0 = (f32x2){ha.x, ha.y}; hv1 = (f32x2){ha.z, ha.w};
        hv2 = (f32x2){hb.x, hb.y}; hv3 = (f32x2){hb.z, hb.w};
    }
    f32x2 x0 = acc0 * inv + hv0 * 2.f;
    f32x2 x1 = acc1 * inv + hv1 * 2.f;
    f32x2 x2 = acc2 * inv + hv2 * 2.f;
    f32x2 x3 = acc3 * inv + hv3 * 2.f;

    // LayerNorm: all quarters hold identical x -> 64-lane reduce counts 4x
    f32x2 sum2 = (x0 + x1) + (x2 + x3);
    f32x2 sq2 = x0 * x0 + x1 * x1 + x2 * x2 + x3 * x3;
    float sum = sum2.x + sum2.y, sq = sq2.x + sq2.y;
#pragma unroll
    for (int d = 1; d < 64; d <<= 1) { sum += __shfl_xor(sum, d); sq += __shfl_xor(sq, d); }
    float mu = sum * (1.f / 512.f);
    float var = sq * (1.f / 512.f) - mu * mu;
    float rstd = rsqrtf(var + 1e-5f);
    f32x2 g0v, g1v, g2v, g3v, b0v, b1v, b2v, b3v;
    {
        float4 ga = *(const float4*)&ln_g[f0];
        float4 gb = *(const float4*)&ln_g[f0 + 4];
        float4 ba = *(const float4*)&ln_b[f0];
        float4 bb = *(const float4*)&ln_b[f0 + 4];
        g0v = (f32x2){ga.x, ga.y}; g1v = (f32x2){ga.z, ga.w};
        g2v = (f32x2){gb.x, gb.y}; g3v = (f32x2){gb.z, gb.w};
        b0v = (f32x2){ba.x, ba.y}; b1v = (f32x2){ba.z, ba.w};
        b2v = (f32x2){bb.x, bb.y}; b3v = (f32x2){bb.z, bb.w};
    }
    f32x2 zero = {0.f, 0.f};
    f32x2 y0 = __builtin_elementwise_max((x0 - mu) * rstd * g0v + b0v, zero);
    f32x2 y1 = __builtin_elementwise_max((x1 - mu) * rstd * g1v + b1v, zero);
    f32x2 y2 = __builtin_elementwise_max((x2 - mu) * rstd * g2v + b2v, zero);
    f32x2 y3 = __builtin_elementwise_max((x3 - mu) * rstd * g3v + b3v, zero);
    if (quarter == 0) {
        float* orow = &h_out[(size_t)v * 128 + f0];
        *(float4*)orow = make_float4(y0.x, y0.y, y1.x, y1.y);
        *(float4*)(orow + 4) = make_float4(y2.x, y2.y, y3.x, y3.y);
        uint4 st;
        st.x = pack2_bf16_rne(y0.x, y0.y);
        st.y = pack2_bf16_rne(y1.x, y1.y);
        st.z = pack2_bf16_rne(y2.x, y2.y);
        st.w = pack2_bf16_rne(y3.x, y3.y);
        *(uint4*)((char*)h16_out + ((size_t)v << 8) + fb) = st;
    }
}

// ---------------- epilogue ----------------
__global__ __launch_bounds__(256) void mean_partial(const float4* __restrict__ src,
                                                    float* __restrict__ gacc, size_t n4) {
    int tid = threadIdx.x;
    size_t i = blockIdx.x * (size_t)256 + tid;
    size_t stride = (size_t)gridDim.x * 256;
    float ax = 0.f, ay = 0.f, az = 0.f, aw = 0.f;
    for (; i < n4; i += stride) {
        float4 v = src[i];
        ax += v.x; ay += v.y; az += v.z; aw += v.w;
    }
    __shared__ float4 sb[256];
    sb[tid] = make_float4(ax, ay, az, aw);
    __syncthreads();
    for (int off = 128; off >= 32; off >>= 1) {
        if (tid < off) {
            float4 o = sb[tid + off];
            sb[tid].x += o.x; sb[tid].y += o.y; sb[tid].z += o.z; sb[tid].w += o.w;
        }
        __syncthreads();
    }
    if (tid < 32) {
        float4 a = sb[tid];
        atomicAdd(&gacc[tid * 4 + 0], a.x);
        atomicAdd(&gacc[tid * 4 + 1], a.y);
        atomicAdd(&gacc[tid * 4 + 2], a.z);
        atomicAdd(&gacc[tid * 4 + 3], a.w);
    }
}

__global__ void graph_mean_final(const float* __restrict__ gacc, float* __restrict__ out, int n) {
    int c = threadIdx.x; // 128
    out[c] = gacc[c] / (float)n;
}

__global__ __launch_bounds__(256) void heads_kernel(
    const float* __restrict__ z,
    const float* __restrict__ Wa, const float* __restrict__ ba,
    const float* __restrict__ Wg, const float* __restrict__ bg,
    const float* __restrict__ Wal, const float* __restrict__ bal,
    const float* __restrict__ Wn, const float* __restrict__ bn,
    const float* __restrict__ Wt, const float* __restrict__ bt,
    float* __restrict__ logits, float* __restrict__ spawn, int n) {
    int v = (blockIdx.x * blockDim.x + threadIdx.x) >> 6;
    int lane = threadIdx.x & 63;
    if (v >= n) return;
    int f0 = lane * 2;
    float2 zv = *(const float2*)&z[(size_t)v * 128 + f0];
    float p0 = zv.x * Wa[f0 * 2]     + zv.y * Wa[(f0 + 1) * 2];
    float p1 = zv.x * Wa[f0 * 2 + 1] + zv.y * Wa[(f0 + 1) * 2 + 1];
    float p2 = zv.x * Wg[f0]  + zv.y * Wg[f0 + 1];
    float p3 = zv.x * Wal[f0] + zv.y * Wal[f0 + 1];
    float p4 = zv.x * Wn[f0]  + zv.y * Wn[f0 + 1];
    float p5 = zv.x * Wt[f0]  + zv.y * Wt[f0 + 1];
#pragma unroll
    for (int d = 1; d < 64; d <<= 1) {
        p0 += __shfl_xor(p0, d); p1 += __shfl_xor(p1, d); p2 += __shfl_xor(p2, d);
        p3 += __shfl_xor(p3, d); p4 += __shfl_xor(p4, d); p5 += __shfl_xor(p5, d);
    }
    if (lane == 0) {
        logits[(size_t)v * 2 + 0] = p0 + ba[0];
        logits[(size_t)v * 2 + 1] = p1 + ba[1];
        float gamma = 5.f / (1.f + __expf(-(p2 + bg[0])));
        float alpha = 2.f / (1.f + __expf(-(p3 + bal[0])));
        float noise = 1.f / (1.f + __expf(-(p4 + bn[0])));
        float theta = tanhf(p5 + bt[0]) * 3.14159265358979323846f;
        spawn[(size_t)v * 4 + 0] = gamma;
        spawn[(size_t)v * 4 + 1] = alpha;
        spawn[(size_t)v * 4 + 2] = noise;
        spawn[(size_t)v * 4 + 3] = theta;
    }
}

extern "C" void kernel_launch(void* const* d_in, const int* in_sizes, int n_in,
                              void* d_out, int out_size, void* d_ws, size_t ws_size,
                              hipStream_t stream) {
    const float* node_feats = (const float*)d_in[0];
    const int*   src  = (const int*)d_in[1];
    const int*   dst  = (const int*)d_in[2];
    const float* W_in = (const float*)d_in[3];
    const float* b_in = (const float*)d_in[4];
    const float* W_src = (const float*)d_in[5];
    const float* b_src = (const float*)d_in[6];
    const float* W_dst = (const float*)d_in[7];
    const float* b_dst = (const float*)d_in[8];
    const float* attn  = (const float*)d_in[9];
    const float* ln_g  = (const float*)d_in[10];
    const float* ln_b  = (const float*)d_in[11];
    const float* W1 = (const float*)d_in[12]; const float* b1 = (const float*)d_in[13];
    const float* W2 = (const float*)d_in[14]; const float* b2 = (const float*)d_in[15];
    const float* Wa = (const float*)d_in[16]; const float* ba = (const float*)d_in[17];
    const float* Wg = (const float*)d_in[18]; const float* bg = (const float*)d_in[19];
    const float* Wal = (const float*)d_in[20]; const float* bal = (const float*)d_in[21];
    const float* Wn = (const float*)d_in[22]; const float* bn = (const float*)d_in[23];
    const float* Wt = (const float*)d_in[24]; const float* bt = (const float*)d_in[25];

    const int n = in_sizes[0] / 32;  // 50000
    const int E = in_sizes[1];       // 1600000
    const int P = (n + 511) / 512;

    char* ws = (char*)d_ws;
    size_t off = 0;
    auto alloc = [&](size_t bytes) -> void* {
        void* p = ws + off;
        off = (off + bytes + 255) & ~(size_t)255;
        return p;
    };
    float* Bh0 = (float*)alloc((size_t)n * 128 * 4);
    float* Bh1 = (float*)alloc((size_t)n * 128 * 4);
    float* Bz  = (float*)alloc((size_t)n * 128 * 4);   // z (f32)
    unsigned short* h16  = (unsigned short*)alloc((size_t)n * 128 * 2);
    unsigned short* hs16 = (unsigned short*)alloc((size_t)n * 128 * 2); // also z1
    unsigned short* hd16 = (unsigned short*)alloc((size_t)n * 128 * 2);
    unsigned short* Wt16 = (unsigned short*)alloc((size_t)8 * 16384 * 2);
    int* deg  = (int*)alloc((size_t)n * 4);
    int* offs = (int*)alloc((size_t)(n + 1) * 4);
    int* woff = (int*)alloc((size_t)n * 4);
    int* csr  = (int*)alloc((size_t)E * 4);
    int* bsum = (int*)alloc((size_t)P * 4);
    int* bpre = (int*)alloc((size_t)P * 4);
    float* gacc = (float*)alloc(128 * 4);

    float* out = (float*)d_out;
    float* out_gemb   = out;
    float* out_nemb   = out + 128;
    float* out_logits = out + 128 + (size_t)n * 128;
    float* out_spawn  = out_logits + (size_t)n * 2;

    hipMemsetAsync(deg, 0, (size_t)n * 4, stream);
    hipMemsetAsync(gacc, 0, 128 * 4, stream);

    count_deg_xcd<<<1024, 256, 0, stream>>>(dst, deg, E, n);
    block_sums<<<P, 512, 0, stream>>>(deg, bsum, n);
    scan_partials<<<1, 128, 0, stream>>>(bsum, bpre, P);
    scan_blocks<<<P, 512, 0, stream>>>(deg, bpre, offs, woff, n);
    fill_csr_xcd<<<1024, 256, 0, stream>>>(src, dst, woff, csr, E, n);

    prep_weights<<<8, 256, 0, stream>>>(W_src, W_dst, W1, W2, Wt16);

    int gemm_grid = (n + GR - 1) / GR;
    int mfma_grid = (n + 63) / 64;

    // input projection -> f32 h + bf16 mirror
    gemm_k<32, false, true, true><<<gemm_grid, 256, 0, stream>>>(node_feats, W_in, b_in, Bh0, h16, n);

    float* cur = Bh0;
    for (int l = 0; l < 3; ++l) {
        gemm_mfma_dual<<<mfma_grid, 256, 0, stream>>>(
            h16, Wt16 + (size_t)l * 16384, Wt16 + (size_t)(3 + l) * 16384,
            b_src + l * 128, b_dst + l * 128, hs16, hd16, n);
        float* nxt = (l == 2) ? out_nemb : ((cur == Bh0) ? Bh1 : Bh0);
        gat_aggregate<<<(n + 3) / 4, 256, 0, stream>>>(cur, hs16, hd16, offs, csr,
                                                       attn + l * 128, ln_g + l * 128,
                                                       ln_b + l * 128, nxt, (unsigned*)h16, n);
        cur = nxt;
    }
    // cur == out_nemb (final node embedding, f32); h16 = bf16 mirror

    gemm_mfma<true, false, true><<<mfma_grid, 256, 0, stream>>>(
        h16, Wt16 + (size_t)6 * 16384, b1, nullptr, hs16, n);           // z1 (bf16)
    gemm_mfma<true, true, false><<<mfma_grid, 256, 0, stream>>>(
        hs16, Wt16 + (size_t)7 * 16384, b2, Bz, nullptr, n);            // z (f32)

    mean_partial<<<512, 256, 0, stream>>>((const float4*)out_nemb, gacc, (size_t)n * 32);
    graph_mean_final<<<1, 128, 0, stream>>>(gacc, out_gemb, n);
    heads_kernel<<<(n + 3) / 4, 256, 0, stream>>>(Bz, Wa, ba, Wg, bg, Wal, bal,
                                                  Wn, bn, Wt, bt, out_logits, out_spawn, n);
}

// Round 9
// 633.580 us; speedup vs baseline: 2.0200x; 1.0858x over previous
//
#include <hip/hip_runtime.h>
#include <hip/hip_bf16.h>

#define HID 128
#define NHEAD 4

typedef __attribute__((ext_vector_type(8))) short bf16x8;
typedef __attribute__((ext_vector_type(4))) float f32x4;
typedef __attribute__((ext_vector_type(2))) float f32x2;

// ---------------- CSR build ----------------
__global__ __launch_bounds__(256) void count_deg_xcd(const int* __restrict__ dst,
                                                     int* __restrict__ deg, int E, int n) {
    int grp = blockIdx.x & 7;
    int blk = blockIdx.x >> 3;
    int nblk = gridDim.x >> 3;
    int lo = (int)(((long long)n * grp) >> 3);
    int hi = (int)(((long long)n * (grp + 1)) >> 3);
    for (int i = blk * 256 + threadIdx.x; i < E; i += nblk * 256) {
        int d = dst[i];
        if (d >= lo && d < hi) atomicAdd(&deg[d], 1);
    }
}

__global__ void block_sums(const int* __restrict__ deg, int* __restrict__ bsum, int n) {
    __shared__ int sbuf[512];
    int tid = threadIdx.x;
    int i = blockIdx.x * 512 + tid;
    sbuf[tid] = (i < n) ? deg[i] : 0;
    __syncthreads();
    for (int d = 256; d > 0; d >>= 1) {
        if (tid < d) sbuf[tid] += sbuf[tid + d];
        __syncthreads();
    }
    if (tid == 0) bsum[blockIdx.x] = sbuf[0];
}

__global__ void scan_partials(const int* __restrict__ bsum, int* __restrict__ bpre, int P) {
    __shared__ int buf[128];
    int tid = threadIdx.x; // 128 threads, P <= 128
    int v = (tid < P) ? bsum[tid] : 0;
    buf[tid] = v;
    __syncthreads();
    for (int d = 1; d < 128; d <<= 1) {
        int t = (tid >= d) ? buf[tid - d] : 0;
        __syncthreads();
        buf[tid] += t;
        __syncthreads();
    }
    if (tid < P) bpre[tid] = buf[tid] - v; // exclusive
}

__global__ void scan_blocks(const int* __restrict__ deg, const int* __restrict__ bpre,
                            int* __restrict__ offs, int* __restrict__ woff, int n) {
    __shared__ int sbuf[512];
    int tid = threadIdx.x;
    int i = blockIdx.x * 512 + tid;
    int v = (i < n) ? deg[i] : 0;
    sbuf[tid] = v;
    __syncthreads();
    for (int d = 1; d < 512; d <<= 1) {
        int t = (tid >= d) ? sbuf[tid - d] : 0;
        __syncthreads();
        sbuf[tid] += t;
        __syncthreads();
    }
    if (i < n) {
        int incl = bpre[blockIdx.x] + sbuf[tid];
        offs[i + 1] = incl;
        woff[i] = incl - v;
    }
    if (i == 0) offs[0] = 0;
}

__global__ __launch_bounds__(256) void fill_csr_xcd(
    const int* __restrict__ src, const int* __restrict__ dst,
    int* __restrict__ woff, int* __restrict__ csr_src, int E, int n) {
    int grp = blockIdx.x & 7;
    int blk = blockIdx.x >> 3;
    int nblk = gridDim.x >> 3;
    int lo = (int)(((long long)n * grp) >> 3);
    int hi = (int)(((long long)n * (grp + 1)) >> 3);
    for (int i = blk * 256 + threadIdx.x; i < E; i += nblk * 256) {
        int d = dst[i];
        if (d >= lo && d < hi) {
            int pos = atomicAdd(&woff[d], 1);
            csr_src[pos] = src[i];
        }
    }
}

// ---------------- helpers ----------------
__device__ __forceinline__ unsigned pack2_bf16_rne(float lo, float hi) {
    unsigned a = __float_as_uint(lo);
    a = (a + 0x7fffu + ((a >> 16) & 1u)) >> 16;
    unsigned b = __float_as_uint(hi);
    b = (b + 0x7fffu + ((b >> 16) & 1u)) & 0xffff0000u;
    return a | b;
}

__device__ __forceinline__ unsigned short bf16_rne(float x) {
    unsigned u = __float_as_uint(x);
    u = (u + 0x7fffu + ((u >> 16) & 1u)) >> 16;
    return (unsigned short)u;
}

__device__ __forceinline__ f32x2 unpack_bf(unsigned u) {
    f32x2 r;
    r.x = __uint_as_float(u << 16);
    r.y = __uint_as_float(u & 0xffff0000u);
    return r;
}

__device__ __forceinline__ f32x2 leaky2(f32x2 q) {
    return __builtin_elementwise_max(q, q * 0.2f);
}

// 4-lane group sum via DPP: xor1 (quad_perm[1,0,3,2]=0xB1), xor2
// (quad_perm[2,3,0,1]=0x4E).
__device__ __forceinline__ float row_sum4(float x) {
    x += __int_as_float(__builtin_amdgcn_update_dpp(0, __float_as_int(x), 0xB1, 0xF, 0xF, true));
    x += __int_as_float(__builtin_amdgcn_update_dpp(0, __float_as_int(x), 0x4E, 0xF, 0xF, true));
    return x;
}

// Transpose+convert 8 [128,128] f32 weight mats to bf16 [N][K]
__global__ void prep_weights(const float* __restrict__ W_src, const float* __restrict__ W_dst,
                             const float* __restrict__ W1, const float* __restrict__ W2,
                             unsigned short* __restrict__ Wt) {
    int mat = blockIdx.x; // 0..7
    const float* Wf = (mat < 3) ? (W_src + (size_t)mat * 16384)
                    : (mat < 6) ? (W_dst + (size_t)(mat - 3) * 16384)
                    : (mat == 6) ? W1 : W2;
    unsigned short* out = Wt + (size_t)mat * 16384;
    for (int idx = threadIdx.x; idx < 16384; idx += blockDim.x) {
        int k = idx >> 7, nn = idx & 127;
        out[nn * 128 + k] = bf16_rne(Wf[idx]);
    }
}

// ---------------- vector GEMM (K=32 input projection) ----------------
#define GR 64
template <int K, bool RELU, bool F32OUT, bool BF16OUT>
__global__ __launch_bounds__(256) void gemm_k(const float* __restrict__ A,
                                              const float* __restrict__ W,
                                              const float* __restrict__ bias,
                                              float* __restrict__ Cf,
                                              unsigned short* __restrict__ C16, int n) {
    __shared__ __align__(16) float a_sh[GR * K];
    const int tid = threadIdx.x;
    const int tx = tid & 31;
    const int ty = tid >> 5;
    const int r0 = blockIdx.x * GR;

    for (int i = tid * 4; i < GR * K; i += 1024) {
        int r = i / K, k = i % K;
        int gr = r0 + r;
        float4 v = make_float4(0.f, 0.f, 0.f, 0.f);
        if (gr < n) v = *(const float4*)&A[(size_t)gr * K + k];
        *(float4*)&a_sh[i] = v;
    }
    __syncthreads();

    float4 acc[8];
#pragma unroll
    for (int r = 0; r < 8; ++r) acc[r] = make_float4(0.f, 0.f, 0.f, 0.f);

    const float* ab = &a_sh[ty * 8 * K];
    const float* wb = &W[tx * 4];

    for (int k = 0; k < K; k += 4) {
        float4 w0 = *(const float4*)&wb[(size_t)(k + 0) * 128];
        float4 w1 = *(const float4*)&wb[(size_t)(k + 1) * 128];
        float4 w2 = *(const float4*)&wb[(size_t)(k + 2) * 128];
        float4 w3 = *(const float4*)&wb[(size_t)(k + 3) * 128];
#pragma unroll
        for (int r = 0; r < 8; ++r) {
            float4 a4 = *(const float4*)&ab[r * K + k];
            acc[r].x = fmaf(a4.x, w0.x, acc[r].x);
            acc[r].y = fmaf(a4.x, w0.y, acc[r].y);
            acc[r].z = fmaf(a4.x, w0.z, acc[r].z);
            acc[r].w = fmaf(a4.x, w0.w, acc[r].w);
            acc[r].x = fmaf(a4.y, w1.x, acc[r].x);
            acc[r].y = fmaf(a4.y, w1.y, acc[r].y);
            acc[r].z = fmaf(a4.y, w1.z, acc[r].z);
            acc[r].w = fmaf(a4.y, w1.w, acc[r].w);
            acc[r].x = fmaf(a4.z, w2.x, acc[r].x);
            acc[r].y = fmaf(a4.z, w2.y, acc[r].y);
            acc[r].z = fmaf(a4.z, w2.z, acc[r].z);
            acc[r].w = fmaf(a4.z, w2.w, acc[r].w);
            acc[r].x = fmaf(a4.w, w3.x, acc[r].x);
            acc[r].y = fmaf(a4.w, w3.y, acc[r].y);
            acc[r].z = fmaf(a4.w, w3.z, acc[r].z);
            acc[r].w = fmaf(a4.w, w3.w, acc[r].w);
        }
    }

    float4 b4 = *(const float4*)&bias[tx * 4];
#pragma unroll
    for (int r = 0; r < 8; ++r) {
        int gr = r0 + ty * 8 + r;
        if (gr < n) {
            float4 o;
            o.x = acc[r].x + b4.x;
            o.y = acc[r].y + b4.y;
            o.z = acc[r].z + b4.z;
            o.w = acc[r].w + b4.w;
            if (RELU) {
                o.x = fmaxf(o.x, 0.f); o.y = fmaxf(o.y, 0.f);
                o.z = fmaxf(o.z, 0.f); o.w = fmaxf(o.w, 0.f);
            }
            if (F32OUT) *(float4*)&Cf[(size_t)gr * 128 + tx * 4] = o;
            if (BF16OUT) {
                uint2 st;
                st.x = pack2_bf16_rne(o.x, o.y);
                st.y = pack2_bf16_rne(o.z, o.w);
                *(uint2*)&C16[(size_t)gr * 128 + tx * 4] = st;
            }
        }
    }
}

// ---------------- MFMA GEMM (single output) ----------------
template <bool RELU, bool F32OUT, bool BF16OUT>
__global__ __launch_bounds__(256) void gemm_mfma(
    const unsigned short* __restrict__ A16,
    const unsigned short* __restrict__ Bt16,
    const float* __restrict__ bias,
    float* __restrict__ Cf, unsigned short* __restrict__ C16, int n) {
    const int wave = threadIdx.x >> 6;
    const int lane = threadIdx.x & 63;
    const int r = lane & 15, g = lane >> 4;
    const int m0 = blockIdx.x * 64 + wave * 16;
    int ra = m0 + r; if (ra > n - 1) ra = n - 1;
    const bf16x8* Arow = (const bf16x8*)(A16 + (size_t)ra * 128);
    bf16x8 a0 = Arow[g];
    bf16x8 a1 = Arow[4 + g];
    bf16x8 a2 = Arow[8 + g];
    bf16x8 a3 = Arow[12 + g];
#pragma unroll
    for (int ct = 0; ct < 8; ++ct) {
        const bf16x8* Brow = (const bf16x8*)(Bt16 + (size_t)(ct * 16 + r) * 128);
        f32x4 acc = {0.f, 0.f, 0.f, 0.f};
        acc = __builtin_amdgcn_mfma_f32_16x16x32_bf16(a0, Brow[g], acc, 0, 0, 0);
        acc = __builtin_amdgcn_mfma_f32_16x16x32_bf16(a1, Brow[4 + g], acc, 0, 0, 0);
        acc = __builtin_amdgcn_mfma_f32_16x16x32_bf16(a2, Brow[8 + g], acc, 0, 0, 0);
        acc = __builtin_amdgcn_mfma_f32_16x16x32_bf16(a3, Brow[12 + g], acc, 0, 0, 0);
        const int col = ct * 16 + r;
        const float bcol = bias[col];
#pragma unroll
        for (int j = 0; j < 4; ++j) {
            int row = m0 + g * 4 + j;
            if (row < n) {
                float v = acc[j] + bcol;
                if (RELU) v = fmaxf(v, 0.f);
                if (F32OUT) Cf[(size_t)row * 128 + col] = v;
                if (BF16OUT) C16[(size_t)row * 128 + col] = bf16_rne(v);
            }
        }
    }
}

// ---------------- MFMA GEMM dual: A read once, two B mats, both bf16 out ----------------
__global__ __launch_bounds__(256) void gemm_mfma_dual(
    const unsigned short* __restrict__ A16,
    const unsigned short* __restrict__ B1t, const unsigned short* __restrict__ B2t,
    const float* __restrict__ bias1, const float* __restrict__ bias2,
    unsigned short* __restrict__ C1, unsigned short* __restrict__ C2, int n) {
    const int wave = threadIdx.x >> 6;
    const int lane = threadIdx.x & 63;
    const int r = lane & 15, g = lane >> 4;
    const int m0 = blockIdx.x * 64 + wave * 16;
    int ra = m0 + r; if (ra > n - 1) ra = n - 1;
    const bf16x8* Arow = (const bf16x8*)(A16 + (size_t)ra * 128);
    bf16x8 a0 = Arow[g];
    bf16x8 a1 = Arow[4 + g];
    bf16x8 a2 = Arow[8 + g];
    bf16x8 a3 = Arow[12 + g];
#pragma unroll
    for (int ct = 0; ct < 8; ++ct) {
        const int col = ct * 16 + r;
        {
            const bf16x8* Brow = (const bf16x8*)(B1t + (size_t)col * 128);
            f32x4 acc = {0.f, 0.f, 0.f, 0.f};
            acc = __builtin_amdgcn_mfma_f32_16x16x32_bf16(a0, Brow[g], acc, 0, 0, 0);
            acc = __builtin_amdgcn_mfma_f32_16x16x32_bf16(a1, Brow[4 + g], acc, 0, 0, 0);
            acc = __builtin_amdgcn_mfma_f32_16x16x32_bf16(a2, Brow[8 + g], acc, 0, 0, 0);
            acc = __builtin_amdgcn_mfma_f32_16x16x32_bf16(a3, Brow[12 + g], acc, 0, 0, 0);
            const float bcol = bias1[col];
#pragma unroll
            for (int j = 0; j < 4; ++j) {
                int row = m0 + g * 4 + j;
                if (row < n) C1[(size_t)row * 128 + col] = bf16_rne(acc[j] + bcol);
            }
        }
        {
            const bf16x8* Brow = (const bf16x8*)(B2t + (size_t)col * 128);
            f32x4 acc = {0.f, 0.f, 0.f, 0.f};
            acc = __builtin_amdgcn_mfma_f32_16x16x32_bf16(a0, Brow[g], acc, 0, 0, 0);
            acc = __builtin_amdgcn_mfma_f32_16x16x32_bf16(a1, Brow[4 + g], acc, 0, 0, 0);
            acc = __builtin_amdgcn_mfma_f32_16x16x32_bf16(a2, Brow[8 + g], acc, 0, 0, 0);
            acc = __builtin_amdgcn_mfma_f32_16x16x32_bf16(a3, Brow[12 + g], acc, 0, 0, 0);
            const float bcol = bias2[col];
#pragma unroll
            for (int j = 0; j < 4; ++j) {
                int row = m0 + g * 4 + j;
                if (row < n) C2[(size_t)row * 128 + col] = bf16_rne(acc[j] + bcol);
            }
        }
    }
}

// ---------------- fused GATv2 aggregate + residuals + LayerNorm + ReLU ----------------
// one wave per node, FOUR edges per wave: quarter q = lane>>4 owns edge i+q.
// lane owns 8 features f0 = (lane&15)*8; head = (lane&15)>>2 -> 4-lane groups.
// log2-domain scores, packed f32 math, shared reference max, software-pipelined
// gather (index+row prefetched one iteration ahead), masked single-pass tail.
__global__ __launch_bounds__(256) void gat_aggregate(
    const float* __restrict__ h,             // [n,128] f32 (residual)
    const unsigned short* __restrict__ hs16, // [n,128] bf16 (gathered)
    const unsigned short* __restrict__ hd16, // [n,128] bf16 (scores only)
    const int* __restrict__ offs,
    const int* __restrict__ csr_src,
    const float* __restrict__ attn,
    const float* __restrict__ ln_g, const float* __restrict__ ln_b,
    float* __restrict__ h_out, unsigned* __restrict__ h16_out, int n) {
    int v = (blockIdx.x * blockDim.x + threadIdx.x) >> 6;
    int lane = threadIdx.x & 63;
    if (v >= n) return;
    const int lh = lane & 15;
    const int quarter = lane >> 4;
    const int f0 = lh * 8;
    const unsigned fb = (unsigned)lh << 4; // byte offset into 256B bf16 row

    const float L2E = 1.4426950408889634f;
    f32x2 av0, av1, av2, av3;
    {
        float4 aa = *(const float4*)&attn[f0];
        float4 ab = *(const float4*)&attn[f0 + 4];
        av0 = (f32x2){aa.x, aa.y} * L2E; av1 = (f32x2){aa.z, aa.w} * L2E;
        av2 = (f32x2){ab.x, ab.y} * L2E; av3 = (f32x2){ab.z, ab.w} * L2E;
    }
    const char* hsb = (const char*)hs16;
    f32x2 hd0, hd1, hd2, hd3;
    {
        uint4 wd = *(const uint4*)((const char*)hd16 + ((size_t)(unsigned)v << 8) + fb);
        hd0 = unpack_bf(wd.x); hd1 = unpack_bf(wd.y);
        hd2 = unpack_bf(wd.z); hd3 = unpack_bf(wd.w);
    }
    // self-loop (identical in all quarters)
    uint4 wv = *(const uint4*)(hsb + ((size_t)(unsigned)v << 8) + fb);
    f32x2 sv0 = unpack_bf(wv.x), sv1 = unpack_bf(wv.y);
    f32x2 sv2 = unpack_bf(wv.z), sv3 = unpack_bf(wv.w);
    float m;
    {
        f32x2 q0 = leaky2(sv0 + hd0), q1 = leaky2(sv1 + hd1);
        f32x2 q2 = leaky2(sv2 + hd2), q3 = leaky2(sv3 + hd3);
        f32x2 dt = q0 * av0; dt += q1 * av1; dt += q2 * av2; dt += q3 * av3;
        m = row_sum4(dt.x + dt.y);
    }
    const bool q0lane = (quarter == 0);
    float s = q0lane ? 1.f : 0.f;
    f32x2 acc0 = q0lane ? sv0 : (f32x2){0.f, 0.f};
    f32x2 acc1 = q0lane ? sv1 : (f32x2){0.f, 0.f};
    f32x2 acc2 = q0lane ? sv2 : (f32x2){0.f, 0.f};
    f32x2 acc3 = q0lane ? sv3 : (f32x2){0.f, 0.f};

    int beg = offs[v], end = offs[v + 1];
    int end4 = beg + ((end - beg) & ~3);

    auto process = [&](uint4 w) {
        f32x2 g0 = unpack_bf(w.x), g1 = unpack_bf(w.y);
        f32x2 g2 = unpack_bf(w.z), g3 = unpack_bf(w.w);
        f32x2 p0 = leaky2(g0 + hd0), p1 = leaky2(g1 + hd1);
        f32x2 p2 = leaky2(g2 + hd2), p3 = leaky2(g3 + hd3);
        f32x2 dt = p0 * av0; dt += p1 * av1; dt += p2 * av2; dt += p3 * av3;
        float sc = row_sum4(dt.x + dt.y);
        float d0 = sc - m;
        if (__builtin_expect(__any(d0 > 8.f), 0)) {
            float dmx = fmaxf(d0, __shfl_xor(d0, 16));
            dmx = fmaxf(dmx, __shfl_xor(dmx, 32));
            float mn = m + fmaxf(dmx, 0.f);
            float rr = exp2f(m - mn);
            s *= rr; acc0 *= rr; acc1 *= rr; acc2 *= rr; acc3 *= rr;
            m = mn; d0 = sc - m;
        }
        float e = exp2f(d0);
        s += e;
        acc0 += g0 * e; acc1 += g1 * e; acc2 += g2 * e; acc3 += g3 * e;
    };

    if (end4 > beg) {
        // software pipeline: gather for iter k+1 issued before processing iter k
        uint4 w = *(const uint4*)(hsb + ((size_t)(unsigned)csr_src[beg + quarter] << 8) + fb);
        int un = (beg + 4 < end4) ? csr_src[beg + 4 + quarter] : 0;
        for (int i = beg + 4; i < end4; i += 4) {
            uint4 wn = *(const uint4*)(hsb + ((size_t)(unsigned)un << 8) + fb);
            if (i + 4 < end4) un = csr_src[i + 4 + quarter];
            process(w);
            w = wn;
        }
        process(w);
    }
    if (end4 < end) {
        // masked tail: one quad iteration, quarters >= remainder contribute 0
        int idx = end4 + quarter;
        bool act = idx < end;
        int u = csr_src[act ? idx : end4];
        uint4 w = *(const uint4*)(hsb + ((size_t)(unsigned)u << 8) + fb);
        f32x2 g0 = unpack_bf(w.x), g1 = unpack_bf(w.y);
        f32x2 g2 = unpack_bf(w.z), g3 = unpack_bf(w.w);
        f32x2 p0 = leaky2(g0 + hd0), p1 = leaky2(g1 + hd1);
        f32x2 p2 = leaky2(g2 + hd2), p3 = leaky2(g3 + hd3);
        f32x2 dt = p0 * av0; dt += p1 * av1; dt += p2 * av2; dt += p3 * av3;
        float sc = row_sum4(dt.x + dt.y);
        float d0 = sc - m;
        float d0m = act ? d0 : -1e30f;
        if (__builtin_expect(__any(d0m > 8.f), 0)) {
            float dmx = fmaxf(d0m, __shfl_xor(d0m, 16));
            dmx = fmaxf(dmx, __shfl_xor(dmx, 32));
            float mn = m + fmaxf(dmx, 0.f);
            float rr = exp2f(m - mn);
            s *= rr; acc0 *= rr; acc1 *= rr; acc2 *= rr; acc3 *= rr;
            m = mn; d0 = sc - m;
        }
        float e = act ? exp2f(d0) : 0.f;
        s += e;
        acc0 += g0 * e; acc1 += g1 * e; acc2 += g2 * e; acc3 += g3 * e;
    }
    // cross-quarter merge (shared m -> plain adds)
#pragma unroll
    for (int d = 16; d <= 32; d <<= 1) {
        s += __shfl_xor(s, d);
        acc0.x += __shfl_xor(acc0.x, d); acc0.y += __shfl_xor(acc0.y, d);
        acc1.x += __shfl_xor(acc1.x, d); acc1.y += __shfl_xor(acc1.y, d);
        acc2.x += __shfl_xor(acc2.x, d); acc2.y += __shfl_xor(acc2.y, d);
        acc3.x += __shfl_xor(acc3.x, d); acc3.y += __shfl_xor(acc3.y, d);
    }
    float inv = 1.0f / (s + 1e-9f);

    f32x2 hv0, hv1, hv2, hv3;
    {
        float4 ha = *(const float4*)&h[(size_t)v * 128 + f0];
        float4 hb = *(const float4*)&h[(size_t)v * 128 + f0 + 4];
        hv0 = (f32x2){ha.x, ha.y}; hv1 = (f32x2){ha.z, ha.w};
        hv2 = (f32x2){hb.x, hb.y}; hv3 = (f32x2){hb.z, hb.w};
    }
    f32x2 x0 = acc0 * inv + hv0 * 2.f;
    f32x2 x1 = acc1 * inv + hv1 * 2.f;
    f32x2 x2 = acc2 * inv + hv2 * 2.f;
    f32x2 x3 = acc3 * inv + hv3 * 2.f;

    // LayerNorm: all quarters hold identical x -> 64-lane reduce counts 4x
    f32x2 sum2 = (x0 + x1) + (x2 + x3);
    f32x2 sq2 = x0 * x0 + x1 * x1 + x2 * x2 + x3 * x3;
    float sum = sum2.x + sum2.y, sq = sq2.x + sq2.y;
#pragma unroll
    for (int d = 1; d < 64; d <<= 1) { sum += __shfl_xor(sum, d); sq += __shfl_xor(sq, d); }
    float mu = sum * (1.f / 512.f);
    float var = sq * (1.f / 512.f) - mu * mu;
    float rstd = rsqrtf(var + 1e-5f);
    f32x2 g0v, g1v, g2v, g3v, b0v, b1v, b2v, b3v;
    {
        float4 ga = *(const float4*)&ln_g[f0];
        float4 gb = *(const float4*)&ln_g[f0 + 4];
        float4 ba = *(const float4*)&ln_b[f0];
        float4 bb = *(const float4*)&ln_b[f0 + 4];
        g0v = (f32x2){ga.x, ga.y}; g1v = (f32x2){ga.z, ga.w};
        g2v = (f32x2){gb.x, gb.y}; g3v = (f32x2){gb.z, gb.w};
        b0v = (f32x2){ba.x, ba.y}; b1v = (f32x2){ba.z, ba.w};
        b2v = (f32x2){bb.x, bb.y}; b3v = (f32x2){bb.z, bb.w};
    }
    f32x2 zero = {0.f, 0.f};
    f32x2 y0 = __builtin_elementwise_max((x0 - mu) * rstd * g0v + b0v, zero);
    f32x2 y1 = __builtin_elementwise_max((x1 - mu) * rstd * g1v + b1v, zero);
    f32x2 y2 = __builtin_elementwise_max((x2 - mu) * rstd * g2v + b2v, zero);
    f32x2 y3 = __builtin_elementwise_max((x3 - mu) * rstd * g3v + b3v, zero);
    if (quarter == 0) {
        float* orow = &h_out[(size_t)v * 128 + f0];
        *(float4*)orow = make_float4(y0.x, y0.y, y1.x, y1.y);
        *(float4*)(orow + 4) = make_float4(y2.x, y2.y, y3.x, y3.y);
        uint4 st;
        st.x = pack2_bf16_rne(y0.x, y0.y);
        st.y = pack2_bf16_rne(y1.x, y1.y);
        st.z = pack2_bf16_rne(y2.x, y2.y);
        st.w = pack2_bf16_rne(y3.x, y3.y);
        *(uint4*)((char*)h16_out + ((size_t)v << 8) + fb) = st;
    }
}

// ---------------- epilogue ----------------
__global__ __launch_bounds__(256) void mean_partial(const float4* __restrict__ src,
                                                    float* __restrict__ gacc, size_t n4) {
    int tid = threadIdx.x;
    size_t i = blockIdx.x * (size_t)256 + tid;
    size_t stride = (size_t)gridDim.x * 256;
    float ax = 0.f, ay = 0.f, az = 0.f, aw = 0.f;
    for (; i < n4; i += stride) {
        float4 v = src[i];
        ax += v.x; ay += v.y; az += v.z; aw += v.w;
    }
    __shared__ float4 sb[256];
    sb[tid] = make_float4(ax, ay, az, aw);
    __syncthreads();
    for (int off = 128; off >= 32; off >>= 1) {
        if (tid < off) {
            float4 o = sb[tid + off];
            sb[tid].x += o.x; sb[tid].y += o.y; sb[tid].z += o.z; sb[tid].w += o.w;
        }
        __syncthreads();
    }
    if (tid < 32) {
        float4 a = sb[tid];
        atomicAdd(&gacc[tid * 4 + 0], a.x);
        atomicAdd(&gacc[tid * 4 + 1], a.y);
        atomicAdd(&gacc[tid * 4 + 2], a.z);
        atomicAdd(&gacc[tid * 4 + 3], a.w);
    }
}

__global__ void graph_mean_final(const float* __restrict__ gacc, float* __restrict__ out, int n) {
    int c = threadIdx.x; // 128
    out[c] = gacc[c] / (float)n;
}

__global__ __launch_bounds__(256) void heads_kernel(
    const float* __restrict__ z,
    const float* __restrict__ Wa, const float* __restrict__ ba,
    const float* __restrict__ Wg, const float* __restrict__ bg,
    const float* __restrict__ Wal, const float* __restrict__ bal,
    const float* __restrict__ Wn, const float* __restrict__ bn,
    const float* __restrict__ Wt, const float* __restrict__ bt,
    float* __restrict__ logits, float* __restrict__ spawn, int n) {
    int v = (blockIdx.x * blockDim.x + threadIdx.x) >> 6;
    int lane = threadIdx.x & 63;
    if (v >= n) return;
    int f0 = lane * 2;
    float2 zv = *(const float2*)&z[(size_t)v * 128 + f0];
    float p0 = zv.x * Wa[f0 * 2]     + zv.y * Wa[(f0 + 1) * 2];
    float p1 = zv.x * Wa[f0 * 2 + 1] + zv.y * Wa[(f0 + 1) * 2 + 1];
    float p2 = zv.x * Wg[f0]  + zv.y * Wg[f0 + 1];
    float p3 = zv.x * Wal[f0] + zv.y * Wal[f0 + 1];
    float p4 = zv.x * Wn[f0]  + zv.y * Wn[f0 + 1];
    float p5 = zv.x * Wt[f0]  + zv.y * Wt[f0 + 1];
#pragma unroll
    for (int d = 1; d < 64; d <<= 1) {
        p0 += __shfl_xor(p0, d); p1 += __shfl_xor(p1, d); p2 += __shfl_xor(p2, d);
        p3 += __shfl_xor(p3, d); p4 += __shfl_xor(p4, d); p5 += __shfl_xor(p5, d);
    }
    if (lane == 0) {
        logits[(size_t)v * 2 + 0] = p0 + ba[0];
        logits[(size_t)v * 2 + 1] = p1 + ba[1];
        float gamma = 5.f / (1.f + __expf(-(p2 + bg[0])));
        float alpha = 2.f / (1.f + __expf(-(p3 + bal[0])));
        float noise = 1.f / (1.f + __expf(-(p4 + bn[0])));
        float theta = tanhf(p5 + bt[0]) * 3.14159265358979323846f;
        spawn[(size_t)v * 4 + 0] = gamma;
        spawn[(size_t)v * 4 + 1] = alpha;
        spawn[(size_t)v * 4 + 2] = noise;
        spawn[(size_t)v * 4 + 3] = theta;
    }
}

extern "C" void kernel_launch(void* const* d_in, const int* in_sizes, int n_in,
                              void* d_out, int out_size, void* d_ws, size_t ws_size,
                              hipStream_t stream) {
    const float* node_feats = (const float*)d_in[0];
    const int*   src  = (const int*)d_in[1];
    const int*   dst  = (const int*)d_in[2];
    const float* W_in = (const float*)d_in[3];
    const float* b_in = (const float*)d_in[4];
    const float* W_src = (const float*)d_in[5];
    const float* b_src = (const float*)d_in[6];
    const float* W_dst = (const float*)d_in[7];
    const float* b_dst = (const float*)d_in[8];
    const float* attn  = (const float*)d_in[9];
    const float* ln_g  = (const float*)d_in[10];
    const float* ln_b  = (const float*)d_in[11];
    const float* W1 = (const float*)d_in[12]; const float* b1 = (const float*)d_in[13];
    const float* W2 = (const float*)d_in[14]; const float* b2 = (const float*)d_in[15];
    const float* Wa = (const float*)d_in[16]; const float* ba = (const float*)d_in[17];
    const float* Wg = (const float*)d_in[18]; const float* bg = (const float*)d_in[19];
    const float* Wal = (const float*)d_in[20]; const float* bal = (const float*)d_in[21];
    const float* Wn = (const float*)d_in[22]; const float* bn = (const float*)d_in[23];
    const float* Wt = (const float*)d_in[24]; const float* bt = (const float*)d_in[25];

    const int n = in_sizes[0] / 32;  // 50000
    const int E = in_sizes[1];       // 1600000
    const int P = (n + 511) / 512;

    char* ws = (char*)d_ws;
    size_t off = 0;
    auto alloc = [&](size_t bytes) -> void* {
        void* p = ws + off;
        off = (off + bytes + 255) & ~(size_t)255;
        return p;
    };
    float* Bh0 = (float*)alloc((size_t)n * 128 * 4);
    float* Bh1 = (float*)alloc((size_t)n * 128 * 4);
    float* Bz  = (float*)alloc((size_t)n * 128 * 4);   // z (f32)
    unsigned short* h16  = (unsigned short*)alloc((size_t)n * 128 * 2);
    unsigned short* hs16 = (unsigned short*)alloc((size_t)n * 128 * 2); // also z1
    unsigned short* hd16 = (unsigned short*)alloc((size_t)n * 128 * 2);
    unsigned short* Wt16 = (unsigned short*)alloc((size_t)8 * 16384 * 2);
    int* deg  = (int*)alloc((size_t)n * 4);
    int* offs = (int*)alloc((size_t)(n + 1) * 4);
    int* woff = (int*)alloc((size_t)n * 4);
    int* csr  = (int*)alloc((size_t)E * 4);
    int* bsum = (int*)alloc((size_t)P * 4);
    int* bpre = (int*)alloc((size_t)P * 4);
    float* gacc = (float*)alloc(128 * 4);

    float* out = (float*)d_out;
    float* out_gemb   = out;
    float* out_nemb   = out + 128;
    float* out_logits = out + 128 + (size_t)n * 128;
    float* out_spawn  = out_logits + (size_t)n * 2;

    hipMemsetAsync(deg, 0, (size_t)n * 4, stream);
    hipMemsetAsync(gacc, 0, 128 * 4, stream);

    count_deg_xcd<<<1024, 256, 0, stream>>>(dst, deg, E, n);
    block_sums<<<P, 512, 0, stream>>>(deg, bsum, n);
    scan_partials<<<1, 128, 0, stream>>>(bsum, bpre, P);
    scan_blocks<<<P, 512, 0, stream>>>(deg, bpre, offs, woff, n);
    fill_csr_xcd<<<1024, 256, 0, stream>>>(src, dst, woff, csr, E, n);

    prep_weights<<<8, 256, 0, stream>>>(W_src, W_dst, W1, W2, Wt16);

    int gemm_grid = (n + GR - 1) / GR;
    int mfma_grid = (n + 63) / 64;

    // input projection -> f32 h + bf16 mirror
    gemm_k<32, false, true, true><<<gemm_grid, 256, 0, stream>>>(node_feats, W_in, b_in, Bh0, h16, n);

    float* cur = Bh0;
    for (int l = 0; l < 3; ++l) {
        gemm_mfma_dual<<<mfma_grid, 256, 0, stream>>>(
            h16, Wt16 + (size_t)l * 16384, Wt16 + (size_t)(3 + l) * 16384,
            b_src + l * 128, b_dst + l * 128, hs16, hd16, n);
        float* nxt = (l == 2) ? out_nemb : ((cur == Bh0) ? Bh1 : Bh0);
        gat_aggregate<<<(n + 3) / 4, 256, 0, stream>>>(cur, hs16, hd16, offs, csr,
                                                       attn + l * 128, ln_g + l * 128,
                                                       ln_b + l * 128, nxt, (unsigned*)h16, n);
        cur = nxt;
    }
    // cur == out_nemb (final node embedding, f32); h16 = bf16 mirror

    gemm_mfma<true, false, true><<<mfma_grid, 256, 0, stream>>>(
        h16, Wt16 + (size_t)6 * 16384, b1, nullptr, hs16, n);           // z1 (bf16)
    gemm_mfma<true, true, false><<<mfma_grid, 256, 0, stream>>>(
        hs16, Wt16 + (size_t)7 * 16384, b2, Bz, nullptr, n);            // z (f32)

    mean_partial<<<512, 256, 0, stream>>>((const float4*)out_nemb, gacc, (size_t)n * 32);
    graph_mean_final<<<1, 128, 0, stream>>>(gacc, out_gemb, n);
    heads_kernel<<<(n + 3) / 4, 256, 0, stream>>>(Bz, Wa, ba, Wg, bg, Wal, bal,
                                                  Wn, bn, Wt, bt, out_logits, out_spawn, n);
}